// Round 4
// baseline (272.471 us; speedup 1.0000x reference)
//
#include <hip/hip_runtime.h>
#include <hip/hip_bf16.h>
#include <math.h>

// B=2 V=3 G=2 NH=8 C=128 CPG=64 CH=16 HPG=4 Hq=Wq=32 D=4 Hk=16 Wk=128 NS=2048
// Hi=Wi=64 SCALE=0.25 OFR=5 EPS=1e-5  RPE 63x255 per head
// All inputs fp32, output fp32 (established R2-R6).
// R17 = R16 with k_attn rebalanced:
//   - grid 512 = (bh, mblk, nc-half) x 512 thr = EXACTLY 2 blocks/CU (R16's 768
//     at 2/CU had a 256-block tail at half occupancy).
//   - window/qa/Ax are vi-independent -> block builds window ONCE, loops vi=0..2
//     internally (wave quarters split the half's 8 nc 4+4, LDS-merged per vi).
//   - halves merged externally: k_attn writes raw O partials + per-row si to
//     workspace (aliased into dead xt region; NEED unchanged); k_outproj sums
//     halves, normalizes by 1/(si0+si1), then does the output GEMM.
//   - dedicated 8KB merge buffer (LDS 68,096 total, still 2/CU; 2 barriers/vi).

typedef __attribute__((ext_vector_type(8))) short short8;
typedef __attribute__((ext_vector_type(4))) float f32x4;

__device__ __forceinline__ unsigned short f2b(float f){        // fp32 -> bf16 RNE
  unsigned u = __float_as_uint(f);
  return (unsigned short)((u + 0x7FFFu + ((u>>16)&1u)) >> 16);
}
__device__ __forceinline__ unsigned cvt_pk_bf16(float lo, float hi){  // HW RNE pair-convert
  unsigned r;
  asm("v_cvt_pk_bf16_f32 %0, %1, %2" : "=v"(r) : "v"(lo), "v"(hi));
  return r;
}

__global__ void k_probe(float* __restrict__ out, float code){
  if(blockIdx.x==0 && threadIdx.x==0) out[0] = code;
}

// ---------------------------------------------------------------- K0: offsets (3072) + x-transpose (768) + weight prep (320)
__global__ __launch_bounds__(256) void k_prep_off(
    const float* __restrict__ query, const float* __restrict__ refp,
    const float* __restrict__ w1, const float* __restrict__ b1,
    const float* __restrict__ lng, const float* __restrict__ lnb,
    const float* __restrict__ w2, float* __restrict__ rwo, float* __restrict__ rws,
    const float* __restrict__ x, float* __restrict__ xt,
    const float* __restrict__ k_w, const float* __restrict__ v_w, const float* __restrict__ out_w,
    unsigned short* __restrict__ kw16, unsigned short* __restrict__ vw16, float* __restrict__ ow_t){
  __shared__ float t[64][65];
  int bx = blockIdx.x;               // 4160 = 3072 offsets + 768 transpose + 320 wprep
  if(bx < 3072){
    int wid  = bx*4 + (threadIdx.x>>6);
    int lane = threadIdx.x & 63;
    int vi  = wid >> 12;
    int rem = wid & 4095;
    int bg  = rem >> 10;
    int pix = rem & 1023;
    int y = pix >> 5, xq = pix & 31;
    int b = bg >> 1, g = bg & 1;
    float qv = query[(size_t)(b*128 + g*64 + lane)*1024 + pix];
    float h[4]; float s1 = 0.f, s2 = 0.f;
    #pragma unroll
    for(int d=0; d<4; ++d){
      h[d] = qv*w1[vi*256 + lane*4 + d] + b1[vi*256 + lane*4 + d];
      s1 += h[d]; s2 += h[d]*h[d];
    }
    #pragma unroll
    for(int off=1; off<64; off<<=1){ s1 += __shfl_xor(s1, off); s2 += __shfl_xor(s2, off); }
    float mu   = s1 * (1.f/256.f);
    float var  = s2 * (1.f/256.f) - mu*mu;
    float rstd = rsqrtf(fmaxf(var, 0.f) + 1e-5f);
    float po[4] = {0.f,0.f,0.f,0.f};
    #pragma unroll
    for(int d=0; d<4; ++d){
      float hv = (h[d]-mu)*rstd*lng[vi*256+lane*4+d] + lnb[vi*256+lane*4+d];
      hv = 0.5f*hv*(1.f + erff(hv*0.70710678118654752f));   // exact GELU
      #pragma unroll
      for(int o=0; o<4; ++o) po[o] += w2[(vi*4+o)*256 + lane*4 + d] * hv;
    }
    #pragma unroll
    for(int off=1; off<64; off<<=1){
      #pragma unroll
      for(int o=0; o<4; ++o) po[o] += __shfl_xor(po[o], off);
    }
    if(lane == 0){
      int tt = y & 1, hk = y >> 1;
      float rng = tt ? (5.f/127.f) : (5.f/15.f);
      float csc = tt ? 63.5f : 15.5f;
      #pragma unroll
      for(int d=0; d<4; ++d){
        int wk = xq*4 + d;
        float rv = refp[(size_t)(((b*3+vi)*16 + hk)*128 + wk)*2 + (1-tt)];  // [..., ::-1]
        float coord = tanhf(po[d])*rng + rv;
        size_t o2 = ((size_t)(vi*4+bg)*2048 + hk*128 + wk)*2 + tt;
        rwo[o2] = coord;
        rws[o2] = coord * csc;
      }
    }
  } else if(bx < 3840){
    int pb = bx - 3072;
    int iy = pb & 63;
    int o2 = pb >> 6;
    const float* src = x + ((size_t)o2*64)*4096 + (size_t)iy*64;
    int ix = threadIdx.x & 63, cq = threadIdx.x >> 6;
    #pragma unroll
    for(int c0 = 0; c0 < 64; c0 += 4)
      t[c0+cq][ix] = src[(size_t)(c0+cq)*4096 + ix];
    __syncthreads();
    float* dst = xt + (((size_t)o2*64 + iy)*64)*64;
    int c = threadIdx.x & 63, xq = threadIdx.x >> 6;
    #pragma unroll
    for(int x0 = 0; x0 < 64; x0 += 4)
      dst[(size_t)(x0+xq)*64 + c] = t[c][x0+xq];
  } else {
    int wb = bx - 3840;              // 320 = 64 kw16 + 64 vw16 + 192 ow_t
    if(wb < 128){
      int i = (wb & 63)*256 + threadIdx.x;
      if(wb < 64) kw16[i] = f2b(k_w[i]);
      else        vw16[i] = f2b(v_w[i]);
    } else {
      int i = (wb-128)*256 + threadIdx.x;
      if(i < 49152){
        int r = i / 384, c = i - r*384;
        ow_t[c*128 + r] = out_w[i];
      }
    }
  }
}

// ---------------------------------------------------------------- K1: fused sample + MFMA K/V projection
__global__ __launch_bounds__(256) void k_sampro(
    const float* __restrict__ rwo, const float* __restrict__ xt,
    const unsigned short* __restrict__ kw16, const float* __restrict__ k_b,
    const unsigned short* __restrict__ vw16, const float* __restrict__ v_b,
    unsigned short* __restrict__ k_b16, unsigned short* __restrict__ v_t16){
  __shared__ alignas(16) unsigned short tile[16*136];   // 4352 B bf16 xs tile
  int bx = blockIdx.x;               // 768 = (vi*2+b)*128 + nt
  int nt = bx & 127;
  int r2 = bx >> 7;
  int b = r2 & 1, vi = r2 >> 1;
  int n0 = nt*16;
  int tid = threadIdx.x, wid = tid>>6, lane = tid&63;
  #pragma unroll
  for(int s = 0; s < 8; ++s){        // 32 (n,g) units, 8 per wave
    int u = wid*8 + s;
    int nl = u >> 1, g = u & 1;
    int n = n0 + nl;
    float yn = rwo[((size_t)(vi*4 + b*2 + g)*2048 + n)*2 + 0];
    float xn = rwo[((size_t)(vi*4 + b*2 + g)*2048 + n)*2 + 1];
    float px = (xn + 1.f)*31.5f;
    float py = (yn + 1.f)*31.5f;
    float x0 = floorf(px), y0 = floorf(py);
    float fx = px - x0, fy = py - y0;
    int ix0 = (int)x0, iy0 = (int)y0;
    const float* base = xt + (size_t)((b*3+vi)*2+g)*4096*64;
    float wts[4] = {(1.f-fx)*(1.f-fy), fx*(1.f-fy), (1.f-fx)*fy, fx*fy};
    int ixs[4] = {ix0, ix0+1, ix0, ix0+1};
    int iys[4] = {iy0, iy0, iy0+1, iy0+1};
    float acc = 0.f;
    #pragma unroll
    for(int tp=0; tp<4; ++tp){
      int ix = ixs[tp], iy = iys[tp];
      if(ix>=0 && ix<64 && iy>=0 && iy<64)
        acc += wts[tp] * base[(size_t)((iy<<6)+ix)*64 + lane];
    }
    tile[nl*136 + g*64 + lane] = f2b(acc);
  }
  __syncthreads();
  // ---- MFMA projection: wave w -> heads {2w, 2w+1}, k + v tiles each
  int c = lane & 15, qd = lane >> 4;
  short8 af[4];                      // A[m=sample n=c][k=c-chan qd*8+j], 4 x K=32 = 128 ch
  #pragma unroll
  for(int kc=0; kc<4; ++kc)
    af[kc] = *(const short8*)(&tile[c*136 + kc*32 + qd*8]);
  size_t vbbase = (size_t)(vi*16 + b*8)*2048*16;
  const float SC2 = 0.36067376022224085f;     // 0.25 * log2(e), folded into K
  #pragma unroll
  for(int half=0; half<2; ++half){
    int nh = wid*2 + half;
    size_t hbase = vbbase + (size_t)nh*2048*16;
    {  // K head: k_b16[n][ch], pre-scaled by SC2
      f32x4 C = {0.f,0.f,0.f,0.f};
      #pragma unroll
      for(int kc=0; kc<4; ++kc){
        short8 bf = *(const short8*)(kw16 + (size_t)(nh*16 + c)*128 + kc*32 + qd*8);
        C = __builtin_amdgcn_mfma_f32_16x16x32_bf16(af[kc], bf, C, 0, 0, 0);
      }
      float bias = k_b[nh*16 + c];
      #pragma unroll
      for(int r=0; r<4; ++r)
        k_b16[hbase + (size_t)(n0 + qd*4 + r)*16 + c] = f2b((C[r] + bias)*SC2);
    }
    {  // V head: v_t16[ch][n], plain layout, vectorized uint2 store
      f32x4 C = {0.f,0.f,0.f,0.f};
      #pragma unroll
      for(int kc=0; kc<4; ++kc){
        short8 bf = *(const short8*)(vw16 + (size_t)(nh*16 + c)*128 + kc*32 + qd*8);
        C = __builtin_amdgcn_mfma_f32_16x16x32_bf16(af[kc], bf, C, 0, 0, 0);
      }
      float bias = v_b[nh*16 + c];
      uint2 pk;
      pk.x = cvt_pk_bf16(C[0]+bias, C[1]+bias);
      pk.y = cvt_pk_bf16(C[2]+bias, C[3]+bias);
      *(uint2*)(v_t16 + hbase + (size_t)c*2048 + n0 + qd*4) = pk;
    }
  }
}

// ---------------------------------------------------------------- K2: MFMA flash attention, 512 thr, vi-loop, external half merge
__global__ __launch_bounds__(512,4) void k_attn(
    const float* __restrict__ rws, const unsigned short* __restrict__ k_b16,
    const unsigned short* __restrict__ v_t16, const float* __restrict__ query,
    const float* __restrict__ rpe, float* __restrict__ apc0, float* __restrict__ apc1,
    float* __restrict__ si_ws){
  __shared__ unsigned P32[47*263];               // 49,444 B (lo, hi-lo) log2-scaled bf16 pairs
  __shared__ alignas(16) short p_sm[8][16*40];   // 10,240 B per-wave P^T buffer
  __shared__ float red_sm[2048];                 //  8,192 B quarter-merge buffer
  int bx = blockIdx.x;            // 512 = bh*32 + mblk*2 + half
  int half = bx & 1;
  int mblk = (bx >> 1) & 15;
  int bh   = bx >> 5;
  int b = bh >> 3, nh = bh & 7, g = nh >> 2, bg = b*2 + g;
  int tid = threadIdx.x, wid = tid >> 6;
  int w4  = wid & 3;              // m-slot within the 64-row block
  int nhf = wid >> 2;             // nc quarter within this half
  int lane = tid & 63, c = lane & 15, qd = lane >> 4;
  int m0 = mblk*64 + w4*16;
  float gy0 = -1.f + (2.f/31.f)*(float)(mblk*2);
  float pyL = 15.5f*(gy0 - 4.f/3.f) + 31.f - 0.01f;
  float pyH = 15.5f*(gy0 + 2.f/31.f + 4.f/3.f) + 31.f + 0.01f;
  int a  = max(-1, (int)floorf(pyL));
  int bb = min(63, (int)floorf(pyH));
  int iy_lo = max(a - 1, bb - 46);
  {
    const float* rt = rpe + (size_t)nh*16065;
    for(int e = tid; e < 47*263; e += 512){
      int rr = e / 263;
      int cc = e - rr*263;
      if(cc < 258){
        int iy = iy_lo + rr;
        int ix = cc - 1;
        bool xv = (ix >= 0) && (ix <= 254);
        float lo = (xv && iy   >= 0 && iy   <= 62) ? rt[iy*255 + ix]     : 0.f;
        float hi = (xv && iy+1 >= 0 && iy+1 <= 62) ? rt[(iy+1)*255 + ix] : 0.f;
        P32[e] = cvt_pk_bf16(lo*1.44269504f, (hi - lo)*1.44269504f);
      }
    }
  }
  short8 qa;
  #pragma unroll
  for(int j=0; j<8; ++j){
    int ch = qd*8 + j;
    qa[j] = (qd < 2) ? (short)f2b(query[(size_t)(b*128 + nh*16 + ch)*1024 + m0 + c]) : (short)0;
  }
  float Ax2[4];
  #pragma unroll
  for(int r=0; r<4; ++r){
    int mr = m0 + qd*4 + r;
    float gxr = -1.f + (2.f/31.f)*(mr & 31);
    Ax2[r] = 63.5f*gxr + 128.f;
  }
  float gyw = -1.f + (2.f/31.f)*(float)(m0 >> 5);
  float Ay  = 15.5f*gyw + 31.f - (float)iy_lo;
  float loC = fmaxf(-1.f - (float)iy_lo, 0.f);
  float hiC = fminf(63.f - (float)iy_lo, 45.f);
  int ncB = half*8 + nhf*4;
  float* apc = half ? apc1 : apc0;
  int basei = (w4*64 + lane)*8;
  __syncthreads();
  for(int vi = 0; vi < 3; ++vi){
    size_t kvb  = (size_t)(vi*16 + bh)*2048*16;
    size_t rwsb = (size_t)(vi*4 + bg)*2048;
    float si[4] = {0.f, 0.f, 0.f, 0.f};
    f32x4 O = {0.f, 0.f, 0.f, 0.f};
    for(int nc = ncB; nc < ncB + 4; ++nc){
      int n0 = nc*128;
      f32x4 Sf[8];
      #pragma unroll
      for(int t=0; t<8; ++t){
        short8 bk = {0,0,0,0,0,0,0,0};
        if(qd < 2) bk = *(const short8*)(k_b16 + kvb + (size_t)(n0 + t*16 + c)*16 + qd*8);
        f32x4 z = {0.f,0.f,0.f,0.f};
        Sf[t] = __builtin_amdgcn_mfma_f32_16x16x32_bf16(qa, bk, z, 0, 0, 0);
      }
      float pf[8][4];
      #pragma unroll
      for(int t=0; t<8; ++t){
        float2 rs = *(const float2*)(rws + (rwsb + n0 + t*16 + c)*2);
        float py = Ay - rs.x;                      // per-sample, shared by all 4 r
        py = fminf(fmaxf(py, loC), hiC);
        float rf = floorf(py);
        float fy = py - rf;
        int rbase = (int)rf * 263;
        #pragma unroll
        for(int r=0; r<4; ++r){
          float px = Ax2[r] - rs.y;
          px = fminf(fmaxf(px, 0.f), 256.f);
          float cf = floorf(px);
          float fx = px - cf;
          int idx = rbase + (int)cf;
          unsigned w0 = P32[idx], w1 = P32[idx+1];
          float lo0 = __uint_as_float(w0 << 16), d0 = __uint_as_float(w0 & 0xFFFF0000u);
          float lo1 = __uint_as_float(w1 << 16), d1 = __uint_as_float(w1 & 0xFFFF0000u);
          float t0 = lo0 + fy*d0;
          float t1 = lo1 + fy*d1;
          float p = exp2f(Sf[t][r] + t0 + fx*(t1 - t0));   // K pre-scaled by 0.25*log2e
          si[r] += p;
          pf[t][r] = p;
        }
      }
      short* pw = &p_sm[wid][0];
      #pragma unroll
      for(int kc=0; kc<4; ++kc){
        #pragma unroll
        for(int r=0; r<4; ++r){
          unsigned pk = cvt_pk_bf16(pf[kc*2][r], pf[kc*2+1][r]);
          pw[(qd*4 + r)*40 + c]      = (short)pk;
          pw[(qd*4 + r)*40 + 16 + c] = (short)(pk >> 16);
        }
        short8 va = *(const short8*)(v_t16 + kvb + (size_t)c*2048 + n0 + kc*32 + qd*8);
        short8 pbf = *(const short8*)(&pw[c*40 + qd*8]);
        O = __builtin_amdgcn_mfma_f32_16x16x32_bf16(va, pbf, O, 0, 0, 0);
      }
    }
    // ---- merge the two quarters via dedicated LDS buffer
    __syncthreads();                 // also guards red_sm reuse from previous vi
    if(nhf){
      red_sm[basei+0] = O[0];  red_sm[basei+1] = O[1];
      red_sm[basei+2] = O[2];  red_sm[basei+3] = O[3];
      red_sm[basei+4] = si[0]; red_sm[basei+5] = si[1];
      red_sm[basei+6] = si[2]; red_sm[basei+7] = si[3];
    }
    __syncthreads();
    if(!nhf){
      O[0] += red_sm[basei+0]; O[1] += red_sm[basei+1];
      O[2] += red_sm[basei+2]; O[3] += red_sm[basei+3];
      si[0] += red_sm[basei+4]; si[1] += red_sm[basei+5];
      si[2] += red_sm[basei+6]; si[3] += red_sm[basei+7];
      #pragma unroll
      for(int r=0; r<4; ++r){
        float sv = si[r];
        sv += __shfl_xor(sv, 1); sv += __shfl_xor(sv, 2);
        sv += __shfl_xor(sv, 4); sv += __shfl_xor(sv, 8);
        si[r] = sv;
      }
      int msrc = (c >> 2)*16 + c;
      int rsel = c & 3;
      float s0 = __shfl(si[0], msrc), s1 = __shfl(si[1], msrc),
            s2 = __shfl(si[2], msrc), s3 = __shfl(si[3], msrc);
      float sv = (rsel==0) ? s0 : ((rsel==1) ? s1 : ((rsel==2) ? s2 : s3));
      float4 o4;
      o4.x = O[0]; o4.y = O[1]; o4.z = O[2]; o4.w = O[3];
      *(float4*)(apc + (size_t)(b*1024 + m0 + c)*384 + vi*128 + nh*16 + qd*4) = o4;
      if(qd == 0)
        si_ws[(size_t)(half*2048 + b*1024 + m0 + c)*24 + vi*8 + nh] = sv;
    }
  }
}

// ---------------------------------------------------------------- K3: half-merge + normalize + output projection
__global__ __launch_bounds__(256) void k_outproj(
    const float* __restrict__ apc0, const float* __restrict__ apc1,
    const float* __restrict__ si_ws, const float* __restrict__ ow_t,
    const float* __restrict__ out_b, float* __restrict__ out){
  __shared__ float A[4*384];         // 6 KB
  __shared__ float invs[4][24];
  int bx = blockIdx.x;               // 512 = b*256 + mt
  int b  = bx >> 8;
  int m0 = (bx & 255)*4;
  if(threadIdx.x < 96){
    int mi = threadIdx.x / 24, j = threadIdx.x - mi*24;
    size_t i0 = (size_t)(b*1024 + m0 + mi)*24 + j;
    invs[mi][j] = 1.f / (si_ws[i0] + si_ws[i0 + (size_t)2048*24]);
  }
  __syncthreads();
  const float4* s0 = (const float4*)(apc0 + ((size_t)b*1024 + m0)*384);
  const float4* s1 = (const float4*)(apc1 + ((size_t)b*1024 + m0)*384);
  float4* dst = (float4*)A;
  for(int i = threadIdx.x; i < 384; i += 256){
    float4 a0 = s0[i], a1 = s1[i];
    int row = i / 96;
    int grp = ((i - row*96) * 4) >> 4;
    float iv = invs[row][grp];
    float4 o;
    o.x = (a0.x + a1.x)*iv; o.y = (a0.y + a1.y)*iv;
    o.z = (a0.z + a1.z)*iv; o.w = (a0.w + a1.w)*iv;
    dst[i] = o;
  }
  __syncthreads();
  int oc = threadIdx.x & 127;
  int mh = threadIdx.x >> 7;         // 0..1, each handles 2 m-rows
  float acc[2] = {0.f,0.f};
  #pragma unroll 4
  for(int vc = 0; vc < 384; ++vc){
    float wv = ow_t[vc*128 + oc];
    #pragma unroll
    for(int j=0; j<2; ++j) acc[j] += wv * A[(mh*2+j)*384 + vc];
  }
  float ob = out_b[oc];
  #pragma unroll
  for(int j=0; j<2; ++j)
    out[((size_t)b*128 + oc)*1024 + m0 + mh*2 + j] = acc[j] + ob;
}

extern "C" void kernel_launch(void* const* d_in, const int* in_sizes, int n_in,
                              void* d_out, int out_size, void* d_ws, size_t ws_size,
                              hipStream_t stream){
  const float* x     = (const float*)d_in[0];
  const float* query = (const float*)d_in[1];
  const float* refp  = (const float*)d_in[2];
  const float* w1    = (const float*)d_in[3];
  const float* b1    = (const float*)d_in[4];
  const float* lng   = (const float*)d_in[5];
  const float* lnb   = (const float*)d_in[6];
  const float* w2    = (const float*)d_in[7];
  const float* k_w   = (const float*)d_in[8];
  const float* k_b   = (const float*)d_in[9];
  const float* v_w   = (const float*)d_in[10];
  const float* v_b   = (const float*)d_in[11];
  const float* out_w = (const float*)d_in[12];
  const float* out_b = (const float*)d_in[13];
  const float* rpe   = (const float*)d_in[14];

  const size_t O_XT   = 0;            // 12,582,912 (dead after k_sampro; reused below)
  const size_t O_RWO  = 12582912;     //    196,608
  const size_t O_RWS  = 12779520;     //    196,608
  const size_t O_KB16 = 12976128;     //  3,145,728
  const size_t O_VT16 = 16121856;     //  3,145,728
  const size_t O_APC  = 19267584;     //  3,145,728  (half 0 partials)
  const size_t O_KW16 = 22413312;     //     32,768
  const size_t O_VW16 = 22446080;     //     32,768
  const size_t O_OWT  = 22478848;     //    196,608
  const size_t NEED   = 22675456;
  // aliases into the dead xt region (k_attn/k_outproj run after k_sampro):
  const size_t O_APC1 = 0;            //  3,145,728  (half 1 partials)
  const size_t O_SIW  = 3145728;      //    393,216  (per-row si partials)
  if(ws_size < NEED){
    k_probe<<<1, 64, 0, stream>>>((float*)d_out, 100.f + (float)(ws_size >> 20));
    return;
  }
  char* ws = (char*)d_ws;
  float* xt      = (float*)(ws + O_XT);
  float* rwo     = (float*)(ws + O_RWO);
  float* rws     = (float*)(ws + O_RWS);
  unsigned short* k_b16 = (unsigned short*)(ws + O_KB16);
  unsigned short* v_t16 = (unsigned short*)(ws + O_VT16);
  float* apc0    = (float*)(ws + O_APC);
  float* apc1    = (float*)(ws + O_APC1);
  float* si_wsp  = (float*)(ws + O_SIW);
  unsigned short* kw16 = (unsigned short*)(ws + O_KW16);
  unsigned short* vw16 = (unsigned short*)(ws + O_VW16);
  float* ow_t    = (float*)(ws + O_OWT);

  k_prep_off<<<4160, 256, 0, stream>>>(query, refp, w1, b1, lng, lnb, w2, rwo, rws,
                                       x, xt, k_w, v_w, out_w, kw16, vw16, ow_t);
  k_sampro  <<<768,  256, 0, stream>>>(rwo, xt, kw16, k_b, vw16, v_b, k_b16, v_t16);
  k_attn    <<<512,  512, 0, stream>>>(rws, k_b16, v_t16, query, rpe, apc0, apc1, si_wsp);
  k_outproj <<<512,  256, 0, stream>>>(apc0, apc1, si_wsp, ow_t, out_b, (float*)d_out);
}

// Round 5
// 261.951 us; speedup vs baseline: 1.0402x; 1.0402x over previous
//
#include <hip/hip_runtime.h>
#include <hip/hip_bf16.h>
#include <math.h>

// B=2 V=3 G=2 NH=8 C=128 CPG=64 CH=16 HPG=4 Hq=Wq=32 D=4 Hk=16 Wk=128 NS=2048
// Hi=Wi=64 SCALE=0.25 OFR=5 EPS=1e-5  RPE 63x255 per head
// All inputs fp32, output fp32 (established R2-R6).
// R18 = R16 with k_attn blocks split by x-half instead of LDS-starved:
//   - block = (vi, bh, m-quad, xhalf): 4 grid-rows x 16 m-cols = 64 m-rows.
//     px range per xhalf is [64h, 64h+192] -> rpe window 49x197 = 38,612 B
//     (was 47x263 = 49,444). LDS total 48,852 -> 3 blocks/CU; grid 768 =
//     exactly 3x256: full residency, no half-occupancy tail (R16's 12% loss).
//   - everything else = R16: 8 waves, nc-halves split across wave groups,
//     single end-of-kernel LDS merge, in-kernel normalization (R17's external
//     merge + vi-loop regressed: 6 barriers/block + 2x partial writes).

typedef __attribute__((ext_vector_type(8))) short short8;
typedef __attribute__((ext_vector_type(4))) float f32x4;

__device__ __forceinline__ unsigned short f2b(float f){        // fp32 -> bf16 RNE
  unsigned u = __float_as_uint(f);
  return (unsigned short)((u + 0x7FFFu + ((u>>16)&1u)) >> 16);
}
__device__ __forceinline__ unsigned cvt_pk_bf16(float lo, float hi){  // HW RNE pair-convert
  unsigned r;
  asm("v_cvt_pk_bf16_f32 %0, %1, %2" : "=v"(r) : "v"(lo), "v"(hi));
  return r;
}

__global__ void k_probe(float* __restrict__ out, float code){
  if(blockIdx.x==0 && threadIdx.x==0) out[0] = code;
}

// ---------------------------------------------------------------- K0: offsets (3072) + x-transpose (768) + weight prep (320)
__global__ __launch_bounds__(256) void k_prep_off(
    const float* __restrict__ query, const float* __restrict__ refp,
    const float* __restrict__ w1, const float* __restrict__ b1,
    const float* __restrict__ lng, const float* __restrict__ lnb,
    const float* __restrict__ w2, float* __restrict__ rwo, float* __restrict__ rws,
    const float* __restrict__ x, float* __restrict__ xt,
    const float* __restrict__ k_w, const float* __restrict__ v_w, const float* __restrict__ out_w,
    unsigned short* __restrict__ kw16, unsigned short* __restrict__ vw16, float* __restrict__ ow_t){
  __shared__ float t[64][65];
  int bx = blockIdx.x;               // 4160 = 3072 offsets + 768 transpose + 320 wprep
  if(bx < 3072){
    int wid  = bx*4 + (threadIdx.x>>6);
    int lane = threadIdx.x & 63;
    int vi  = wid >> 12;
    int rem = wid & 4095;
    int bg  = rem >> 10;
    int pix = rem & 1023;
    int y = pix >> 5, xq = pix & 31;
    int b = bg >> 1, g = bg & 1;
    float qv = query[(size_t)(b*128 + g*64 + lane)*1024 + pix];
    float h[4]; float s1 = 0.f, s2 = 0.f;
    #pragma unroll
    for(int d=0; d<4; ++d){
      h[d] = qv*w1[vi*256 + lane*4 + d] + b1[vi*256 + lane*4 + d];
      s1 += h[d]; s2 += h[d]*h[d];
    }
    #pragma unroll
    for(int off=1; off<64; off<<=1){ s1 += __shfl_xor(s1, off); s2 += __shfl_xor(s2, off); }
    float mu   = s1 * (1.f/256.f);
    float var  = s2 * (1.f/256.f) - mu*mu;
    float rstd = rsqrtf(fmaxf(var, 0.f) + 1e-5f);
    float po[4] = {0.f,0.f,0.f,0.f};
    #pragma unroll
    for(int d=0; d<4; ++d){
      float hv = (h[d]-mu)*rstd*lng[vi*256+lane*4+d] + lnb[vi*256+lane*4+d];
      hv = 0.5f*hv*(1.f + erff(hv*0.70710678118654752f));   // exact GELU
      #pragma unroll
      for(int o=0; o<4; ++o) po[o] += w2[(vi*4+o)*256 + lane*4 + d] * hv;
    }
    #pragma unroll
    for(int off=1; off<64; off<<=1){
      #pragma unroll
      for(int o=0; o<4; ++o) po[o] += __shfl_xor(po[o], off);
    }
    if(lane == 0){
      int tt = y & 1, hk = y >> 1;
      float rng = tt ? (5.f/127.f) : (5.f/15.f);
      float csc = tt ? 63.5f : 15.5f;
      #pragma unroll
      for(int d=0; d<4; ++d){
        int wk = xq*4 + d;
        float rv = refp[(size_t)(((b*3+vi)*16 + hk)*128 + wk)*2 + (1-tt)];  // [..., ::-1]
        float coord = tanhf(po[d])*rng + rv;
        size_t o2 = ((size_t)(vi*4+bg)*2048 + hk*128 + wk)*2 + tt;
        rwo[o2] = coord;
        rws[o2] = coord * csc;
      }
    }
  } else if(bx < 3840){
    int pb = bx - 3072;
    int iy = pb & 63;
    int o2 = pb >> 6;
    const float* src = x + ((size_t)o2*64)*4096 + (size_t)iy*64;
    int ix = threadIdx.x & 63, cq = threadIdx.x >> 6;
    #pragma unroll
    for(int c0 = 0; c0 < 64; c0 += 4)
      t[c0+cq][ix] = src[(size_t)(c0+cq)*4096 + ix];
    __syncthreads();
    float* dst = xt + (((size_t)o2*64 + iy)*64)*64;
    int c = threadIdx.x & 63, xq = threadIdx.x >> 6;
    #pragma unroll
    for(int x0 = 0; x0 < 64; x0 += 4)
      dst[(size_t)(x0+xq)*64 + c] = t[c][x0+xq];
  } else {
    int wb = bx - 3840;              // 320 = 64 kw16 + 64 vw16 + 192 ow_t
    if(wb < 128){
      int i = (wb & 63)*256 + threadIdx.x;
      if(wb < 64) kw16[i] = f2b(k_w[i]);
      else        vw16[i] = f2b(v_w[i]);
    } else {
      int i = (wb-128)*256 + threadIdx.x;
      if(i < 49152){
        int r = i / 384, c = i - r*384;
        ow_t[c*128 + r] = out_w[i];
      }
    }
  }
}

// ---------------------------------------------------------------- K1: fused sample + MFMA K/V projection
__global__ __launch_bounds__(256) void k_sampro(
    const float* __restrict__ rwo, const float* __restrict__ xt,
    const unsigned short* __restrict__ kw16, const float* __restrict__ k_b,
    const unsigned short* __restrict__ vw16, const float* __restrict__ v_b,
    unsigned short* __restrict__ k_b16, unsigned short* __restrict__ v_t16){
  __shared__ alignas(16) unsigned short tile[16*136];   // 4352 B bf16 xs tile
  int bx = blockIdx.x;               // 768 = (vi*2+b)*128 + nt
  int nt = bx & 127;
  int r2 = bx >> 7;
  int b = r2 & 1, vi = r2 >> 1;
  int n0 = nt*16;
  int tid = threadIdx.x, wid = tid>>6, lane = tid&63;
  #pragma unroll
  for(int s = 0; s < 8; ++s){        // 32 (n,g) units, 8 per wave
    int u = wid*8 + s;
    int nl = u >> 1, g = u & 1;
    int n = n0 + nl;
    float yn = rwo[((size_t)(vi*4 + b*2 + g)*2048 + n)*2 + 0];
    float xn = rwo[((size_t)(vi*4 + b*2 + g)*2048 + n)*2 + 1];
    float px = (xn + 1.f)*31.5f;
    float py = (yn + 1.f)*31.5f;
    float x0 = floorf(px), y0 = floorf(py);
    float fx = px - x0, fy = py - y0;
    int ix0 = (int)x0, iy0 = (int)y0;
    const float* base = xt + (size_t)((b*3+vi)*2+g)*4096*64;
    float wts[4] = {(1.f-fx)*(1.f-fy), fx*(1.f-fy), (1.f-fx)*fy, fx*fy};
    int ixs[4] = {ix0, ix0+1, ix0, ix0+1};
    int iys[4] = {iy0, iy0, iy0+1, iy0+1};
    float acc = 0.f;
    #pragma unroll
    for(int tp=0; tp<4; ++tp){
      int ix = ixs[tp], iy = iys[tp];
      if(ix>=0 && ix<64 && iy>=0 && iy<64)
        acc += wts[tp] * base[(size_t)((iy<<6)+ix)*64 + lane];
    }
    tile[nl*136 + g*64 + lane] = f2b(acc);
  }
  __syncthreads();
  // ---- MFMA projection: wave w -> heads {2w, 2w+1}, k + v tiles each
  int c = lane & 15, qd = lane >> 4;
  short8 af[4];                      // A[m=sample n=c][k=c-chan qd*8+j], 4 x K=32 = 128 ch
  #pragma unroll
  for(int kc=0; kc<4; ++kc)
    af[kc] = *(const short8*)(&tile[c*136 + kc*32 + qd*8]);
  size_t vbbase = (size_t)(vi*16 + b*8)*2048*16;
  const float SC2 = 0.36067376022224085f;     // 0.25 * log2(e), folded into K
  #pragma unroll
  for(int half=0; half<2; ++half){
    int nh = wid*2 + half;
    size_t hbase = vbbase + (size_t)nh*2048*16;
    {  // K head: k_b16[n][ch], pre-scaled by SC2
      f32x4 C = {0.f,0.f,0.f,0.f};
      #pragma unroll
      for(int kc=0; kc<4; ++kc){
        short8 bf = *(const short8*)(kw16 + (size_t)(nh*16 + c)*128 + kc*32 + qd*8);
        C = __builtin_amdgcn_mfma_f32_16x16x32_bf16(af[kc], bf, C, 0, 0, 0);
      }
      float bias = k_b[nh*16 + c];
      #pragma unroll
      for(int r=0; r<4; ++r)
        k_b16[hbase + (size_t)(n0 + qd*4 + r)*16 + c] = f2b((C[r] + bias)*SC2);
    }
    {  // V head: v_t16[ch][n], plain layout, vectorized uint2 store
      f32x4 C = {0.f,0.f,0.f,0.f};
      #pragma unroll
      for(int kc=0; kc<4; ++kc){
        short8 bf = *(const short8*)(vw16 + (size_t)(nh*16 + c)*128 + kc*32 + qd*8);
        C = __builtin_amdgcn_mfma_f32_16x16x32_bf16(af[kc], bf, C, 0, 0, 0);
      }
      float bias = v_b[nh*16 + c];
      uint2 pk;
      pk.x = cvt_pk_bf16(C[0]+bias, C[1]+bias);
      pk.y = cvt_pk_bf16(C[2]+bias, C[3]+bias);
      *(uint2*)(v_t16 + hbase + (size_t)c*2048 + n0 + qd*4) = pk;
    }
  }
}

// ---------------------------------------------------------------- K2: MFMA flash attention, 512 thr, x-half blocks, 3 blocks/CU
__global__ __launch_bounds__(512,6) void k_attn(
    const float* __restrict__ rws, const unsigned short* __restrict__ k_b16,
    const unsigned short* __restrict__ v_t16, const float* __restrict__ query,
    const float* __restrict__ rpe, float* __restrict__ attn_pc){
  __shared__ unsigned P32[49*197];               // 38,612 B (lo, hi-lo) log2-scaled bf16 pairs
  __shared__ alignas(16) short p_sm[8][16*40];   // 10,240 B per-wave P^T buffer (reused as f32 merge buffer)
  int bx = blockIdx.x;            // 768 = vi*256 + bh*16 + mq*2 + h
  int vi = bx >> 8;
  int bh = (bx >> 4) & 15;
  int mq = (bx >> 1) & 7;         // m-quad: 4 consecutive grid rows
  int h  = bx & 1;                // x-half: m-cols [16h, 16h+16)
  int b = bh >> 3, nh = bh & 7, g = nh >> 2, bg = b*2 + g;
  int tid = threadIdx.x, wid = tid >> 6;
  int w4  = wid & 3;              // grid-row within the quad
  int nhf = wid >> 2;             // nc half: 0 -> nc 0..7, 1 -> nc 8..15
  int lane = tid & 63, c = lane & 15, qd = lane >> 4;
  int m0 = (mq*4 + w4)*32 + 16*h;
  int xoff = h*64;
  float gy0 = -1.f + (2.f/31.f)*(float)(mq*4);
  float pyL = 15.5f*(gy0 - 4.f/3.f) + 31.f - 0.01f;
  float pyH = 15.5f*(gy0 + 6.f/31.f + 4.f/3.f) + 31.f + 0.01f;
  int a  = max(-1, (int)floorf(pyL));
  int bb = min(63, (int)floorf(pyH));
  int iy_lo = max(a - 1, bb - 48);
  {
    const float* rt = rpe + (size_t)nh*16065;
    for(int e = tid; e < 49*197; e += 512){
      int rr = e / 197;
      int cc = e - rr*197;
      int iy = iy_lo + rr;
      int ix = cc - 1 + xoff;
      bool xv = (ix >= 0) && (ix <= 254);
      float lo = (xv && iy   >= 0 && iy   <= 62) ? rt[iy*255 + ix]     : 0.f;
      float hi = (xv && iy+1 >= 0 && iy+1 <= 62) ? rt[(iy+1)*255 + ix] : 0.f;
      P32[e] = cvt_pk_bf16(lo*1.44269504f, (hi - lo)*1.44269504f);
    }
  }
  short8 qa;
  #pragma unroll
  for(int j=0; j<8; ++j){
    int ch = qd*8 + j;
    qa[j] = (qd < 2) ? (short)f2b(query[(size_t)(b*128 + nh*16 + ch)*1024 + m0 + c]) : (short)0;
  }
  float Ax2[4];
  #pragma unroll
  for(int r=0; r<4; ++r){
    int mr = m0 + qd*4 + r;
    float gxr = -1.f + (2.f/31.f)*(mr & 31);
    Ax2[r] = 63.5f*gxr + 128.f;
  }
  // wave's 16 m-rows share one grid row -> y-side wave-uniform per sample
  float gyw = -1.f + (2.f/31.f)*(float)(m0 >> 5);
  float Ay  = 15.5f*gyw + 31.f - (float)iy_lo;
  float loC = fmaxf(-1.f - (float)iy_lo, 0.f);
  float hiC = fminf(63.f - (float)iy_lo, 47.f);
  float pxLo = (float)xoff, pxHi = (float)(xoff + 192);
  float si[4] = {0.f, 0.f, 0.f, 0.f};
  f32x4 O = {0.f, 0.f, 0.f, 0.f};
  size_t kvb  = (size_t)(vi*16 + bh)*2048*16;
  size_t rwsb = (size_t)(vi*4 + bg)*2048;
  __syncthreads();
  for(int nc = nhf*8, ncE = nhf*8 + 8; nc < ncE; ++nc){
    int n0 = nc*128;
    f32x4 Sf[8];
    #pragma unroll
    for(int t=0; t<8; ++t){
      short8 bk = {0,0,0,0,0,0,0,0};
      if(qd < 2) bk = *(const short8*)(k_b16 + kvb + (size_t)(n0 + t*16 + c)*16 + qd*8);
      f32x4 z = {0.f,0.f,0.f,0.f};
      Sf[t] = __builtin_amdgcn_mfma_f32_16x16x32_bf16(qa, bk, z, 0, 0, 0);
    }
    float pf[8][4];
    #pragma unroll
    for(int t=0; t<8; ++t){
      float2 rs = *(const float2*)(rws + (rwsb + n0 + t*16 + c)*2);
      float py = Ay - rs.x;                      // per-sample, shared by all 4 r
      py = fminf(fmaxf(py, loC), hiC);
      float rf = floorf(py);
      float fy = py - rf;
      int rbase = (int)rf * 197;
      #pragma unroll
      for(int r=0; r<4; ++r){
        float px = Ax2[r] - rs.y;
        px = fminf(fmaxf(px, pxLo), pxHi);
        float cf = floorf(px);
        float fx = px - cf;
        int idx = rbase + (int)cf + 1 - xoff;
        unsigned w0 = P32[idx], w1 = P32[idx+1];
        float lo0 = __uint_as_float(w0 << 16), d0 = __uint_as_float(w0 & 0xFFFF0000u);
        float lo1 = __uint_as_float(w1 << 16), d1 = __uint_as_float(w1 & 0xFFFF0000u);
        float t0 = lo0 + fy*d0;
        float t1 = lo1 + fy*d1;
        float p = exp2f(Sf[t][r] + t0 + fx*(t1 - t0));   // K pre-scaled by 0.25*log2e
        si[r] += p;
        pf[t][r] = p;
      }
    }
    short* pw = &p_sm[wid][0];
    #pragma unroll
    for(int kc=0; kc<4; ++kc){
      #pragma unroll
      for(int r=0; r<4; ++r){
        unsigned pk = cvt_pk_bf16(pf[kc*2][r], pf[kc*2+1][r]);
        pw[(qd*4 + r)*40 + c]      = (short)pk;
        pw[(qd*4 + r)*40 + 16 + c] = (short)(pk >> 16);
      }
      short8 va = *(const short8*)(v_t16 + kvb + (size_t)c*2048 + n0 + kc*32 + qd*8);
      short8 pbf = *(const short8*)(&pw[c*40 + qd*8]);
      O = __builtin_amdgcn_mfma_f32_16x16x32_bf16(va, pbf, O, 0, 0, 0);
    }
  }
  // ---- merge the two nc halves via LDS (reuse p_sm block as f32 buffer)
  __syncthreads();
  float* red = (float*)&p_sm[0][0];
  int basei = (w4*64 + lane)*8;
  if(nhf){
    red[basei+0] = O[0];  red[basei+1] = O[1];
    red[basei+2] = O[2];  red[basei+3] = O[3];
    red[basei+4] = si[0]; red[basei+5] = si[1];
    red[basei+6] = si[2]; red[basei+7] = si[3];
  }
  __syncthreads();
  if(!nhf){
    O[0] += red[basei+0]; O[1] += red[basei+1];
    O[2] += red[basei+2]; O[3] += red[basei+3];
    si[0] += red[basei+4]; si[1] += red[basei+5];
    si[2] += red[basei+6]; si[3] += red[basei+7];
    #pragma unroll
    for(int r=0; r<4; ++r){
      float sv = si[r];
      sv += __shfl_xor(sv, 1); sv += __shfl_xor(sv, 2);
      sv += __shfl_xor(sv, 4); sv += __shfl_xor(sv, 8);
      si[r] = sv;
    }
    int msrc = (c >> 2)*16 + c;
    int rsel = c & 3;
    float s0 = __shfl(si[0], msrc), s1 = __shfl(si[1], msrc),
          s2 = __shfl(si[2], msrc), s3 = __shfl(si[3], msrc);
    float sv = (rsel==0) ? s0 : ((rsel==1) ? s1 : ((rsel==2) ? s2 : s3));
    float inv = 1.f/sv;
    float4 o4;
    o4.x = O[0]*inv; o4.y = O[1]*inv; o4.z = O[2]*inv; o4.w = O[3]*inv;
    *(float4*)(attn_pc + (size_t)(b*1024 + m0 + c)*384 + vi*128 + nh*16 + qd*4) = o4;
  }
}

// ---------------------------------------------------------------- K3: output projection (512 blocks, 4 m-rows each)
__global__ __launch_bounds__(256) void k_outproj(
    const float* __restrict__ attn_pc, const float* __restrict__ ow_t, const float* __restrict__ out_b,
    float* __restrict__ out){
  __shared__ float A[4*384];         // 6 KB
  int bx = blockIdx.x;               // 512 = b*256 + mt
  int b  = bx >> 8;
  int m0 = (bx & 255)*4;
  const float4* src = (const float4*)(attn_pc + ((size_t)b*1024 + m0)*384);
  float4* dst = (float4*)A;
  for(int i = threadIdx.x; i < 384; i += 256) dst[i] = src[i];
  __syncthreads();
  int oc = threadIdx.x & 127;
  int mh = threadIdx.x >> 7;         // 0..1, each handles 2 m-rows
  float acc[2] = {0.f,0.f};
  #pragma unroll 4
  for(int vc = 0; vc < 384; ++vc){
    float wv = ow_t[vc*128 + oc];
    #pragma unroll
    for(int j=0; j<2; ++j) acc[j] += wv * A[(mh*2+j)*384 + vc];
  }
  float ob = out_b[oc];
  #pragma unroll
  for(int j=0; j<2; ++j)
    out[((size_t)b*128 + oc)*1024 + m0 + mh*2 + j] = acc[j] + ob;
}

extern "C" void kernel_launch(void* const* d_in, const int* in_sizes, int n_in,
                              void* d_out, int out_size, void* d_ws, size_t ws_size,
                              hipStream_t stream){
  const float* x     = (const float*)d_in[0];
  const float* query = (const float*)d_in[1];
  const float* refp  = (const float*)d_in[2];
  const float* w1    = (const float*)d_in[3];
  const float* b1    = (const float*)d_in[4];
  const float* lng   = (const float*)d_in[5];
  const float* lnb   = (const float*)d_in[6];
  const float* w2    = (const float*)d_in[7];
  const float* k_w   = (const float*)d_in[8];
  const float* k_b   = (const float*)d_in[9];
  const float* v_w   = (const float*)d_in[10];
  const float* v_b   = (const float*)d_in[11];
  const float* out_w = (const float*)d_in[12];
  const float* out_b = (const float*)d_in[13];
  const float* rpe   = (const float*)d_in[14];

  const size_t O_XT   = 0;            // 12,582,912
  const size_t O_RWO  = 12582912;     //    196,608
  const size_t O_RWS  = 12779520;     //    196,608
  const size_t O_KB16 = 12976128;     //  3,145,728
  const size_t O_VT16 = 16121856;     //  3,145,728
  const size_t O_APC  = 19267584;     //  3,145,728
  const size_t O_KW16 = 22413312;     //     32,768
  const size_t O_VW16 = 22446080;     //     32,768
  const size_t O_OWT  = 22478848;     //    196,608
  const size_t NEED   = 22675456;
  if(ws_size < NEED){
    k_probe<<<1, 64, 0, stream>>>((float*)d_out, 100.f + (float)(ws_size >> 20));
    return;
  }
  char* ws = (char*)d_ws;
  float* xt      = (float*)(ws + O_XT);
  float* rwo     = (float*)(ws + O_RWO);
  float* rws     = (float*)(ws + O_RWS);
  unsigned short* k_b16 = (unsigned short*)(ws + O_KB16);
  unsigned short* v_t16 = (unsigned short*)(ws + O_VT16);
  float* attn_pc = (float*)(ws + O_APC);
  unsigned short* kw16 = (unsigned short*)(ws + O_KW16);
  unsigned short* vw16 = (unsigned short*)(ws + O_VW16);
  float* ow_t    = (float*)(ws + O_OWT);

  k_prep_off<<<4160, 256, 0, stream>>>(query, refp, w1, b1, lng, lnb, w2, rwo, rws,
                                       x, xt, k_w, v_w, out_w, kw16, vw16, ow_t);
  k_sampro  <<<768,  256, 0, stream>>>(rwo, xt, kw16, k_b, vw16, v_b, k_b16, v_t16);
  k_attn    <<<768,  512, 0, stream>>>(rws, k_b16, v_t16, query, rpe, attn_pc);
  k_outproj <<<512,  256, 0, stream>>>(attn_pc, ow_t, out_b, (float*)d_out);
}

// Round 6
// 248.929 us; speedup vs baseline: 1.0946x; 1.0523x over previous
//
#include <hip/hip_runtime.h>
#include <hip/hip_bf16.h>
#include <math.h>

// B=2 V=3 G=2 NH=8 C=128 CPG=64 CH=16 HPG=4 Hq=Wq=32 D=4 Hk=16 Wk=128 NS=2048
// Hi=Wi=64 SCALE=0.25 OFR=5 EPS=1e-5  RPE 63x255 per head
// All inputs fp32, output fp32 (established R2-R6).
// R19 = R18 with the k_attn register spill fixed (R18's smoking gun: VGPR 40 +
// WRITE_SIZE 3072->15360KB = scratch traffic; at 3 blocks/CU the VGPR cap is
// 512/6=85 and Sf[8][4]+pf[8][4] alone need 64):
//   - nc-loop restructured as per-kc pipeline: only 2 current + 2 next S
//     fragments (one-ahead MFMA issue; latency hides under the ~100 cy of
//     bias VALU per kc); P values computed per-kc right before their
//     cvt_pk/LDS-write/PV-MFMA. Live state ~60 regs < 85 cap -> no spill.
//   - everything else identical to R18 (x-half window blocks, 3 blocks/CU,
//     single end merge, in-kernel normalization).

typedef __attribute__((ext_vector_type(8))) short short8;
typedef __attribute__((ext_vector_type(4))) float f32x4;

__device__ __forceinline__ unsigned short f2b(float f){        // fp32 -> bf16 RNE
  unsigned u = __float_as_uint(f);
  return (unsigned short)((u + 0x7FFFu + ((u>>16)&1u)) >> 16);
}
__device__ __forceinline__ unsigned cvt_pk_bf16(float lo, float hi){  // HW RNE pair-convert
  unsigned r;
  asm("v_cvt_pk_bf16_f32 %0, %1, %2" : "=v"(r) : "v"(lo), "v"(hi));
  return r;
}

__global__ void k_probe(float* __restrict__ out, float code){
  if(blockIdx.x==0 && threadIdx.x==0) out[0] = code;
}

// ---------------------------------------------------------------- K0: offsets (3072) + x-transpose (768) + weight prep (320)
__global__ __launch_bounds__(256) void k_prep_off(
    const float* __restrict__ query, const float* __restrict__ refp,
    const float* __restrict__ w1, const float* __restrict__ b1,
    const float* __restrict__ lng, const float* __restrict__ lnb,
    const float* __restrict__ w2, float* __restrict__ rwo, float* __restrict__ rws,
    const float* __restrict__ x, float* __restrict__ xt,
    const float* __restrict__ k_w, const float* __restrict__ v_w, const float* __restrict__ out_w,
    unsigned short* __restrict__ kw16, unsigned short* __restrict__ vw16, float* __restrict__ ow_t){
  __shared__ float t[64][65];
  int bx = blockIdx.x;               // 4160 = 3072 offsets + 768 transpose + 320 wprep
  if(bx < 3072){
    int wid  = bx*4 + (threadIdx.x>>6);
    int lane = threadIdx.x & 63;
    int vi  = wid >> 12;
    int rem = wid & 4095;
    int bg  = rem >> 10;
    int pix = rem & 1023;
    int y = pix >> 5, xq = pix & 31;
    int b = bg >> 1, g = bg & 1;
    float qv = query[(size_t)(b*128 + g*64 + lane)*1024 + pix];
    float h[4]; float s1 = 0.f, s2 = 0.f;
    #pragma unroll
    for(int d=0; d<4; ++d){
      h[d] = qv*w1[vi*256 + lane*4 + d] + b1[vi*256 + lane*4 + d];
      s1 += h[d]; s2 += h[d]*h[d];
    }
    #pragma unroll
    for(int off=1; off<64; off<<=1){ s1 += __shfl_xor(s1, off); s2 += __shfl_xor(s2, off); }
    float mu   = s1 * (1.f/256.f);
    float var  = s2 * (1.f/256.f) - mu*mu;
    float rstd = rsqrtf(fmaxf(var, 0.f) + 1e-5f);
    float po[4] = {0.f,0.f,0.f,0.f};
    #pragma unroll
    for(int d=0; d<4; ++d){
      float hv = (h[d]-mu)*rstd*lng[vi*256+lane*4+d] + lnb[vi*256+lane*4+d];
      hv = 0.5f*hv*(1.f + erff(hv*0.70710678118654752f));   // exact GELU
      #pragma unroll
      for(int o=0; o<4; ++o) po[o] += w2[(vi*4+o)*256 + lane*4 + d] * hv;
    }
    #pragma unroll
    for(int off=1; off<64; off<<=1){
      #pragma unroll
      for(int o=0; o<4; ++o) po[o] += __shfl_xor(po[o], off);
    }
    if(lane == 0){
      int tt = y & 1, hk = y >> 1;
      float rng = tt ? (5.f/127.f) : (5.f/15.f);
      float csc = tt ? 63.5f : 15.5f;
      #pragma unroll
      for(int d=0; d<4; ++d){
        int wk = xq*4 + d;
        float rv = refp[(size_t)(((b*3+vi)*16 + hk)*128 + wk)*2 + (1-tt)];  // [..., ::-1]
        float coord = tanhf(po[d])*rng + rv;
        size_t o2 = ((size_t)(vi*4+bg)*2048 + hk*128 + wk)*2 + tt;
        rwo[o2] = coord;
        rws[o2] = coord * csc;
      }
    }
  } else if(bx < 3840){
    int pb = bx - 3072;
    int iy = pb & 63;
    int o2 = pb >> 6;
    const float* src = x + ((size_t)o2*64)*4096 + (size_t)iy*64;
    int ix = threadIdx.x & 63, cq = threadIdx.x >> 6;
    #pragma unroll
    for(int c0 = 0; c0 < 64; c0 += 4)
      t[c0+cq][ix] = src[(size_t)(c0+cq)*4096 + ix];
    __syncthreads();
    float* dst = xt + (((size_t)o2*64 + iy)*64)*64;
    int c = threadIdx.x & 63, xq = threadIdx.x >> 6;
    #pragma unroll
    for(int x0 = 0; x0 < 64; x0 += 4)
      dst[(size_t)(x0+xq)*64 + c] = t[c][x0+xq];
  } else {
    int wb = bx - 3840;              // 320 = 64 kw16 + 64 vw16 + 192 ow_t
    if(wb < 128){
      int i = (wb & 63)*256 + threadIdx.x;
      if(wb < 64) kw16[i] = f2b(k_w[i]);
      else        vw16[i] = f2b(v_w[i]);
    } else {
      int i = (wb-128)*256 + threadIdx.x;
      if(i < 49152){
        int r = i / 384, c = i - r*384;
        ow_t[c*128 + r] = out_w[i];
      }
    }
  }
}

// ---------------------------------------------------------------- K1: fused sample + MFMA K/V projection
__global__ __launch_bounds__(256) void k_sampro(
    const float* __restrict__ rwo, const float* __restrict__ xt,
    const unsigned short* __restrict__ kw16, const float* __restrict__ k_b,
    const unsigned short* __restrict__ vw16, const float* __restrict__ v_b,
    unsigned short* __restrict__ k_b16, unsigned short* __restrict__ v_t16){
  __shared__ alignas(16) unsigned short tile[16*136];   // 4352 B bf16 xs tile
  int bx = blockIdx.x;               // 768 = (vi*2+b)*128 + nt
  int nt = bx & 127;
  int r2 = bx >> 7;
  int b = r2 & 1, vi = r2 >> 1;
  int n0 = nt*16;
  int tid = threadIdx.x, wid = tid>>6, lane = tid&63;
  #pragma unroll
  for(int s = 0; s < 8; ++s){        // 32 (n,g) units, 8 per wave
    int u = wid*8 + s;
    int nl = u >> 1, g = u & 1;
    int n = n0 + nl;
    float yn = rwo[((size_t)(vi*4 + b*2 + g)*2048 + n)*2 + 0];
    float xn = rwo[((size_t)(vi*4 + b*2 + g)*2048 + n)*2 + 1];
    float px = (xn + 1.f)*31.5f;
    float py = (yn + 1.f)*31.5f;
    float x0 = floorf(px), y0 = floorf(py);
    float fx = px - x0, fy = py - y0;
    int ix0 = (int)x0, iy0 = (int)y0;
    const float* base = xt + (size_t)((b*3+vi)*2+g)*4096*64;
    float wts[4] = {(1.f-fx)*(1.f-fy), fx*(1.f-fy), (1.f-fx)*fy, fx*fy};
    int ixs[4] = {ix0, ix0+1, ix0, ix0+1};
    int iys[4] = {iy0, iy0, iy0+1, iy0+1};
    float acc = 0.f;
    #pragma unroll
    for(int tp=0; tp<4; ++tp){
      int ix = ixs[tp], iy = iys[tp];
      if(ix>=0 && ix<64 && iy>=0 && iy<64)
        acc += wts[tp] * base[(size_t)((iy<<6)+ix)*64 + lane];
    }
    tile[nl*136 + g*64 + lane] = f2b(acc);
  }
  __syncthreads();
  // ---- MFMA projection: wave w -> heads {2w, 2w+1}, k + v tiles each
  int c = lane & 15, qd = lane >> 4;
  short8 af[4];                      // A[m=sample n=c][k=c-chan qd*8+j], 4 x K=32 = 128 ch
  #pragma unroll
  for(int kc=0; kc<4; ++kc)
    af[kc] = *(const short8*)(&tile[c*136 + kc*32 + qd*8]);
  size_t vbbase = (size_t)(vi*16 + b*8)*2048*16;
  const float SC2 = 0.36067376022224085f;     // 0.25 * log2(e), folded into K
  #pragma unroll
  for(int half=0; half<2; ++half){
    int nh = wid*2 + half;
    size_t hbase = vbbase + (size_t)nh*2048*16;
    {  // K head: k_b16[n][ch], pre-scaled by SC2
      f32x4 C = {0.f,0.f,0.f,0.f};
      #pragma unroll
      for(int kc=0; kc<4; ++kc){
        short8 bf = *(const short8*)(kw16 + (size_t)(nh*16 + c)*128 + kc*32 + qd*8);
        C = __builtin_amdgcn_mfma_f32_16x16x32_bf16(af[kc], bf, C, 0, 0, 0);
      }
      float bias = k_b[nh*16 + c];
      #pragma unroll
      for(int r=0; r<4; ++r)
        k_b16[hbase + (size_t)(n0 + qd*4 + r)*16 + c] = f2b((C[r] + bias)*SC2);
    }
    {  // V head: v_t16[ch][n], plain layout, vectorized uint2 store
      f32x4 C = {0.f,0.f,0.f,0.f};
      #pragma unroll
      for(int kc=0; kc<4; ++kc){
        short8 bf = *(const short8*)(vw16 + (size_t)(nh*16 + c)*128 + kc*32 + qd*8);
        C = __builtin_amdgcn_mfma_f32_16x16x32_bf16(af[kc], bf, C, 0, 0, 0);
      }
      float bias = v_b[nh*16 + c];
      uint2 pk;
      pk.x = cvt_pk_bf16(C[0]+bias, C[1]+bias);
      pk.y = cvt_pk_bf16(C[2]+bias, C[3]+bias);
      *(uint2*)(v_t16 + hbase + (size_t)c*2048 + n0 + qd*4) = pk;
    }
  }
}

// ---------------------------------------------------------------- K2: MFMA flash attention, 512 thr, x-half blocks, 3 blocks/CU,
//                                                                  per-kc pipelined (no pf/Sf arrays -> no spills)
__global__ __launch_bounds__(512,6) void k_attn(
    const float* __restrict__ rws, const unsigned short* __restrict__ k_b16,
    const unsigned short* __restrict__ v_t16, const float* __restrict__ query,
    const float* __restrict__ rpe, float* __restrict__ attn_pc){
  __shared__ unsigned P32[49*197];               // 38,612 B (lo, hi-lo) log2-scaled bf16 pairs
  __shared__ alignas(16) short p_sm[8][16*40];   // 10,240 B per-wave P^T buffer (reused as f32 merge buffer)
  int bx = blockIdx.x;            // 768 = vi*256 + bh*16 + mq*2 + h
  int vi = bx >> 8;
  int bh = (bx >> 4) & 15;
  int mq = (bx >> 1) & 7;         // m-quad: 4 consecutive grid rows
  int h  = bx & 1;                // x-half: m-cols [16h, 16h+16)
  int b = bh >> 3, nh = bh & 7, g = nh >> 2, bg = b*2 + g;
  int tid = threadIdx.x, wid = tid >> 6;
  int w4  = wid & 3;              // grid-row within the quad
  int nhf = wid >> 2;             // nc half: 0 -> nc 0..7, 1 -> nc 8..15
  int lane = tid & 63, c = lane & 15, qd = lane >> 4;
  int m0 = (mq*4 + w4)*32 + 16*h;
  int xoff = h*64;
  float gy0 = -1.f + (2.f/31.f)*(float)(mq*4);
  float pyL = 15.5f*(gy0 - 4.f/3.f) + 31.f - 0.01f;
  float pyH = 15.5f*(gy0 + 6.f/31.f + 4.f/3.f) + 31.f + 0.01f;
  int a  = max(-1, (int)floorf(pyL));
  int bb = min(63, (int)floorf(pyH));
  int iy_lo = max(a - 1, bb - 48);
  {
    const float* rt = rpe + (size_t)nh*16065;
    for(int e = tid; e < 49*197; e += 512){
      int rr = e / 197;
      int cc = e - rr*197;
      int iy = iy_lo + rr;
      int ix = cc - 1 + xoff;
      bool xv = (ix >= 0) && (ix <= 254);
      float lo = (xv && iy   >= 0 && iy   <= 62) ? rt[iy*255 + ix]     : 0.f;
      float hi = (xv && iy+1 >= 0 && iy+1 <= 62) ? rt[(iy+1)*255 + ix] : 0.f;
      P32[e] = cvt_pk_bf16(lo*1.44269504f, (hi - lo)*1.44269504f);
    }
  }
  short8 qa;
  #pragma unroll
  for(int j=0; j<8; ++j){
    int ch = qd*8 + j;
    qa[j] = (qd < 2) ? (short)f2b(query[(size_t)(b*128 + nh*16 + ch)*1024 + m0 + c]) : (short)0;
  }
  float Ax2[4];
  #pragma unroll
  for(int r=0; r<4; ++r){
    int mr = m0 + qd*4 + r;
    float gxr = -1.f + (2.f/31.f)*(mr & 31);
    Ax2[r] = 63.5f*gxr + 128.f;
  }
  // wave's 16 m-rows share one grid row -> y-side wave-uniform per sample
  float gyw = -1.f + (2.f/31.f)*(float)(m0 >> 5);
  float Ay  = 15.5f*gyw + 31.f - (float)iy_lo;
  float loC = fmaxf(-1.f - (float)iy_lo, 0.f);
  float hiC = fminf(63.f - (float)iy_lo, 47.f);
  float pxLo = (float)xoff, pxHi = (float)(xoff + 192);
  float si[4] = {0.f, 0.f, 0.f, 0.f};
  f32x4 O = {0.f, 0.f, 0.f, 0.f};
  size_t kvb  = (size_t)(vi*16 + bh)*2048*16;
  size_t rwsb = (size_t)(vi*4 + bg)*2048;
  short* pw = &p_sm[wid][0];
  const f32x4 z = {0.f,0.f,0.f,0.f};
  __syncthreads();
  for(int nc = nhf*8, ncE = nhf*8 + 8; nc < ncE; ++nc){
    int n0 = nc*128;
    const unsigned short* kb = k_b16 + kvb + (size_t)(n0 + c)*16 + qd*8;   // + t*256
    // ---- prologue: issue S-MFMAs for t=0,1
    f32x4 S0, S1, N0, N1;
    {
      short8 bk0 = {0,0,0,0,0,0,0,0}, bk1 = {0,0,0,0,0,0,0,0};
      if(qd < 2){ bk0 = *(const short8*)(kb); bk1 = *(const short8*)(kb + 256); }
      N0 = __builtin_amdgcn_mfma_f32_16x16x32_bf16(qa, bk0, z, 0, 0, 0);
      N1 = __builtin_amdgcn_mfma_f32_16x16x32_bf16(qa, bk1, z, 0, 0, 0);
    }
    #pragma unroll
    for(int kc=0; kc<4; ++kc){
      S0 = N0; S1 = N1;
      if(kc < 3){                      // one-ahead: issue S for t=2kc+2, 2kc+3
        short8 bk0 = {0,0,0,0,0,0,0,0}, bk1 = {0,0,0,0,0,0,0,0};
        if(qd < 2){ bk0 = *(const short8*)(kb + (2*kc+2)*256); bk1 = *(const short8*)(kb + (2*kc+3)*256); }
        N0 = __builtin_amdgcn_mfma_f32_16x16x32_bf16(qa, bk0, z, 0, 0, 0);
        N1 = __builtin_amdgcn_mfma_f32_16x16x32_bf16(qa, bk1, z, 0, 0, 0);
      }
      // ---- bias + exp for t=2kc (S0) and t=2kc+1 (S1)
      float pe[4], po[4];
      {
        float2 rs = *(const float2*)(rws + (rwsb + n0 + (2*kc)*16 + c)*2);
        float py = Ay - rs.x;
        py = fminf(fmaxf(py, loC), hiC);
        float rf = floorf(py);
        float fy = py - rf;
        int rbase = (int)rf * 197;
        #pragma unroll
        for(int r=0; r<4; ++r){
          float px = Ax2[r] - rs.y;
          px = fminf(fmaxf(px, pxLo), pxHi);
          float cf = floorf(px);
          float fx = px - cf;
          int idx = rbase + (int)cf + 1 - xoff;
          unsigned w0 = P32[idx], w1 = P32[idx+1];
          float lo0 = __uint_as_float(w0 << 16), d0 = __uint_as_float(w0 & 0xFFFF0000u);
          float lo1 = __uint_as_float(w1 << 16), d1 = __uint_as_float(w1 & 0xFFFF0000u);
          float t0 = lo0 + fy*d0;
          float t1 = lo1 + fy*d1;
          float p = exp2f(S0[r] + t0 + fx*(t1 - t0));   // K pre-scaled by 0.25*log2e
          si[r] += p;
          pe[r] = p;
        }
      }
      {
        float2 rs = *(const float2*)(rws + (rwsb + n0 + (2*kc+1)*16 + c)*2);
        float py = Ay - rs.x;
        py = fminf(fmaxf(py, loC), hiC);
        float rf = floorf(py);
        float fy = py - rf;
        int rbase = (int)rf * 197;
        #pragma unroll
        for(int r=0; r<4; ++r){
          float px = Ax2[r] - rs.y;
          px = fminf(fmaxf(px, pxLo), pxHi);
          float cf = floorf(px);
          float fx = px - cf;
          int idx = rbase + (int)cf + 1 - xoff;
          unsigned w0 = P32[idx], w1 = P32[idx+1];
          float lo0 = __uint_as_float(w0 << 16), d0 = __uint_as_float(w0 & 0xFFFF0000u);
          float lo1 = __uint_as_float(w1 << 16), d1 = __uint_as_float(w1 & 0xFFFF0000u);
          float t0 = lo0 + fy*d0;
          float t1 = lo1 + fy*d1;
          float p = exp2f(S1[r] + t0 + fx*(t1 - t0));
          si[r] += p;
          po[r] = p;
        }
      }
      // ---- pack P^T into per-wave LDS, then PV MFMA for this kc
      #pragma unroll
      for(int r=0; r<4; ++r){
        unsigned pk = cvt_pk_bf16(pe[r], po[r]);
        pw[(qd*4 + r)*40 + c]      = (short)pk;
        pw[(qd*4 + r)*40 + 16 + c] = (short)(pk >> 16);
      }
      short8 va = *(const short8*)(v_t16 + kvb + (size_t)c*2048 + n0 + kc*32 + qd*8);
      short8 pbf = *(const short8*)(&pw[c*40 + qd*8]);
      O = __builtin_amdgcn_mfma_f32_16x16x32_bf16(va, pbf, O, 0, 0, 0);
    }
  }
  // ---- merge the two nc halves via LDS (reuse p_sm block as f32 buffer)
  __syncthreads();
  float* red = (float*)&p_sm[0][0];
  int basei = (w4*64 + lane)*8;
  if(nhf){
    red[basei+0] = O[0];  red[basei+1] = O[1];
    red[basei+2] = O[2];  red[basei+3] = O[3];
    red[basei+4] = si[0]; red[basei+5] = si[1];
    red[basei+6] = si[2]; red[basei+7] = si[3];
  }
  __syncthreads();
  if(!nhf){
    O[0] += red[basei+0]; O[1] += red[basei+1];
    O[2] += red[basei+2]; O[3] += red[basei+3];
    si[0] += red[basei+4]; si[1] += red[basei+5];
    si[2] += red[basei+6]; si[3] += red[basei+7];
    #pragma unroll
    for(int r=0; r<4; ++r){
      float sv = si[r];
      sv += __shfl_xor(sv, 1); sv += __shfl_xor(sv, 2);
      sv += __shfl_xor(sv, 4); sv += __shfl_xor(sv, 8);
      si[r] = sv;
    }
    int msrc = (c >> 2)*16 + c;
    int rsel = c & 3;
    float s0 = __shfl(si[0], msrc), s1 = __shfl(si[1], msrc),
          s2 = __shfl(si[2], msrc), s3 = __shfl(si[3], msrc);
    float sv = (rsel==0) ? s0 : ((rsel==1) ? s1 : ((rsel==2) ? s2 : s3));
    float inv = 1.f/sv;
    float4 o4;
    o4.x = O[0]*inv; o4.y = O[1]*inv; o4.z = O[2]*inv; o4.w = O[3]*inv;
    *(float4*)(attn_pc + (size_t)(b*1024 + m0 + c)*384 + vi*128 + nh*16 + qd*4) = o4;
  }
}

// ---------------------------------------------------------------- K3: output projection (512 blocks, 4 m-rows each)
__global__ __launch_bounds__(256) void k_outproj(
    const float* __restrict__ attn_pc, const float* __restrict__ ow_t, const float* __restrict__ out_b,
    float* __restrict__ out){
  __shared__ float A[4*384];         // 6 KB
  int bx = blockIdx.x;               // 512 = b*256 + mt
  int b  = bx >> 8;
  int m0 = (bx & 255)*4;
  const float4* src = (const float4*)(attn_pc + ((size_t)b*1024 + m0)*384);
  float4* dst = (float4*)A;
  for(int i = threadIdx.x; i < 384; i += 256) dst[i] = src[i];
  __syncthreads();
  int oc = threadIdx.x & 127;
  int mh = threadIdx.x >> 7;         // 0..1, each handles 2 m-rows
  float acc[2] = {0.f,0.f};
  #pragma unroll 4
  for(int vc = 0; vc < 384; ++vc){
    float wv = ow_t[vc*128 + oc];
    #pragma unroll
    for(int j=0; j<2; ++j) acc[j] += wv * A[(mh*2+j)*384 + vc];
  }
  float ob = out_b[oc];
  #pragma unroll
  for(int j=0; j<2; ++j)
    out[((size_t)b*128 + oc)*1024 + m0 + mh*2 + j] = acc[j] + ob;
}

extern "C" void kernel_launch(void* const* d_in, const int* in_sizes, int n_in,
                              void* d_out, int out_size, void* d_ws, size_t ws_size,
                              hipStream_t stream){
  const float* x     = (const float*)d_in[0];
  const float* query = (const float*)d_in[1];
  const float* refp  = (const float*)d_in[2];
  const float* w1    = (const float*)d_in[3];
  const float* b1    = (const float*)d_in[4];
  const float* lng   = (const float*)d_in[5];
  const float* lnb   = (const float*)d_in[6];
  const float* w2    = (const float*)d_in[7];
  const float* k_w   = (const float*)d_in[8];
  const float* k_b   = (const float*)d_in[9];
  const float* v_w   = (const float*)d_in[10];
  const float* v_b   = (const float*)d_in[11];
  const float* out_w = (const float*)d_in[12];
  const float* out_b = (const float*)d_in[13];
  const float* rpe   = (const float*)d_in[14];

  const size_t O_XT   = 0;            // 12,582,912
  const size_t O_RWO  = 12582912;     //    196,608
  const size_t O_RWS  = 12779520;     //    196,608
  const size_t O_KB16 = 12976128;     //  3,145,728
  const size_t O_VT16 = 16121856;     //  3,145,728
  const size_t O_APC  = 19267584;     //  3,145,728
  const size_t O_KW16 = 22413312;     //     32,768
  const size_t O_VW16 = 22446080;     //     32,768
  const size_t O_OWT  = 22478848;     //    196,608
  const size_t NEED   = 22675456;
  if(ws_size < NEED){
    k_probe<<<1, 64, 0, stream>>>((float*)d_out, 100.f + (float)(ws_size >> 20));
    return;
  }
  char* ws = (char*)d_ws;
  float* xt      = (float*)(ws + O_XT);
  float* rwo     = (float*)(ws + O_RWO);
  float* rws     = (float*)(ws + O_RWS);
  unsigned short* k_b16 = (unsigned short*)(ws + O_KB16);
  unsigned short* v_t16 = (unsigned short*)(ws + O_VT16);
  float* attn_pc = (float*)(ws + O_APC);
  unsigned short* kw16 = (unsigned short*)(ws + O_KW16);
  unsigned short* vw16 = (unsigned short*)(ws + O_VW16);
  float* ow_t    = (float*)(ws + O_OWT);

  k_prep_off<<<4160, 256, 0, stream>>>(query, refp, w1, b1, lng, lnb, w2, rwo, rws,
                                       x, xt, k_w, v_w, out_w, kw16, vw16, ow_t);
  k_sampro  <<<768,  256, 0, stream>>>(rwo, xt, kw16, k_b, vw16, v_b, k_b16, v_t16);
  k_attn    <<<768,  512, 0, stream>>>(rws, k_b16, v_t16, query, rpe, attn_pc);
  k_outproj <<<512,  256, 0, stream>>>(attn_pc, ow_t, out_b, (float*)d_out);
}

// Round 7
// 240.266 us; speedup vs baseline: 1.1340x; 1.0361x over previous
//
#include <hip/hip_runtime.h>
#include <hip/hip_bf16.h>
#include <math.h>

// B=2 V=3 G=2 NH=8 C=128 CPG=64 CH=16 HPG=4 Hq=Wq=32 D=4 Hk=16 Wk=128 NS=2048
// Hi=Wi=64 SCALE=0.25 OFR=5 EPS=1e-5  RPE 63x255 per head
// All inputs fp32, output fp32 (established R2-R6).
// R20 = R19 with:
//   - k_attn spill finished off: no explicit one-ahead prefetch (both S-MFMAs
//     issue at top of kc body; the ~60 S-independent bias VALU ops that follow
//     hide their latency; -8 live VGPR), bias computed S-free then 8 exp2s.
//     xoff folded into Ax2. Live state ~60 < 85-reg cap at 6 waves/SIMD.
//   - k_sampro TLP doubled: 512-thread blocks, 8 waves, wave w owns head w
//     (K+V, 8 MFMA); sampling 4 units/wave. 24 waves/CU (was 12) to cover the
//     scattered xt gather latency. Same work, same LDS tile, same stores.

typedef __attribute__((ext_vector_type(8))) short short8;
typedef __attribute__((ext_vector_type(4))) float f32x4;

__device__ __forceinline__ unsigned short f2b(float f){        // fp32 -> bf16 RNE
  unsigned u = __float_as_uint(f);
  return (unsigned short)((u + 0x7FFFu + ((u>>16)&1u)) >> 16);
}
__device__ __forceinline__ unsigned cvt_pk_bf16(float lo, float hi){  // HW RNE pair-convert
  unsigned r;
  asm("v_cvt_pk_bf16_f32 %0, %1, %2" : "=v"(r) : "v"(lo), "v"(hi));
  return r;
}

__global__ void k_probe(float* __restrict__ out, float code){
  if(blockIdx.x==0 && threadIdx.x==0) out[0] = code;
}

// ---------------------------------------------------------------- K0: offsets (3072) + x-transpose (768) + weight prep (320)
__global__ __launch_bounds__(256) void k_prep_off(
    const float* __restrict__ query, const float* __restrict__ refp,
    const float* __restrict__ w1, const float* __restrict__ b1,
    const float* __restrict__ lng, const float* __restrict__ lnb,
    const float* __restrict__ w2, float* __restrict__ rwo, float* __restrict__ rws,
    const float* __restrict__ x, float* __restrict__ xt,
    const float* __restrict__ k_w, const float* __restrict__ v_w, const float* __restrict__ out_w,
    unsigned short* __restrict__ kw16, unsigned short* __restrict__ vw16, float* __restrict__ ow_t){
  __shared__ float t[64][65];
  int bx = blockIdx.x;               // 4160 = 3072 offsets + 768 transpose + 320 wprep
  if(bx < 3072){
    int wid  = bx*4 + (threadIdx.x>>6);
    int lane = threadIdx.x & 63;
    int vi  = wid >> 12;
    int rem = wid & 4095;
    int bg  = rem >> 10;
    int pix = rem & 1023;
    int y = pix >> 5, xq = pix & 31;
    int b = bg >> 1, g = bg & 1;
    float qv = query[(size_t)(b*128 + g*64 + lane)*1024 + pix];
    float h[4]; float s1 = 0.f, s2 = 0.f;
    #pragma unroll
    for(int d=0; d<4; ++d){
      h[d] = qv*w1[vi*256 + lane*4 + d] + b1[vi*256 + lane*4 + d];
      s1 += h[d]; s2 += h[d]*h[d];
    }
    #pragma unroll
    for(int off=1; off<64; off<<=1){ s1 += __shfl_xor(s1, off); s2 += __shfl_xor(s2, off); }
    float mu   = s1 * (1.f/256.f);
    float var  = s2 * (1.f/256.f) - mu*mu;
    float rstd = rsqrtf(fmaxf(var, 0.f) + 1e-5f);
    float po[4] = {0.f,0.f,0.f,0.f};
    #pragma unroll
    for(int d=0; d<4; ++d){
      float hv = (h[d]-mu)*rstd*lng[vi*256+lane*4+d] + lnb[vi*256+lane*4+d];
      hv = 0.5f*hv*(1.f + erff(hv*0.70710678118654752f));   // exact GELU
      #pragma unroll
      for(int o=0; o<4; ++o) po[o] += w2[(vi*4+o)*256 + lane*4 + d] * hv;
    }
    #pragma unroll
    for(int off=1; off<64; off<<=1){
      #pragma unroll
      for(int o=0; o<4; ++o) po[o] += __shfl_xor(po[o], off);
    }
    if(lane == 0){
      int tt = y & 1, hk = y >> 1;
      float rng = tt ? (5.f/127.f) : (5.f/15.f);
      float csc = tt ? 63.5f : 15.5f;
      #pragma unroll
      for(int d=0; d<4; ++d){
        int wk = xq*4 + d;
        float rv = refp[(size_t)(((b*3+vi)*16 + hk)*128 + wk)*2 + (1-tt)];  // [..., ::-1]
        float coord = tanhf(po[d])*rng + rv;
        size_t o2 = ((size_t)(vi*4+bg)*2048 + hk*128 + wk)*2 + tt;
        rwo[o2] = coord;
        rws[o2] = coord * csc;
      }
    }
  } else if(bx < 3840){
    int pb = bx - 3072;
    int iy = pb & 63;
    int o2 = pb >> 6;
    const float* src = x + ((size_t)o2*64)*4096 + (size_t)iy*64;
    int ix = threadIdx.x & 63, cq = threadIdx.x >> 6;
    #pragma unroll
    for(int c0 = 0; c0 < 64; c0 += 4)
      t[c0+cq][ix] = src[(size_t)(c0+cq)*4096 + ix];
    __syncthreads();
    float* dst = xt + (((size_t)o2*64 + iy)*64)*64;
    int c = threadIdx.x & 63, xq = threadIdx.x >> 6;
    #pragma unroll
    for(int x0 = 0; x0 < 64; x0 += 4)
      dst[(size_t)(x0+xq)*64 + c] = t[c][x0+xq];
  } else {
    int wb = bx - 3840;              // 320 = 64 kw16 + 64 vw16 + 192 ow_t
    if(wb < 128){
      int i = (wb & 63)*256 + threadIdx.x;
      if(wb < 64) kw16[i] = f2b(k_w[i]);
      else        vw16[i] = f2b(v_w[i]);
    } else {
      int i = (wb-128)*256 + threadIdx.x;
      if(i < 49152){
        int r = i / 384, c = i - r*384;
        ow_t[c*128 + r] = out_w[i];
      }
    }
  }
}

// ---------------------------------------------------------------- K1: fused sample + MFMA K/V projection, 8 waves (1 head/wave)
__global__ __launch_bounds__(512) void k_sampro(
    const float* __restrict__ rwo, const float* __restrict__ xt,
    const unsigned short* __restrict__ kw16, const float* __restrict__ k_b,
    const unsigned short* __restrict__ vw16, const float* __restrict__ v_b,
    unsigned short* __restrict__ k_b16, unsigned short* __restrict__ v_t16){
  __shared__ alignas(16) unsigned short tile[16*136];   // 4352 B bf16 xs tile
  int bx = blockIdx.x;               // 768 = (vi*2+b)*128 + nt
  int nt = bx & 127;
  int r2 = bx >> 7;
  int b = r2 & 1, vi = r2 >> 1;
  int n0 = nt*16;
  int tid = threadIdx.x, wid = tid>>6, lane = tid&63;
  #pragma unroll
  for(int s = 0; s < 4; ++s){        // 32 (n,g) units, 4 per wave
    int u = wid*4 + s;
    int nl = u >> 1, g = u & 1;
    int n = n0 + nl;
    float yn = rwo[((size_t)(vi*4 + b*2 + g)*2048 + n)*2 + 0];
    float xn = rwo[((size_t)(vi*4 + b*2 + g)*2048 + n)*2 + 1];
    float px = (xn + 1.f)*31.5f;
    float py = (yn + 1.f)*31.5f;
    float x0 = floorf(px), y0 = floorf(py);
    float fx = px - x0, fy = py - y0;
    int ix0 = (int)x0, iy0 = (int)y0;
    const float* base = xt + (size_t)((b*3+vi)*2+g)*4096*64;
    float wts[4] = {(1.f-fx)*(1.f-fy), fx*(1.f-fy), (1.f-fx)*fy, fx*fy};
    int ixs[4] = {ix0, ix0+1, ix0, ix0+1};
    int iys[4] = {iy0, iy0, iy0+1, iy0+1};
    float acc = 0.f;
    #pragma unroll
    for(int tp=0; tp<4; ++tp){
      int ix = ixs[tp], iy = iys[tp];
      if(ix>=0 && ix<64 && iy>=0 && iy<64)
        acc += wts[tp] * base[(size_t)((iy<<6)+ix)*64 + lane];
    }
    tile[nl*136 + g*64 + lane] = f2b(acc);
  }
  __syncthreads();
  // ---- MFMA projection: wave w -> head w, K + V tiles
  int c = lane & 15, qd = lane >> 4;
  short8 af[4];                      // A[m=sample n=c][k=c-chan qd*8+j], 4 x K=32 = 128 ch
  #pragma unroll
  for(int kc=0; kc<4; ++kc)
    af[kc] = *(const short8*)(&tile[c*136 + kc*32 + qd*8]);
  size_t vbbase = (size_t)(vi*16 + b*8)*2048*16;
  const float SC2 = 0.36067376022224085f;     // 0.25 * log2(e), folded into K
  int nh = wid;
  size_t hbase = vbbase + (size_t)nh*2048*16;
  {  // K head: k_b16[n][ch], pre-scaled by SC2
    f32x4 C = {0.f,0.f,0.f,0.f};
    #pragma unroll
    for(int kc=0; kc<4; ++kc){
      short8 bf = *(const short8*)(kw16 + (size_t)(nh*16 + c)*128 + kc*32 + qd*8);
      C = __builtin_amdgcn_mfma_f32_16x16x32_bf16(af[kc], bf, C, 0, 0, 0);
    }
    float bias = k_b[nh*16 + c];
    #pragma unroll
    for(int r=0; r<4; ++r)
      k_b16[hbase + (size_t)(n0 + qd*4 + r)*16 + c] = f2b((C[r] + bias)*SC2);
  }
  {  // V head: v_t16[ch][n], plain layout, vectorized uint2 store
    f32x4 C = {0.f,0.f,0.f,0.f};
    #pragma unroll
    for(int kc=0; kc<4; ++kc){
      short8 bf = *(const short8*)(vw16 + (size_t)(nh*16 + c)*128 + kc*32 + qd*8);
      C = __builtin_amdgcn_mfma_f32_16x16x32_bf16(af[kc], bf, C, 0, 0, 0);
    }
    float bias = v_b[nh*16 + c];
    uint2 pk;
    pk.x = cvt_pk_bf16(C[0]+bias, C[1]+bias);
    pk.y = cvt_pk_bf16(C[2]+bias, C[3]+bias);
    *(uint2*)(v_t16 + hbase + (size_t)c*2048 + n0 + qd*4) = pk;
  }
}

// ---------------------------------------------------------------- K2: MFMA flash attention, 512 thr, x-half blocks, 3 blocks/CU,
//                                                                  per-kc, bias-before-S (no prefetch regs, no spill)
__global__ __launch_bounds__(512,6) void k_attn(
    const float* __restrict__ rws, const unsigned short* __restrict__ k_b16,
    const unsigned short* __restrict__ v_t16, const float* __restrict__ query,
    const float* __restrict__ rpe, float* __restrict__ attn_pc){
  __shared__ unsigned P32[49*197];               // 38,612 B (lo, hi-lo) log2-scaled bf16 pairs
  __shared__ alignas(16) short p_sm[8][16*40];   // 10,240 B per-wave P^T buffer (reused as f32 merge buffer)
  int bx = blockIdx.x;            // 768 = vi*256 + bh*16 + mq*2 + h
  int vi = bx >> 8;
  int bh = (bx >> 4) & 15;
  int mq = (bx >> 1) & 7;         // m-quad: 4 consecutive grid rows
  int h  = bx & 1;                // x-half: m-cols [16h, 16h+16)
  int b = bh >> 3, nh = bh & 7, g = nh >> 2, bg = b*2 + g;
  int tid = threadIdx.x, wid = tid >> 6;
  int w4  = wid & 3;              // grid-row within the quad
  int nhf = wid >> 2;             // nc half: 0 -> nc 0..7, 1 -> nc 8..15
  int lane = tid & 63, c = lane & 15, qd = lane >> 4;
  int m0 = (mq*4 + w4)*32 + 16*h;
  int xoff = h*64;
  float gy0 = -1.f + (2.f/31.f)*(float)(mq*4);
  float pyL = 15.5f*(gy0 - 4.f/3.f) + 31.f - 0.01f;
  float pyH = 15.5f*(gy0 + 6.f/31.f + 4.f/3.f) + 31.f + 0.01f;
  int a  = max(-1, (int)floorf(pyL));
  int bb = min(63, (int)floorf(pyH));
  int iy_lo = max(a - 1, bb - 48);
  {
    const float* rt = rpe + (size_t)nh*16065;
    for(int e = tid; e < 49*197; e += 512){
      int rr = e / 197;
      int cc = e - rr*197;
      int iy = iy_lo + rr;
      int ix = cc - 1 + xoff;
      bool xv = (ix >= 0) && (ix <= 254);
      float lo = (xv && iy   >= 0 && iy   <= 62) ? rt[iy*255 + ix]     : 0.f;
      float hi = (xv && iy+1 >= 0 && iy+1 <= 62) ? rt[(iy+1)*255 + ix] : 0.f;
      P32[e] = cvt_pk_bf16(lo*1.44269504f, (hi - lo)*1.44269504f);
    }
  }
  short8 qa;
  #pragma unroll
  for(int j=0; j<8; ++j){
    int ch = qd*8 + j;
    qa[j] = (qd < 2) ? (short)f2b(query[(size_t)(b*128 + nh*16 + ch)*1024 + m0 + c]) : (short)0;
  }
  float Ax2[4];                    // xoff folded in: px is window-local
  #pragma unroll
  for(int r=0; r<4; ++r){
    int mr = m0 + qd*4 + r;
    float gxr = -1.f + (2.f/31.f)*(mr & 31);
    Ax2[r] = 63.5f*gxr + 128.f - (float)xoff;
  }
  // wave's 16 m-rows share one grid row -> y-side wave-uniform per sample
  float gyw = -1.f + (2.f/31.f)*(float)(m0 >> 5);
  float Ay  = 15.5f*gyw + 31.f - (float)iy_lo;
  float loC = fmaxf(-1.f - (float)iy_lo, 0.f);
  float hiC = fminf(63.f - (float)iy_lo, 47.f);
  float si[4] = {0.f, 0.f, 0.f, 0.f};
  f32x4 O = {0.f, 0.f, 0.f, 0.f};
  size_t kvb  = (size_t)(vi*16 + bh)*2048*16;
  size_t rwsb = (size_t)(vi*4 + bg)*2048;
  short* pw = &p_sm[wid][0];
  const f32x4 z = {0.f,0.f,0.f,0.f};
  __syncthreads();
  for(int nc = nhf*8, ncE = nhf*8 + 8; nc < ncE; ++nc){
    int n0 = nc*128;
    const unsigned short* kb = k_b16 + kvb + (size_t)(n0 + c)*16 + qd*8;   // + t*256
    #pragma unroll
    for(int kc=0; kc<4; ++kc){
      // ---- issue both S-MFMAs for this kc first; bias math below is
      //      S-independent and hides their latency (no prefetch regs needed)
      short8 bk0 = {0,0,0,0,0,0,0,0}, bk1 = {0,0,0,0,0,0,0,0};
      if(qd < 2){ bk0 = *(const short8*)(kb + (2*kc)*256); bk1 = *(const short8*)(kb + (2*kc+1)*256); }
      f32x4 S0 = __builtin_amdgcn_mfma_f32_16x16x32_bf16(qa, bk0, z, 0, 0, 0);
      f32x4 S1 = __builtin_amdgcn_mfma_f32_16x16x32_bf16(qa, bk1, z, 0, 0, 0);
      // ---- S-free bias values for t=2kc, 2kc+1
      float be[4], bo[4];
      {
        float2 rs = *(const float2*)(rws + (rwsb + n0 + (2*kc)*16 + c)*2);
        float py = Ay - rs.x;
        py = fminf(fmaxf(py, loC), hiC);
        float rf = floorf(py);
        float fy = py - rf;
        int rbase = (int)rf * 197 + 1;
        #pragma unroll
        for(int r=0; r<4; ++r){
          float px = Ax2[r] - rs.y;
          px = fminf(fmaxf(px, 0.f), 192.f);
          float cf = floorf(px);
          float fx = px - cf;
          int idx = rbase + (int)cf;
          unsigned w0 = P32[idx], w1 = P32[idx+1];
          float lo0 = __uint_as_float(w0 << 16), d0 = __uint_as_float(w0 & 0xFFFF0000u);
          float lo1 = __uint_as_float(w1 << 16), d1 = __uint_as_float(w1 & 0xFFFF0000u);
          float t0 = lo0 + fy*d0;
          float t1 = lo1 + fy*d1;
          be[r] = t0 + fx*(t1 - t0);
        }
      }
      {
        float2 rs = *(const float2*)(rws + (rwsb + n0 + (2*kc+1)*16 + c)*2);
        float py = Ay - rs.x;
        py = fminf(fmaxf(py, loC), hiC);
        float rf = floorf(py);
        float fy = py - rf;
        int rbase = (int)rf * 197 + 1;
        #pragma unroll
        for(int r=0; r<4; ++r){
          float px = Ax2[r] - rs.y;
          px = fminf(fmaxf(px, 0.f), 192.f);
          float cf = floorf(px);
          float fx = px - cf;
          int idx = rbase + (int)cf;
          unsigned w0 = P32[idx], w1 = P32[idx+1];
          float lo0 = __uint_as_float(w0 << 16), d0 = __uint_as_float(w0 & 0xFFFF0000u);
          float lo1 = __uint_as_float(w1 << 16), d1 = __uint_as_float(w1 & 0xFFFF0000u);
          float t0 = lo0 + fy*d0;
          float t1 = lo1 + fy*d1;
          bo[r] = t0 + fx*(t1 - t0);
        }
      }
      // ---- exp2 with S (K pre-scaled by 0.25*log2e), accumulate si, pack P^T
      float pe[4], po[4];
      #pragma unroll
      for(int r=0; r<4; ++r){ pe[r] = exp2f(S0[r] + be[r]); si[r] += pe[r]; }
      #pragma unroll
      for(int r=0; r<4; ++r){ po[r] = exp2f(S1[r] + bo[r]); si[r] += po[r]; }
      #pragma unroll
      for(int r=0; r<4; ++r){
        unsigned pk = cvt_pk_bf16(pe[r], po[r]);
        pw[(qd*4 + r)*40 + c]      = (short)pk;
        pw[(qd*4 + r)*40 + 16 + c] = (short)(pk >> 16);
      }
      short8 va = *(const short8*)(v_t16 + kvb + (size_t)c*2048 + n0 + kc*32 + qd*8);
      short8 pbf = *(const short8*)(&pw[c*40 + qd*8]);
      O = __builtin_amdgcn_mfma_f32_16x16x32_bf16(va, pbf, O, 0, 0, 0);
    }
  }
  // ---- merge the two nc halves via LDS (reuse p_sm block as f32 buffer)
  __syncthreads();
  float* red = (float*)&p_sm[0][0];
  int basei = (w4*64 + lane)*8;
  if(nhf){
    red[basei+0] = O[0];  red[basei+1] = O[1];
    red[basei+2] = O[2];  red[basei+3] = O[3];
    red[basei+4] = si[0]; red[basei+5] = si[1];
    red[basei+6] = si[2]; red[basei+7] = si[3];
  }
  __syncthreads();
  if(!nhf){
    O[0] += red[basei+0]; O[1] += red[basei+1];
    O[2] += red[basei+2]; O[3] += red[basei+3];
    si[0] += red[basei+4]; si[1] += red[basei+5];
    si[2] += red[basei+6]; si[3] += red[basei+7];
    #pragma unroll
    for(int r=0; r<4; ++r){
      float sv = si[r];
      sv += __shfl_xor(sv, 1); sv += __shfl_xor(sv, 2);
      sv += __shfl_xor(sv, 4); sv += __shfl_xor(sv, 8);
      si[r] = sv;
    }
    int msrc = (c >> 2)*16 + c;
    int rsel = c & 3;
    float s0 = __shfl(si[0], msrc), s1 = __shfl(si[1], msrc),
          s2 = __shfl(si[2], msrc), s3 = __shfl(si[3], msrc);
    float sv = (rsel==0) ? s0 : ((rsel==1) ? s1 : ((rsel==2) ? s2 : s3));
    float inv = 1.f/sv;
    float4 o4;
    o4.x = O[0]*inv; o4.y = O[1]*inv; o4.z = O[2]*inv; o4.w = O[3]*inv;
    *(float4*)(attn_pc + (size_t)(b*1024 + m0 + c)*384 + vi*128 + nh*16 + qd*4) = o4;
  }
}

// ---------------------------------------------------------------- K3: output projection (512 blocks, 4 m-rows each)
__global__ __launch_bounds__(256) void k_outproj(
    const float* __restrict__ attn_pc, const float* __restrict__ ow_t, const float* __restrict__ out_b,
    float* __restrict__ out){
  __shared__ float A[4*384];         // 6 KB
  int bx = blockIdx.x;               // 512 = b*256 + mt
  int b  = bx >> 8;
  int m0 = (bx & 255)*4;
  const float4* src = (const float4*)(attn_pc + ((size_t)b*1024 + m0)*384);
  float4* dst = (float4*)A;
  for(int i = threadIdx.x; i < 384; i += 256) dst[i] = src[i];
  __syncthreads();
  int oc = threadIdx.x & 127;
  int mh = threadIdx.x >> 7;         // 0..1, each handles 2 m-rows
  float acc[2] = {0.f,0.f};
  #pragma unroll 4
  for(int vc = 0; vc < 384; ++vc){
    float wv = ow_t[vc*128 + oc];
    #pragma unroll
    for(int j=0; j<2; ++j) acc[j] += wv * A[(mh*2+j)*384 + vc];
  }
  float ob = out_b[oc];
  #pragma unroll
  for(int j=0; j<2; ++j)
    out[((size_t)b*128 + oc)*1024 + m0 + mh*2 + j] = acc[j] + ob;
}

extern "C" void kernel_launch(void* const* d_in, const int* in_sizes, int n_in,
                              void* d_out, int out_size, void* d_ws, size_t ws_size,
                              hipStream_t stream){
  const float* x     = (const float*)d_in[0];
  const float* query = (const float*)d_in[1];
  const float* refp  = (const float*)d_in[2];
  const float* w1    = (const float*)d_in[3];
  const float* b1    = (const float*)d_in[4];
  const float* lng   = (const float*)d_in[5];
  const float* lnb   = (const float*)d_in[6];
  const float* w2    = (const float*)d_in[7];
  const float* k_w   = (const float*)d_in[8];
  const float* k_b   = (const float*)d_in[9];
  const float* v_w   = (const float*)d_in[10];
  const float* v_b   = (const float*)d_in[11];
  const float* out_w = (const float*)d_in[12];
  const float* out_b = (const float*)d_in[13];
  const float* rpe   = (const float*)d_in[14];

  const size_t O_XT   = 0;            // 12,582,912
  const size_t O_RWO  = 12582912;     //    196,608
  const size_t O_RWS  = 12779520;     //    196,608
  const size_t O_KB16 = 12976128;     //  3,145,728
  const size_t O_VT16 = 16121856;     //  3,145,728
  const size_t O_APC  = 19267584;     //  3,145,728
  const size_t O_KW16 = 22413312;     //     32,768
  const size_t O_VW16 = 22446080;     //     32,768
  const size_t O_OWT  = 22478848;     //    196,608
  const size_t NEED   = 22675456;
  if(ws_size < NEED){
    k_probe<<<1, 64, 0, stream>>>((float*)d_out, 100.f + (float)(ws_size >> 20));
    return;
  }
  char* ws = (char*)d_ws;
  float* xt      = (float*)(ws + O_XT);
  float* rwo     = (float*)(ws + O_RWO);
  float* rws     = (float*)(ws + O_RWS);
  unsigned short* k_b16 = (unsigned short*)(ws + O_KB16);
  unsigned short* v_t16 = (unsigned short*)(ws + O_VT16);
  float* attn_pc = (float*)(ws + O_APC);
  unsigned short* kw16 = (unsigned short*)(ws + O_KW16);
  unsigned short* vw16 = (unsigned short*)(ws + O_VW16);
  float* ow_t    = (float*)(ws + O_OWT);

  k_prep_off<<<4160, 256, 0, stream>>>(query, refp, w1, b1, lng, lnb, w2, rwo, rws,
                                       x, xt, k_w, v_w, out_w, kw16, vw16, ow_t);
  k_sampro  <<<768,  512, 0, stream>>>(rwo, xt, kw16, k_b, vw16, v_b, k_b16, v_t16);
  k_attn    <<<768,  512, 0, stream>>>(rws, k_b16, v_t16, query, rpe, attn_pc);
  k_outproj <<<512,  256, 0, stream>>>(attn_pc, ow_t, out_b, (float*)d_out);
}

// Round 8
// 236.060 us; speedup vs baseline: 1.1542x; 1.0178x over previous
//
#include <hip/hip_runtime.h>
#include <hip/hip_bf16.h>
#include <math.h>

// B=2 V=3 G=2 NH=8 C=128 CPG=64 CH=16 HPG=4 Hq=Wq=32 D=4 Hk=16 Wk=128 NS=2048
// Hi=Wi=64 SCALE=0.25 OFR=5 EPS=1e-5  RPE 63x255 per head
// All inputs fp32, output fp32 (established R2-R6).
// R21 = R20 with k_attn QK^T switched to the K=16 MFMA (v_mfma_f32_16x16x16_bf16):
//   CH=16, so the old 16x16x32 path zero-padded half of every operand (qa 4 VGPR
//   half-zero, bk 16B loads half-zero, if(qd<2) exec churn) — and still spilled
//   (R20: VGPR 40 + ~17MB scratch WRITE_SIZE). K=16 operands are 2 VGPRs each,
//   all 64 lanes carry real data (ch = qd*4+j), loads are 8B, no conditionals.
//   Summing 16 real + 16 zero fp32 products == summing 16 real -> bit-identical.
//   Guarded by __has_builtin; fallback = proven 32-wide path.
// Everything else identical to R20.

typedef __attribute__((ext_vector_type(8))) short short8;
typedef __attribute__((ext_vector_type(4))) short short4v;
typedef __attribute__((ext_vector_type(4))) float f32x4;

#if __has_builtin(__builtin_amdgcn_mfma_f32_16x16x16_bf16)
  #define MFMA16(a,b,c) __builtin_amdgcn_mfma_f32_16x16x16_bf16((a),(b),(c),0,0,0)
  #define HAVE_MFMA16 1
#elif __has_builtin(__builtin_amdgcn_mfma_f32_16x16x16bf16_1k)
  #define MFMA16(a,b,c) __builtin_amdgcn_mfma_f32_16x16x16bf16_1k((a),(b),(c),0,0,0)
  #define HAVE_MFMA16 1
#else
  #define HAVE_MFMA16 0
#endif

__device__ __forceinline__ unsigned short f2b(float f){        // fp32 -> bf16 RNE
  unsigned u = __float_as_uint(f);
  return (unsigned short)((u + 0x7FFFu + ((u>>16)&1u)) >> 16);
}
__device__ __forceinline__ unsigned cvt_pk_bf16(float lo, float hi){  // HW RNE pair-convert
  unsigned r;
  asm("v_cvt_pk_bf16_f32 %0, %1, %2" : "=v"(r) : "v"(lo), "v"(hi));
  return r;
}

__global__ void k_probe(float* __restrict__ out, float code){
  if(blockIdx.x==0 && threadIdx.x==0) out[0] = code;
}

// ---------------------------------------------------------------- K0: offsets (3072) + x-transpose (768) + weight prep (320)
__global__ __launch_bounds__(256) void k_prep_off(
    const float* __restrict__ query, const float* __restrict__ refp,
    const float* __restrict__ w1, const float* __restrict__ b1,
    const float* __restrict__ lng, const float* __restrict__ lnb,
    const float* __restrict__ w2, float* __restrict__ rwo, float* __restrict__ rws,
    const float* __restrict__ x, float* __restrict__ xt,
    const float* __restrict__ k_w, const float* __restrict__ v_w, const float* __restrict__ out_w,
    unsigned short* __restrict__ kw16, unsigned short* __restrict__ vw16, float* __restrict__ ow_t){
  __shared__ float t[64][65];
  int bx = blockIdx.x;               // 4160 = 3072 offsets + 768 transpose + 320 wprep
  if(bx < 3072){
    int wid  = bx*4 + (threadIdx.x>>6);
    int lane = threadIdx.x & 63;
    int vi  = wid >> 12;
    int rem = wid & 4095;
    int bg  = rem >> 10;
    int pix = rem & 1023;
    int y = pix >> 5, xq = pix & 31;
    int b = bg >> 1, g = bg & 1;
    float qv = query[(size_t)(b*128 + g*64 + lane)*1024 + pix];
    float h[4]; float s1 = 0.f, s2 = 0.f;
    #pragma unroll
    for(int d=0; d<4; ++d){
      h[d] = qv*w1[vi*256 + lane*4 + d] + b1[vi*256 + lane*4 + d];
      s1 += h[d]; s2 += h[d]*h[d];
    }
    #pragma unroll
    for(int off=1; off<64; off<<=1){ s1 += __shfl_xor(s1, off); s2 += __shfl_xor(s2, off); }
    float mu   = s1 * (1.f/256.f);
    float var  = s2 * (1.f/256.f) - mu*mu;
    float rstd = rsqrtf(fmaxf(var, 0.f) + 1e-5f);
    float po[4] = {0.f,0.f,0.f,0.f};
    #pragma unroll
    for(int d=0; d<4; ++d){
      float hv = (h[d]-mu)*rstd*lng[vi*256+lane*4+d] + lnb[vi*256+lane*4+d];
      hv = 0.5f*hv*(1.f + erff(hv*0.70710678118654752f));   // exact GELU
      #pragma unroll
      for(int o=0; o<4; ++o) po[o] += w2[(vi*4+o)*256 + lane*4 + d] * hv;
    }
    #pragma unroll
    for(int off=1; off<64; off<<=1){
      #pragma unroll
      for(int o=0; o<4; ++o) po[o] += __shfl_xor(po[o], off);
    }
    if(lane == 0){
      int tt = y & 1, hk = y >> 1;
      float rng = tt ? (5.f/127.f) : (5.f/15.f);
      float csc = tt ? 63.5f : 15.5f;
      #pragma unroll
      for(int d=0; d<4; ++d){
        int wk = xq*4 + d;
        float rv = refp[(size_t)(((b*3+vi)*16 + hk)*128 + wk)*2 + (1-tt)];  // [..., ::-1]
        float coord = tanhf(po[d])*rng + rv;
        size_t o2 = ((size_t)(vi*4+bg)*2048 + hk*128 + wk)*2 + tt;
        rwo[o2] = coord;
        rws[o2] = coord * csc;
      }
    }
  } else if(bx < 3840){
    int pb = bx - 3072;
    int iy = pb & 63;
    int o2 = pb >> 6;
    const float* src = x + ((size_t)o2*64)*4096 + (size_t)iy*64;
    int ix = threadIdx.x & 63, cq = threadIdx.x >> 6;
    #pragma unroll
    for(int c0 = 0; c0 < 64; c0 += 4)
      t[c0+cq][ix] = src[(size_t)(c0+cq)*4096 + ix];
    __syncthreads();
    float* dst = xt + (((size_t)o2*64 + iy)*64)*64;
    int c = threadIdx.x & 63, xq = threadIdx.x >> 6;
    #pragma unroll
    for(int x0 = 0; x0 < 64; x0 += 4)
      dst[(size_t)(x0+xq)*64 + c] = t[c][x0+xq];
  } else {
    int wb = bx - 3840;              // 320 = 64 kw16 + 64 vw16 + 192 ow_t
    if(wb < 128){
      int i = (wb & 63)*256 + threadIdx.x;
      if(wb < 64) kw16[i] = f2b(k_w[i]);
      else        vw16[i] = f2b(v_w[i]);
    } else {
      int i = (wb-128)*256 + threadIdx.x;
      if(i < 49152){
        int r = i / 384, c = i - r*384;
        ow_t[c*128 + r] = out_w[i];
      }
    }
  }
}

// ---------------------------------------------------------------- K1: fused sample + MFMA K/V projection, 8 waves (1 head/wave)
__global__ __launch_bounds__(512) void k_sampro(
    const float* __restrict__ rwo, const float* __restrict__ xt,
    const unsigned short* __restrict__ kw16, const float* __restrict__ k_b,
    const unsigned short* __restrict__ vw16, const float* __restrict__ v_b,
    unsigned short* __restrict__ k_b16, unsigned short* __restrict__ v_t16){
  __shared__ alignas(16) unsigned short tile[16*136];   // 4352 B bf16 xs tile
  int bx = blockIdx.x;               // 768 = (vi*2+b)*128 + nt
  int nt = bx & 127;
  int r2 = bx >> 7;
  int b = r2 & 1, vi = r2 >> 1;
  int n0 = nt*16;
  int tid = threadIdx.x, wid = tid>>6, lane = tid&63;
  #pragma unroll
  for(int s = 0; s < 4; ++s){        // 32 (n,g) units, 4 per wave
    int u = wid*4 + s;
    int nl = u >> 1, g = u & 1;
    int n = n0 + nl;
    float yn = rwo[((size_t)(vi*4 + b*2 + g)*2048 + n)*2 + 0];
    float xn = rwo[((size_t)(vi*4 + b*2 + g)*2048 + n)*2 + 1];
    float px = (xn + 1.f)*31.5f;
    float py = (yn + 1.f)*31.5f;
    float x0 = floorf(px), y0 = floorf(py);
    float fx = px - x0, fy = py - y0;
    int ix0 = (int)x0, iy0 = (int)y0;
    const float* base = xt + (size_t)((b*3+vi)*2+g)*4096*64;
    float wts[4] = {(1.f-fx)*(1.f-fy), fx*(1.f-fy), (1.f-fx)*fy, fx*fy};
    int ixs[4] = {ix0, ix0+1, ix0, ix0+1};
    int iys[4] = {iy0, iy0, iy0+1, iy0+1};
    float acc = 0.f;
    #pragma unroll
    for(int tp=0; tp<4; ++tp){
      int ix = ixs[tp], iy = iys[tp];
      if(ix>=0 && ix<64 && iy>=0 && iy<64)
        acc += wts[tp] * base[(size_t)((iy<<6)+ix)*64 + lane];
    }
    tile[nl*136 + g*64 + lane] = f2b(acc);
  }
  __syncthreads();
  // ---- MFMA projection: wave w -> head w, K + V tiles
  int c = lane & 15, qd = lane >> 4;
  short8 af[4];                      // A[m=sample n=c][k=c-chan qd*8+j], 4 x K=32 = 128 ch
  #pragma unroll
  for(int kc=0; kc<4; ++kc)
    af[kc] = *(const short8*)(&tile[c*136 + kc*32 + qd*8]);
  size_t vbbase = (size_t)(vi*16 + b*8)*2048*16;
  const float SC2 = 0.36067376022224085f;     // 0.25 * log2(e), folded into K
  int nh = wid;
  size_t hbase = vbbase + (size_t)nh*2048*16;
  {  // K head: k_b16[n][ch], pre-scaled by SC2
    f32x4 C = {0.f,0.f,0.f,0.f};
    #pragma unroll
    for(int kc=0; kc<4; ++kc){
      short8 bf = *(const short8*)(kw16 + (size_t)(nh*16 + c)*128 + kc*32 + qd*8);
      C = __builtin_amdgcn_mfma_f32_16x16x32_bf16(af[kc], bf, C, 0, 0, 0);
    }
    float bias = k_b[nh*16 + c];
    #pragma unroll
    for(int r=0; r<4; ++r)
      k_b16[hbase + (size_t)(n0 + qd*4 + r)*16 + c] = f2b((C[r] + bias)*SC2);
  }
  {  // V head: v_t16[ch][n], plain layout, vectorized uint2 store
    f32x4 C = {0.f,0.f,0.f,0.f};
    #pragma unroll
    for(int kc=0; kc<4; ++kc){
      short8 bf = *(const short8*)(vw16 + (size_t)(nh*16 + c)*128 + kc*32 + qd*8);
      C = __builtin_amdgcn_mfma_f32_16x16x32_bf16(af[kc], bf, C, 0, 0, 0);
    }
    float bias = v_b[nh*16 + c];
    uint2 pk;
    pk.x = cvt_pk_bf16(C[0]+bias, C[1]+bias);
    pk.y = cvt_pk_bf16(C[2]+bias, C[3]+bias);
    *(uint2*)(v_t16 + hbase + (size_t)c*2048 + n0 + qd*4) = pk;
  }
}

// ---------------------------------------------------------------- K2: MFMA flash attention, 512 thr, x-half blocks, 3 blocks/CU,
//                                                                  K=16 QK MFMA (CH=16 exact, no zero-pad, no spill)
__global__ __launch_bounds__(512,6) void k_attn(
    const float* __restrict__ rws, const unsigned short* __restrict__ k_b16,
    const unsigned short* __restrict__ v_t16, const float* __restrict__ query,
    const float* __restrict__ rpe, float* __restrict__ attn_pc){
  __shared__ unsigned P32[49*197];               // 38,612 B (lo, hi-lo) log2-scaled bf16 pairs
  __shared__ alignas(16) short p_sm[8][16*40];   // 10,240 B per-wave P^T buffer (reused as f32 merge buffer)
  int bx = blockIdx.x;            // 768 = vi*256 + bh*16 + mq*2 + h
  int vi = bx >> 8;
  int bh = (bx >> 4) & 15;
  int mq = (bx >> 1) & 7;         // m-quad: 4 consecutive grid rows
  int h  = bx & 1;                // x-half: m-cols [16h, 16h+16)
  int b = bh >> 3, nh = bh & 7, g = nh >> 2, bg = b*2 + g;
  int tid = threadIdx.x, wid = tid >> 6;
  int w4  = wid & 3;              // grid-row within the quad
  int nhf = wid >> 2;             // nc half: 0 -> nc 0..7, 1 -> nc 8..15
  int lane = tid & 63, c = lane & 15, qd = lane >> 4;
  int m0 = (mq*4 + w4)*32 + 16*h;
  int xoff = h*64;
  float gy0 = -1.f + (2.f/31.f)*(float)(mq*4);
  float pyL = 15.5f*(gy0 - 4.f/3.f) + 31.f - 0.01f;
  float pyH = 15.5f*(gy0 + 6.f/31.f + 4.f/3.f) + 31.f + 0.01f;
  int a  = max(-1, (int)floorf(pyL));
  int bb = min(63, (int)floorf(pyH));
  int iy_lo = max(a - 1, bb - 48);
  {
    const float* rt = rpe + (size_t)nh*16065;
    for(int e = tid; e < 49*197; e += 512){
      int rr = e / 197;
      int cc = e - rr*197;
      int iy = iy_lo + rr;
      int ix = cc - 1 + xoff;
      bool xv = (ix >= 0) && (ix <= 254);
      float lo = (xv && iy   >= 0 && iy   <= 62) ? rt[iy*255 + ix]     : 0.f;
      float hi = (xv && iy+1 >= 0 && iy+1 <= 62) ? rt[(iy+1)*255 + ix] : 0.f;
      P32[e] = cvt_pk_bf16(lo*1.44269504f, (hi - lo)*1.44269504f);
    }
  }
#if HAVE_MFMA16
  short4v qa;                      // K=16: ch = qd*4 + j, every lane real data
  #pragma unroll
  for(int j=0; j<4; ++j){
    int ch = qd*4 + j;
    qa[j] = (short)f2b(query[(size_t)(b*128 + nh*16 + ch)*1024 + m0 + c]);
  }
#else
  short8 qa;
  #pragma unroll
  for(int j=0; j<8; ++j){
    int ch = qd*8 + j;
    qa[j] = (qd < 2) ? (short)f2b(query[(size_t)(b*128 + nh*16 + ch)*1024 + m0 + c]) : (short)0;
  }
#endif
  float Ax2[4];                    // xoff folded in: px is window-local
  #pragma unroll
  for(int r=0; r<4; ++r){
    int mr = m0 + qd*4 + r;
    float gxr = -1.f + (2.f/31.f)*(mr & 31);
    Ax2[r] = 63.5f*gxr + 128.f - (float)xoff;
  }
  // wave's 16 m-rows share one grid row -> y-side wave-uniform per sample
  float gyw = -1.f + (2.f/31.f)*(float)(m0 >> 5);
  float Ay  = 15.5f*gyw + 31.f - (float)iy_lo;
  float loC = fmaxf(-1.f - (float)iy_lo, 0.f);
  float hiC = fminf(63.f - (float)iy_lo, 47.f);
  float si[4] = {0.f, 0.f, 0.f, 0.f};
  f32x4 O = {0.f, 0.f, 0.f, 0.f};
  size_t kvb  = (size_t)(vi*16 + bh)*2048*16;
  size_t rwsb = (size_t)(vi*4 + bg)*2048;
  short* pw = &p_sm[wid][0];
  const f32x4 z = {0.f,0.f,0.f,0.f};
  __syncthreads();
  for(int nc = nhf*8, ncE = nhf*8 + 8; nc < ncE; ++nc){
    int n0 = nc*128;
#if HAVE_MFMA16
    const unsigned short* kb = k_b16 + kvb + (size_t)(n0 + c)*16 + qd*4;   // + t*256
#else
    const unsigned short* kb = k_b16 + kvb + (size_t)(n0 + c)*16 + qd*8;   // + t*256
#endif
    #pragma unroll
    for(int kc=0; kc<4; ++kc){
      // ---- issue both S-MFMAs for this kc first; bias math below is
      //      S-independent and hides their latency
#if HAVE_MFMA16
      short4v bk0 = *(const short4v*)(kb + (2*kc)*256);
      short4v bk1 = *(const short4v*)(kb + (2*kc+1)*256);
      f32x4 S0 = MFMA16(qa, bk0, z);
      f32x4 S1 = MFMA16(qa, bk1, z);
#else
      short8 bk0 = {0,0,0,0,0,0,0,0}, bk1 = {0,0,0,0,0,0,0,0};
      if(qd < 2){ bk0 = *(const short8*)(kb + (2*kc)*256); bk1 = *(const short8*)(kb + (2*kc+1)*256); }
      f32x4 S0 = __builtin_amdgcn_mfma_f32_16x16x32_bf16(qa, bk0, z, 0, 0, 0);
      f32x4 S1 = __builtin_amdgcn_mfma_f32_16x16x32_bf16(qa, bk1, z, 0, 0, 0);
#endif
      // ---- S-free bias values for t=2kc, 2kc+1
      float be[4], bo[4];
      {
        float2 rs = *(const float2*)(rws + (rwsb + n0 + (2*kc)*16 + c)*2);
        float py = Ay - rs.x;
        py = fminf(fmaxf(py, loC), hiC);
        float rf = floorf(py);
        float fy = py - rf;
        int rbase = (int)rf * 197 + 1;
        #pragma unroll
        for(int r=0; r<4; ++r){
          float px = Ax2[r] - rs.y;
          px = fminf(fmaxf(px, 0.f), 192.f);
          float cf = floorf(px);
          float fx = px - cf;
          int idx = rbase + (int)cf;
          unsigned w0 = P32[idx], w1 = P32[idx+1];
          float lo0 = __uint_as_float(w0 << 16), d0 = __uint_as_float(w0 & 0xFFFF0000u);
          float lo1 = __uint_as_float(w1 << 16), d1 = __uint_as_float(w1 & 0xFFFF0000u);
          float t0 = lo0 + fy*d0;
          float t1 = lo1 + fy*d1;
          be[r] = t0 + fx*(t1 - t0);
        }
      }
      {
        float2 rs = *(const float2*)(rws + (rwsb + n0 + (2*kc+1)*16 + c)*2);
        float py = Ay - rs.x;
        py = fminf(fmaxf(py, loC), hiC);
        float rf = floorf(py);
        float fy = py - rf;
        int rbase = (int)rf * 197 + 1;
        #pragma unroll
        for(int r=0; r<4; ++r){
          float px = Ax2[r] - rs.y;
          px = fminf(fmaxf(px, 0.f), 192.f);
          float cf = floorf(px);
          float fx = px - cf;
          int idx = rbase + (int)cf;
          unsigned w0 = P32[idx], w1 = P32[idx+1];
          float lo0 = __uint_as_float(w0 << 16), d0 = __uint_as_float(w0 & 0xFFFF0000u);
          float lo1 = __uint_as_float(w1 << 16), d1 = __uint_as_float(w1 & 0xFFFF0000u);
          float t0 = lo0 + fy*d0;
          float t1 = lo1 + fy*d1;
          bo[r] = t0 + fx*(t1 - t0);
        }
      }
      // ---- exp2 with S (K pre-scaled by 0.25*log2e), accumulate si, pack P^T
      float pe[4], po[4];
      #pragma unroll
      for(int r=0; r<4; ++r){ pe[r] = exp2f(S0[r] + be[r]); si[r] += pe[r]; }
      #pragma unroll
      for(int r=0; r<4; ++r){ po[r] = exp2f(S1[r] + bo[r]); si[r] += po[r]; }
      #pragma unroll
      for(int r=0; r<4; ++r){
        unsigned pk = cvt_pk_bf16(pe[r], po[r]);
        pw[(qd*4 + r)*40 + c]      = (short)pk;
        pw[(qd*4 + r)*40 + 16 + c] = (short)(pk >> 16);
      }
      short8 va = *(const short8*)(v_t16 + kvb + (size_t)c*2048 + n0 + kc*32 + qd*8);
      short8 pbf = *(const short8*)(&pw[c*40 + qd*8]);
      O = __builtin_amdgcn_mfma_f32_16x16x32_bf16(va, pbf, O, 0, 0, 0);
    }
  }
  // ---- merge the two nc halves via LDS (reuse p_sm block as f32 buffer)
  __syncthreads();
  float* red = (float*)&p_sm[0][0];
  int basei = (w4*64 + lane)*8;
  if(nhf){
    red[basei+0] = O[0];  red[basei+1] = O[1];
    red[basei+2] = O[2];  red[basei+3] = O[3];
    red[basei+4] = si[0]; red[basei+5] = si[1];
    red[basei+6] = si[2]; red[basei+7] = si[3];
  }
  __syncthreads();
  if(!nhf){
    O[0] += red[basei+0]; O[1] += red[basei+1];
    O[2] += red[basei+2]; O[3] += red[basei+3];
    si[0] += red[basei+4]; si[1] += red[basei+5];
    si[2] += red[basei+6]; si[3] += red[basei+7];
    #pragma unroll
    for(int r=0; r<4; ++r){
      float sv = si[r];
      sv += __shfl_xor(sv, 1); sv += __shfl_xor(sv, 2);
      sv += __shfl_xor(sv, 4); sv += __shfl_xor(sv, 8);
      si[r] = sv;
    }
    int msrc = (c >> 2)*16 + c;
    int rsel = c & 3;
    float s0 = __shfl(si[0], msrc), s1 = __shfl(si[1], msrc),
          s2 = __shfl(si[2], msrc), s3 = __shfl(si[3], msrc);
    float sv = (rsel==0) ? s0 : ((rsel==1) ? s1 : ((rsel==2) ? s2 : s3));
    float inv = 1.f/sv;
    float4 o4;
    o4.x = O[0]*inv; o4.y = O[1]*inv; o4.z = O[2]*inv; o4.w = O[3]*inv;
    *(float4*)(attn_pc + (size_t)(b*1024 + m0 + c)*384 + vi*128 + nh*16 + qd*4) = o4;
  }
}

// ---------------------------------------------------------------- K3: output projection (512 blocks, 4 m-rows each)
__global__ __launch_bounds__(256) void k_outproj(
    const float* __restrict__ attn_pc, const float* __restrict__ ow_t, const float* __restrict__ out_b,
    float* __restrict__ out){
  __shared__ float A[4*384];         // 6 KB
  int bx = blockIdx.x;               // 512 = b*256 + mt
  int b  = bx >> 8;
  int m0 = (bx & 255)*4;
  const float4* src = (const float4*)(attn_pc + ((size_t)b*1024 + m0)*384);
  float4* dst = (float4*)A;
  for(int i = threadIdx.x; i < 384; i += 256) dst[i] = src[i];
  __syncthreads();
  int oc = threadIdx.x & 127;
  int mh = threadIdx.x >> 7;         // 0..1, each handles 2 m-rows
  float acc[2] = {0.f,0.f};
  #pragma unroll 4
  for(int vc = 0; vc < 384; ++vc){
    float wv = ow_t[vc*128 + oc];
    #pragma unroll
    for(int j=0; j<2; ++j) acc[j] += wv * A[(mh*2+j)*384 + vc];
  }
  float ob = out_b[oc];
  #pragma unroll
  for(int j=0; j<2; ++j)
    out[((size_t)b*128 + oc)*1024 + m0 + mh*2 + j] = acc[j] + ob;
}

extern "C" void kernel_launch(void* const* d_in, const int* in_sizes, int n_in,
                              void* d_out, int out_size, void* d_ws, size_t ws_size,
                              hipStream_t stream){
  const float* x     = (const float*)d_in[0];
  const float* query = (const float*)d_in[1];
  const float* refp  = (const float*)d_in[2];
  const float* w1    = (const float*)d_in[3];
  const float* b1    = (const float*)d_in[4];
  const float* lng   = (const float*)d_in[5];
  const float* lnb   = (const float*)d_in[6];
  const float* w2    = (const float*)d_in[7];
  const float* k_w   = (const float*)d_in[8];
  const float* k_b   = (const float*)d_in[9];
  const float* v_w   = (const float*)d_in[10];
  const float* v_b   = (const float*)d_in[11];
  const float* out_w = (const float*)d_in[12];
  const float* out_b = (const float*)d_in[13];
  const float* rpe   = (const float*)d_in[14];

  const size_t O_XT   = 0;            // 12,582,912
  const size_t O_RWO  = 12582912;     //    196,608
  const size_t O_RWS  = 12779520;     //    196,608
  const size_t O_KB16 = 12976128;     //  3,145,728
  const size_t O_VT16 = 16121856;     //  3,145,728
  const size_t O_APC  = 19267584;     //  3,145,728
  const size_t O_KW16 = 22413312;     //     32,768
  const size_t O_VW16 = 22446080;     //     32,768
  const size_t O_OWT  = 22478848;     //    196,608
  const size_t NEED   = 22675456;
  if(ws_size < NEED){
    k_probe<<<1, 64, 0, stream>>>((float*)d_out, 100.f + (float)(ws_size >> 20));
    return;
  }
  char* ws = (char*)d_ws;
  float* xt      = (float*)(ws + O_XT);
  float* rwo     = (float*)(ws + O_RWO);
  float* rws     = (float*)(ws + O_RWS);
  unsigned short* k_b16 = (unsigned short*)(ws + O_KB16);
  unsigned short* v_t16 = (unsigned short*)(ws + O_VT16);
  float* attn_pc = (float*)(ws + O_APC);
  unsigned short* kw16 = (unsigned short*)(ws + O_KW16);
  unsigned short* vw16 = (unsigned short*)(ws + O_VW16);
  float* ow_t    = (float*)(ws + O_OWT);

  k_prep_off<<<4160, 256, 0, stream>>>(query, refp, w1, b1, lng, lnb, w2, rwo, rws,
                                       x, xt, k_w, v_w, out_w, kw16, vw16, ow_t);
  k_sampro  <<<768,  512, 0, stream>>>(rwo, xt, kw16, k_b, vw16, v_b, k_b16, v_t16);
  k_attn    <<<768,  512, 0, stream>>>(rws, k_b16, v_t16, query, rpe, attn_pc);
  k_outproj <<<512,  256, 0, stream>>>(attn_pc, ow_t, out_b, (float*)d_out);
}

// Round 9
// 232.029 us; speedup vs baseline: 1.1743x; 1.0174x over previous
//
#include <hip/hip_runtime.h>
#include <hip/hip_bf16.h>
#include <math.h>

// B=2 V=3 G=2 NH=8 C=128 CPG=64 CH=16 HPG=4 Hq=Wq=32 D=4 Hk=16 Wk=128 NS=2048
// Hi=Wi=64 SCALE=0.25 OFR=5 EPS=1e-5  RPE 63x255 per head
// All inputs fp32, output fp32 (established R2-R6).
// R22 = R21 with k_attn bias+exp fused per (t,r): the be[4]/bo[4] staging arrays
//   (8 live VGPRs) existed to separate S-free bias math from exp2; at 24
//   waves/CU TLP hides the MFMA latency without them. This is the final ~8
//   regs over the 80-reg cap at 6 waves/SIMD (R21 still had ~7.7MB scratch
//   WRITE_SIZE). Everything else identical to R21 (K=16 QK MFMA, x-half
//   window blocks, 3 blocks/CU, single end merge).

typedef __attribute__((ext_vector_type(8))) short short8;
typedef __attribute__((ext_vector_type(4))) short short4v;
typedef __attribute__((ext_vector_type(4))) float f32x4;

#if __has_builtin(__builtin_amdgcn_mfma_f32_16x16x16_bf16)
  #define MFMA16(a,b,c) __builtin_amdgcn_mfma_f32_16x16x16_bf16((a),(b),(c),0,0,0)
  #define HAVE_MFMA16 1
#elif __has_builtin(__builtin_amdgcn_mfma_f32_16x16x16bf16_1k)
  #define MFMA16(a,b,c) __builtin_amdgcn_mfma_f32_16x16x16bf16_1k((a),(b),(c),0,0,0)
  #define HAVE_MFMA16 1
#else
  #define HAVE_MFMA16 0
#endif

__device__ __forceinline__ unsigned short f2b(float f){        // fp32 -> bf16 RNE
  unsigned u = __float_as_uint(f);
  return (unsigned short)((u + 0x7FFFu + ((u>>16)&1u)) >> 16);
}
__device__ __forceinline__ unsigned cvt_pk_bf16(float lo, float hi){  // HW RNE pair-convert
  unsigned r;
  asm("v_cvt_pk_bf16_f32 %0, %1, %2" : "=v"(r) : "v"(lo), "v"(hi));
  return r;
}

__global__ void k_probe(float* __restrict__ out, float code){
  if(blockIdx.x==0 && threadIdx.x==0) out[0] = code;
}

// ---------------------------------------------------------------- K0: offsets (3072) + x-transpose (768) + weight prep (320)
__global__ __launch_bounds__(256) void k_prep_off(
    const float* __restrict__ query, const float* __restrict__ refp,
    const float* __restrict__ w1, const float* __restrict__ b1,
    const float* __restrict__ lng, const float* __restrict__ lnb,
    const float* __restrict__ w2, float* __restrict__ rwo, float* __restrict__ rws,
    const float* __restrict__ x, float* __restrict__ xt,
    const float* __restrict__ k_w, const float* __restrict__ v_w, const float* __restrict__ out_w,
    unsigned short* __restrict__ kw16, unsigned short* __restrict__ vw16, float* __restrict__ ow_t){
  __shared__ float t[64][65];
  int bx = blockIdx.x;               // 4160 = 3072 offsets + 768 transpose + 320 wprep
  if(bx < 3072){
    int wid  = bx*4 + (threadIdx.x>>6);
    int lane = threadIdx.x & 63;
    int vi  = wid >> 12;
    int rem = wid & 4095;
    int bg  = rem >> 10;
    int pix = rem & 1023;
    int y = pix >> 5, xq = pix & 31;
    int b = bg >> 1, g = bg & 1;
    float qv = query[(size_t)(b*128 + g*64 + lane)*1024 + pix];
    float h[4]; float s1 = 0.f, s2 = 0.f;
    #pragma unroll
    for(int d=0; d<4; ++d){
      h[d] = qv*w1[vi*256 + lane*4 + d] + b1[vi*256 + lane*4 + d];
      s1 += h[d]; s2 += h[d]*h[d];
    }
    #pragma unroll
    for(int off=1; off<64; off<<=1){ s1 += __shfl_xor(s1, off); s2 += __shfl_xor(s2, off); }
    float mu   = s1 * (1.f/256.f);
    float var  = s2 * (1.f/256.f) - mu*mu;
    float rstd = rsqrtf(fmaxf(var, 0.f) + 1e-5f);
    float po[4] = {0.f,0.f,0.f,0.f};
    #pragma unroll
    for(int d=0; d<4; ++d){
      float hv = (h[d]-mu)*rstd*lng[vi*256+lane*4+d] + lnb[vi*256+lane*4+d];
      hv = 0.5f*hv*(1.f + erff(hv*0.70710678118654752f));   // exact GELU
      #pragma unroll
      for(int o=0; o<4; ++o) po[o] += w2[(vi*4+o)*256 + lane*4 + d] * hv;
    }
    #pragma unroll
    for(int off=1; off<64; off<<=1){
      #pragma unroll
      for(int o=0; o<4; ++o) po[o] += __shfl_xor(po[o], off);
    }
    if(lane == 0){
      int tt = y & 1, hk = y >> 1;
      float rng = tt ? (5.f/127.f) : (5.f/15.f);
      float csc = tt ? 63.5f : 15.5f;
      #pragma unroll
      for(int d=0; d<4; ++d){
        int wk = xq*4 + d;
        float rv = refp[(size_t)(((b*3+vi)*16 + hk)*128 + wk)*2 + (1-tt)];  // [..., ::-1]
        float coord = tanhf(po[d])*rng + rv;
        size_t o2 = ((size_t)(vi*4+bg)*2048 + hk*128 + wk)*2 + tt;
        rwo[o2] = coord;
        rws[o2] = coord * csc;
      }
    }
  } else if(bx < 3840){
    int pb = bx - 3072;
    int iy = pb & 63;
    int o2 = pb >> 6;
    const float* src = x + ((size_t)o2*64)*4096 + (size_t)iy*64;
    int ix = threadIdx.x & 63, cq = threadIdx.x >> 6;
    #pragma unroll
    for(int c0 = 0; c0 < 64; c0 += 4)
      t[c0+cq][ix] = src[(size_t)(c0+cq)*4096 + ix];
    __syncthreads();
    float* dst = xt + (((size_t)o2*64 + iy)*64)*64;
    int c = threadIdx.x & 63, xq = threadIdx.x >> 6;
    #pragma unroll
    for(int x0 = 0; x0 < 64; x0 += 4)
      dst[(size_t)(x0+xq)*64 + c] = t[c][x0+xq];
  } else {
    int wb = bx - 3840;              // 320 = 64 kw16 + 64 vw16 + 192 ow_t
    if(wb < 128){
      int i = (wb & 63)*256 + threadIdx.x;
      if(wb < 64) kw16[i] = f2b(k_w[i]);
      else        vw16[i] = f2b(v_w[i]);
    } else {
      int i = (wb-128)*256 + threadIdx.x;
      if(i < 49152){
        int r = i / 384, c = i - r*384;
        ow_t[c*128 + r] = out_w[i];
      }
    }
  }
}

// ---------------------------------------------------------------- K1: fused sample + MFMA K/V projection, 8 waves (1 head/wave)
__global__ __launch_bounds__(512) void k_sampro(
    const float* __restrict__ rwo, const float* __restrict__ xt,
    const unsigned short* __restrict__ kw16, const float* __restrict__ k_b,
    const unsigned short* __restrict__ vw16, const float* __restrict__ v_b,
    unsigned short* __restrict__ k_b16, unsigned short* __restrict__ v_t16){
  __shared__ alignas(16) unsigned short tile[16*136];   // 4352 B bf16 xs tile
  int bx = blockIdx.x;               // 768 = (vi*2+b)*128 + nt
  int nt = bx & 127;
  int r2 = bx >> 7;
  int b = r2 & 1, vi = r2 >> 1;
  int n0 = nt*16;
  int tid = threadIdx.x, wid = tid>>6, lane = tid&63;
  #pragma unroll
  for(int s = 0; s < 4; ++s){        // 32 (n,g) units, 4 per wave
    int u = wid*4 + s;
    int nl = u >> 1, g = u & 1;
    int n = n0 + nl;
    float yn = rwo[((size_t)(vi*4 + b*2 + g)*2048 + n)*2 + 0];
    float xn = rwo[((size_t)(vi*4 + b*2 + g)*2048 + n)*2 + 1];
    float px = (xn + 1.f)*31.5f;
    float py = (yn + 1.f)*31.5f;
    float x0 = floorf(px), y0 = floorf(py);
    float fx = px - x0, fy = py - y0;
    int ix0 = (int)x0, iy0 = (int)y0;
    const float* base = xt + (size_t)((b*3+vi)*2+g)*4096*64;
    float wts[4] = {(1.f-fx)*(1.f-fy), fx*(1.f-fy), (1.f-fx)*fy, fx*fy};
    int ixs[4] = {ix0, ix0+1, ix0, ix0+1};
    int iys[4] = {iy0, iy0, iy0+1, iy0+1};
    float acc = 0.f;
    #pragma unroll
    for(int tp=0; tp<4; ++tp){
      int ix = ixs[tp], iy = iys[tp];
      if(ix>=0 && ix<64 && iy>=0 && iy<64)
        acc += wts[tp] * base[(size_t)((iy<<6)+ix)*64 + lane];
    }
    tile[nl*136 + g*64 + lane] = f2b(acc);
  }
  __syncthreads();
  // ---- MFMA projection: wave w -> head w, K + V tiles
  int c = lane & 15, qd = lane >> 4;
  short8 af[4];                      // A[m=sample n=c][k=c-chan qd*8+j], 4 x K=32 = 128 ch
  #pragma unroll
  for(int kc=0; kc<4; ++kc)
    af[kc] = *(const short8*)(&tile[c*136 + kc*32 + qd*8]);
  size_t vbbase = (size_t)(vi*16 + b*8)*2048*16;
  const float SC2 = 0.36067376022224085f;     // 0.25 * log2(e), folded into K
  int nh = wid;
  size_t hbase = vbbase + (size_t)nh*2048*16;
  {  // K head: k_b16[n][ch], pre-scaled by SC2
    f32x4 C = {0.f,0.f,0.f,0.f};
    #pragma unroll
    for(int kc=0; kc<4; ++kc){
      short8 bf = *(const short8*)(kw16 + (size_t)(nh*16 + c)*128 + kc*32 + qd*8);
      C = __builtin_amdgcn_mfma_f32_16x16x32_bf16(af[kc], bf, C, 0, 0, 0);
    }
    float bias = k_b[nh*16 + c];
    #pragma unroll
    for(int r=0; r<4; ++r)
      k_b16[hbase + (size_t)(n0 + qd*4 + r)*16 + c] = f2b((C[r] + bias)*SC2);
  }
  {  // V head: v_t16[ch][n], plain layout, vectorized uint2 store
    f32x4 C = {0.f,0.f,0.f,0.f};
    #pragma unroll
    for(int kc=0; kc<4; ++kc){
      short8 bf = *(const short8*)(vw16 + (size_t)(nh*16 + c)*128 + kc*32 + qd*8);
      C = __builtin_amdgcn_mfma_f32_16x16x32_bf16(af[kc], bf, C, 0, 0, 0);
    }
    float bias = v_b[nh*16 + c];
    uint2 pk;
    pk.x = cvt_pk_bf16(C[0]+bias, C[1]+bias);
    pk.y = cvt_pk_bf16(C[2]+bias, C[3]+bias);
    *(uint2*)(v_t16 + hbase + (size_t)c*2048 + n0 + qd*4) = pk;
  }
}

// ---------------------------------------------------------------- K2: MFMA flash attention, 512 thr, x-half blocks, 3 blocks/CU,
//                                                                  K=16 QK MFMA, fused bias+exp (live state < 80 regs)
__global__ __launch_bounds__(512,6) void k_attn(
    const float* __restrict__ rws, const unsigned short* __restrict__ k_b16,
    const unsigned short* __restrict__ v_t16, const float* __restrict__ query,
    const float* __restrict__ rpe, float* __restrict__ attn_pc){
  __shared__ unsigned P32[49*197];               // 38,612 B (lo, hi-lo) log2-scaled bf16 pairs
  __shared__ alignas(16) short p_sm[8][16*40];   // 10,240 B per-wave P^T buffer (reused as f32 merge buffer)
  int bx = blockIdx.x;            // 768 = vi*256 + bh*16 + mq*2 + h
  int vi = bx >> 8;
  int bh = (bx >> 4) & 15;
  int mq = (bx >> 1) & 7;         // m-quad: 4 consecutive grid rows
  int h  = bx & 1;                // x-half: m-cols [16h, 16h+16)
  int b = bh >> 3, nh = bh & 7, g = nh >> 2, bg = b*2 + g;
  int tid = threadIdx.x, wid = tid >> 6;
  int w4  = wid & 3;              // grid-row within the quad
  int nhf = wid >> 2;             // nc half: 0 -> nc 0..7, 1 -> nc 8..15
  int lane = tid & 63, c = lane & 15, qd = lane >> 4;
  int m0 = (mq*4 + w4)*32 + 16*h;
  int xoff = h*64;
  float gy0 = -1.f + (2.f/31.f)*(float)(mq*4);
  float pyL = 15.5f*(gy0 - 4.f/3.f) + 31.f - 0.01f;
  float pyH = 15.5f*(gy0 + 6.f/31.f + 4.f/3.f) + 31.f + 0.01f;
  int a  = max(-1, (int)floorf(pyL));
  int bb = min(63, (int)floorf(pyH));
  int iy_lo = max(a - 1, bb - 48);
  {
    const float* rt = rpe + (size_t)nh*16065;
    for(int e = tid; e < 49*197; e += 512){
      int rr = e / 197;
      int cc = e - rr*197;
      int iy = iy_lo + rr;
      int ix = cc - 1 + xoff;
      bool xv = (ix >= 0) && (ix <= 254);
      float lo = (xv && iy   >= 0 && iy   <= 62) ? rt[iy*255 + ix]     : 0.f;
      float hi = (xv && iy+1 >= 0 && iy+1 <= 62) ? rt[(iy+1)*255 + ix] : 0.f;
      P32[e] = cvt_pk_bf16(lo*1.44269504f, (hi - lo)*1.44269504f);
    }
  }
#if HAVE_MFMA16
  short4v qa;                      // K=16: ch = qd*4 + j, every lane real data
  #pragma unroll
  for(int j=0; j<4; ++j){
    int ch = qd*4 + j;
    qa[j] = (short)f2b(query[(size_t)(b*128 + nh*16 + ch)*1024 + m0 + c]);
  }
#else
  short8 qa;
  #pragma unroll
  for(int j=0; j<8; ++j){
    int ch = qd*8 + j;
    qa[j] = (qd < 2) ? (short)f2b(query[(size_t)(b*128 + nh*16 + ch)*1024 + m0 + c]) : (short)0;
  }
#endif
  float Ax2[4];                    // xoff folded in: px is window-local
  #pragma unroll
  for(int r=0; r<4; ++r){
    int mr = m0 + qd*4 + r;
    float gxr = -1.f + (2.f/31.f)*(mr & 31);
    Ax2[r] = 63.5f*gxr + 128.f - (float)xoff;
  }
  // wave's 16 m-rows share one grid row -> y-side wave-uniform per sample
  float gyw = -1.f + (2.f/31.f)*(float)(m0 >> 5);
  float Ay  = 15.5f*gyw + 31.f - (float)iy_lo;
  float loC = fmaxf(-1.f - (float)iy_lo, 0.f);
  float hiC = fminf(63.f - (float)iy_lo, 47.f);
  float si[4] = {0.f, 0.f, 0.f, 0.f};
  f32x4 O = {0.f, 0.f, 0.f, 0.f};
  size_t kvb  = (size_t)(vi*16 + bh)*2048*16;
  size_t rwsb = (size_t)(vi*4 + bg)*2048;
  short* pw = &p_sm[wid][0];
  const f32x4 z = {0.f,0.f,0.f,0.f};
  __syncthreads();
  for(int nc = nhf*8, ncE = nhf*8 + 8; nc < ncE; ++nc){
    int n0 = nc*128;
#if HAVE_MFMA16
    const unsigned short* kb = k_b16 + kvb + (size_t)(n0 + c)*16 + qd*4;   // + t*256
#else
    const unsigned short* kb = k_b16 + kvb + (size_t)(n0 + c)*16 + qd*8;   // + t*256
#endif
    #pragma unroll
    for(int kc=0; kc<4; ++kc){
      // ---- issue both S-MFMAs for this kc first; the per-t address/bias
      //      math below is S-independent and covers their latency
#if HAVE_MFMA16
      short4v bk0 = *(const short4v*)(kb + (2*kc)*256);
      short4v bk1 = *(const short4v*)(kb + (2*kc+1)*256);
      f32x4 S0 = MFMA16(qa, bk0, z);
      f32x4 S1 = MFMA16(qa, bk1, z);
#else
      short8 bk0 = {0,0,0,0,0,0,0,0}, bk1 = {0,0,0,0,0,0,0,0};
      if(qd < 2){ bk0 = *(const short8*)(kb + (2*kc)*256); bk1 = *(const short8*)(kb + (2*kc+1)*256); }
      f32x4 S0 = __builtin_amdgcn_mfma_f32_16x16x32_bf16(qa, bk0, z, 0, 0, 0);
      f32x4 S1 = __builtin_amdgcn_mfma_f32_16x16x32_bf16(qa, bk1, z, 0, 0, 0);
#endif
      // ---- fused bias+exp per (t,r): no be/bo staging arrays (-8 live VGPR)
      float pe[4], po[4];
      {
        float2 rs = *(const float2*)(rws + (rwsb + n0 + (2*kc)*16 + c)*2);
        float py = Ay - rs.x;
        py = fminf(fmaxf(py, loC), hiC);
        float rf = floorf(py);
        float fy = py - rf;
        int rbase = (int)rf * 197 + 1;
        #pragma unroll
        for(int r=0; r<4; ++r){
          float px = Ax2[r] - rs.y;
          px = fminf(fmaxf(px, 0.f), 192.f);
          float cf = floorf(px);
          float fx = px - cf;
          int idx = rbase + (int)cf;
          unsigned w0 = P32[idx], w1 = P32[idx+1];
          float lo0 = __uint_as_float(w0 << 16), d0 = __uint_as_float(w0 & 0xFFFF0000u);
          float lo1 = __uint_as_float(w1 << 16), d1 = __uint_as_float(w1 & 0xFFFF0000u);
          float t0 = lo0 + fy*d0;
          float t1 = lo1 + fy*d1;
          float p = exp2f(S0[r] + t0 + fx*(t1 - t0));   // K pre-scaled by 0.25*log2e
          si[r] += p;
          pe[r] = p;
        }
      }
      {
        float2 rs = *(const float2*)(rws + (rwsb + n0 + (2*kc+1)*16 + c)*2);
        float py = Ay - rs.x;
        py = fminf(fmaxf(py, loC), hiC);
        float rf = floorf(py);
        float fy = py - rf;
        int rbase = (int)rf * 197 + 1;
        #pragma unroll
        for(int r=0; r<4; ++r){
          float px = Ax2[r] - rs.y;
          px = fminf(fmaxf(px, 0.f), 192.f);
          float cf = floorf(px);
          float fx = px - cf;
          int idx = rbase + (int)cf;
          unsigned w0 = P32[idx], w1 = P32[idx+1];
          float lo0 = __uint_as_float(w0 << 16), d0 = __uint_as_float(w0 & 0xFFFF0000u);
          float lo1 = __uint_as_float(w1 << 16), d1 = __uint_as_float(w1 & 0xFFFF0000u);
          float t0 = lo0 + fy*d0;
          float t1 = lo1 + fy*d1;
          float p = exp2f(S1[r] + t0 + fx*(t1 - t0));
          si[r] += p;
          po[r] = p;
        }
      }
      // ---- pack P^T into per-wave LDS, then PV MFMA for this kc
      #pragma unroll
      for(int r=0; r<4; ++r){
        unsigned pk = cvt_pk_bf16(pe[r], po[r]);
        pw[(qd*4 + r)*40 + c]      = (short)pk;
        pw[(qd*4 + r)*40 + 16 + c] = (short)(pk >> 16);
      }
      short8 va = *(const short8*)(v_t16 + kvb + (size_t)c*2048 + n0 + kc*32 + qd*8);
      short8 pbf = *(const short8*)(&pw[c*40 + qd*8]);
      O = __builtin_amdgcn_mfma_f32_16x16x32_bf16(va, pbf, O, 0, 0, 0);
    }
  }
  // ---- merge the two nc halves via LDS (reuse p_sm block as f32 buffer)
  __syncthreads();
  float* red = (float*)&p_sm[0][0];
  int basei = (w4*64 + lane)*8;
  if(nhf){
    red[basei+0] = O[0];  red[basei+1] = O[1];
    red[basei+2] = O[2];  red[basei+3] = O[3];
    red[basei+4] = si[0]; red[basei+5] = si[1];
    red[basei+6] = si[2]; red[basei+7] = si[3];
  }
  __syncthreads();
  if(!nhf){
    O[0] += red[basei+0]; O[1] += red[basei+1];
    O[2] += red[basei+2]; O[3] += red[basei+3];
    si[0] += red[basei+4]; si[1] += red[basei+5];
    si[2] += red[basei+6]; si[3] += red[basei+7];
    #pragma unroll
    for(int r=0; r<4; ++r){
      float sv = si[r];
      sv += __shfl_xor(sv, 1); sv += __shfl_xor(sv, 2);
      sv += __shfl_xor(sv, 4); sv += __shfl_xor(sv, 8);
      si[r] = sv;
    }
    int msrc = (c >> 2)*16 + c;
    int rsel = c & 3;
    float s0 = __shfl(si[0], msrc), s1 = __shfl(si[1], msrc),
          s2 = __shfl(si[2], msrc), s3 = __shfl(si[3], msrc);
    float sv = (rsel==0) ? s0 : ((rsel==1) ? s1 : ((rsel==2) ? s2 : s3));
    float inv = 1.f/sv;
    float4 o4;
    o4.x = O[0]*inv; o4.y = O[1]*inv; o4.z = O[2]*inv; o4.w = O[3]*inv;
    *(float4*)(attn_pc + (size_t)(b*1024 + m0 + c)*384 + vi*128 + nh*16 + qd*4) = o4;
  }
}

// ---------------------------------------------------------------- K3: output projection (512 blocks, 4 m-rows each)
__global__ __launch_bounds__(256) void k_outproj(
    const float* __restrict__ attn_pc, const float* __restrict__ ow_t, const float* __restrict__ out_b,
    float* __restrict__ out){
  __shared__ float A[4*384];         // 6 KB
  int bx = blockIdx.x;               // 512 = b*256 + mt
  int b  = bx >> 8;
  int m0 = (bx & 255)*4;
  const float4* src = (const float4*)(attn_pc + ((size_t)b*1024 + m0)*384);
  float4* dst = (float4*)A;
  for(int i = threadIdx.x; i < 384; i += 256) dst[i] = src[i];
  __syncthreads();
  int oc = threadIdx.x & 127;
  int mh = threadIdx.x >> 7;         // 0..1, each handles 2 m-rows
  float acc[2] = {0.f,0.f};
  #pragma unroll 4
  for(int vc = 0; vc < 384; ++vc){
    float wv = ow_t[vc*128 + oc];
    #pragma unroll
    for(int j=0; j<2; ++j) acc[j] += wv * A[(mh*2+j)*384 + vc];
  }
  float ob = out_b[oc];
  #pragma unroll
  for(int j=0; j<2; ++j)
    out[((size_t)b*128 + oc)*1024 + m0 + mh*2 + j] = acc[j] + ob;
}

extern "C" void kernel_launch(void* const* d_in, const int* in_sizes, int n_in,
                              void* d_out, int out_size, void* d_ws, size_t ws_size,
                              hipStream_t stream){
  const float* x     = (const float*)d_in[0];
  const float* query = (const float*)d_in[1];
  const float* refp  = (const float*)d_in[2];
  const float* w1    = (const float*)d_in[3];
  const float* b1    = (const float*)d_in[4];
  const float* lng   = (const float*)d_in[5];
  const float* lnb   = (const float*)d_in[6];
  const float* w2    = (const float*)d_in[7];
  const float* k_w   = (const float*)d_in[8];
  const float* k_b   = (const float*)d_in[9];
  const float* v_w   = (const float*)d_in[10];
  const float* v_b   = (const float*)d_in[11];
  const float* out_w = (const float*)d_in[12];
  const float* out_b = (const float*)d_in[13];
  const float* rpe   = (const float*)d_in[14];

  const size_t O_XT   = 0;            // 12,582,912
  const size_t O_RWO  = 12582912;     //    196,608
  const size_t O_RWS  = 12779520;     //    196,608
  const size_t O_KB16 = 12976128;     //  3,145,728
  const size_t O_VT16 = 16121856;     //  3,145,728
  const size_t O_APC  = 19267584;     //  3,145,728
  const size_t O_KW16 = 22413312;     //     32,768
  const size_t O_VW16 = 22446080;     //     32,768
  const size_t O_OWT  = 22478848;     //    196,608
  const size_t NEED   = 22675456;
  if(ws_size < NEED){
    k_probe<<<1, 64, 0, stream>>>((float*)d_out, 100.f + (float)(ws_size >> 20));
    return;
  }
  char* ws = (char*)d_ws;
  float* xt      = (float*)(ws + O_XT);
  float* rwo     = (float*)(ws + O_RWO);
  float* rws     = (float*)(ws + O_RWS);
  unsigned short* k_b16 = (unsigned short*)(ws + O_KB16);
  unsigned short* v_t16 = (unsigned short*)(ws + O_VT16);
  float* attn_pc = (float*)(ws + O_APC);
  unsigned short* kw16 = (unsigned short*)(ws + O_KW16);
  unsigned short* vw16 = (unsigned short*)(ws + O_VW16);
  float* ow_t    = (float*)(ws + O_OWT);

  k_prep_off<<<4160, 256, 0, stream>>>(query, refp, w1, b1, lng, lnb, w2, rwo, rws,
                                       x, xt, k_w, v_w, out_w, kw16, vw16, ow_t);
  k_sampro  <<<768,  512, 0, stream>>>(rwo, xt, kw16, k_b, vw16, v_b, k_b16, v_t16);
  k_attn    <<<768,  512, 0, stream>>>(rws, k_b16, v_t16, query, rpe, attn_pc);
  k_outproj <<<512,  256, 0, stream>>>(attn_pc, ow_t, out_b, (float*)d_out);
}

// Round 10
// 228.368 us; speedup vs baseline: 1.1931x; 1.0160x over previous
//
#include <hip/hip_runtime.h>
#include <hip/hip_bf16.h>
#include <math.h>

// B=2 V=3 G=2 NH=8 C=128 CPG=64 CH=16 HPG=4 Hq=Wq=32 D=4 Hk=16 Wk=128 NS=2048
// Hi=Wi=64 SCALE=0.25 OFR=5 EPS=1e-5  RPE 63x255 per head
// All inputs fp32, output fp32 (established R2-R6).
// R23 = R22 with the softmax denominator moved off the VALU:
//   - si via all-ones-A MFMA on the P^T tile (D[i][m] = sum_n P[n][m] for every
//     row i) accumulated per kc alongside PV. Removes 256 scalar adds/thread
//     from the saturated VALU (75% busy) onto the idle MFMA pipe (4% busy),
//     AND kills the 20-op shfl_xor/msrc/rsel epilogue: each lane directly
//     holds si[m=c], its own output row.
//   - s_setprio(1) around the MFMA clusters (T5: independent-wave attn regime).
//   - spill tripwire: ones fragment adds 4 live VGPRs; WRITE_SIZE must stay
//     3072 KB (R22 finally zeroed the scratch traffic).
// Everything else identical to R22.

typedef __attribute__((ext_vector_type(8))) short short8;
typedef __attribute__((ext_vector_type(4))) short short4v;
typedef __attribute__((ext_vector_type(4))) float f32x4;

#if __has_builtin(__builtin_amdgcn_mfma_f32_16x16x16_bf16)
  #define MFMA16(a,b,c) __builtin_amdgcn_mfma_f32_16x16x16_bf16((a),(b),(c),0,0,0)
  #define HAVE_MFMA16 1
#elif __has_builtin(__builtin_amdgcn_mfma_f32_16x16x16bf16_1k)
  #define MFMA16(a,b,c) __builtin_amdgcn_mfma_f32_16x16x16bf16_1k((a),(b),(c),0,0,0)
  #define HAVE_MFMA16 1
#else
  #define HAVE_MFMA16 0
#endif

__device__ __forceinline__ unsigned short f2b(float f){        // fp32 -> bf16 RNE
  unsigned u = __float_as_uint(f);
  return (unsigned short)((u + 0x7FFFu + ((u>>16)&1u)) >> 16);
}
__device__ __forceinline__ unsigned cvt_pk_bf16(float lo, float hi){  // HW RNE pair-convert
  unsigned r;
  asm("v_cvt_pk_bf16_f32 %0, %1, %2" : "=v"(r) : "v"(lo), "v"(hi));
  return r;
}

__global__ void k_probe(float* __restrict__ out, float code){
  if(blockIdx.x==0 && threadIdx.x==0) out[0] = code;
}

// ---------------------------------------------------------------- K0: offsets (3072) + x-transpose (768) + weight prep (320)
__global__ __launch_bounds__(256) void k_prep_off(
    const float* __restrict__ query, const float* __restrict__ refp,
    const float* __restrict__ w1, const float* __restrict__ b1,
    const float* __restrict__ lng, const float* __restrict__ lnb,
    const float* __restrict__ w2, float* __restrict__ rwo, float* __restrict__ rws,
    const float* __restrict__ x, float* __restrict__ xt,
    const float* __restrict__ k_w, const float* __restrict__ v_w, const float* __restrict__ out_w,
    unsigned short* __restrict__ kw16, unsigned short* __restrict__ vw16, float* __restrict__ ow_t){
  __shared__ float t[64][65];
  int bx = blockIdx.x;               // 4160 = 3072 offsets + 768 transpose + 320 wprep
  if(bx < 3072){
    int wid  = bx*4 + (threadIdx.x>>6);
    int lane = threadIdx.x & 63;
    int vi  = wid >> 12;
    int rem = wid & 4095;
    int bg  = rem >> 10;
    int pix = rem & 1023;
    int y = pix >> 5, xq = pix & 31;
    int b = bg >> 1, g = bg & 1;
    float qv = query[(size_t)(b*128 + g*64 + lane)*1024 + pix];
    float h[4]; float s1 = 0.f, s2 = 0.f;
    #pragma unroll
    for(int d=0; d<4; ++d){
      h[d] = qv*w1[vi*256 + lane*4 + d] + b1[vi*256 + lane*4 + d];
      s1 += h[d]; s2 += h[d]*h[d];
    }
    #pragma unroll
    for(int off=1; off<64; off<<=1){ s1 += __shfl_xor(s1, off); s2 += __shfl_xor(s2, off); }
    float mu   = s1 * (1.f/256.f);
    float var  = s2 * (1.f/256.f) - mu*mu;
    float rstd = rsqrtf(fmaxf(var, 0.f) + 1e-5f);
    float po[4] = {0.f,0.f,0.f,0.f};
    #pragma unroll
    for(int d=0; d<4; ++d){
      float hv = (h[d]-mu)*rstd*lng[vi*256+lane*4+d] + lnb[vi*256+lane*4+d];
      hv = 0.5f*hv*(1.f + erff(hv*0.70710678118654752f));   // exact GELU
      #pragma unroll
      for(int o=0; o<4; ++o) po[o] += w2[(vi*4+o)*256 + lane*4 + d] * hv;
    }
    #pragma unroll
    for(int off=1; off<64; off<<=1){
      #pragma unroll
      for(int o=0; o<4; ++o) po[o] += __shfl_xor(po[o], off);
    }
    if(lane == 0){
      int tt = y & 1, hk = y >> 1;
      float rng = tt ? (5.f/127.f) : (5.f/15.f);
      float csc = tt ? 63.5f : 15.5f;
      #pragma unroll
      for(int d=0; d<4; ++d){
        int wk = xq*4 + d;
        float rv = refp[(size_t)(((b*3+vi)*16 + hk)*128 + wk)*2 + (1-tt)];  // [..., ::-1]
        float coord = tanhf(po[d])*rng + rv;
        size_t o2 = ((size_t)(vi*4+bg)*2048 + hk*128 + wk)*2 + tt;
        rwo[o2] = coord;
        rws[o2] = coord * csc;
      }
    }
  } else if(bx < 3840){
    int pb = bx - 3072;
    int iy = pb & 63;
    int o2 = pb >> 6;
    const float* src = x + ((size_t)o2*64)*4096 + (size_t)iy*64;
    int ix = threadIdx.x & 63, cq = threadIdx.x >> 6;
    #pragma unroll
    for(int c0 = 0; c0 < 64; c0 += 4)
      t[c0+cq][ix] = src[(size_t)(c0+cq)*4096 + ix];
    __syncthreads();
    float* dst = xt + (((size_t)o2*64 + iy)*64)*64;
    int c = threadIdx.x & 63, xq = threadIdx.x >> 6;
    #pragma unroll
    for(int x0 = 0; x0 < 64; x0 += 4)
      dst[(size_t)(x0+xq)*64 + c] = t[c][x0+xq];
  } else {
    int wb = bx - 3840;              // 320 = 64 kw16 + 64 vw16 + 192 ow_t
    if(wb < 128){
      int i = (wb & 63)*256 + threadIdx.x;
      if(wb < 64) kw16[i] = f2b(k_w[i]);
      else        vw16[i] = f2b(v_w[i]);
    } else {
      int i = (wb-128)*256 + threadIdx.x;
      if(i < 49152){
        int r = i / 384, c = i - r*384;
        ow_t[c*128 + r] = out_w[i];
      }
    }
  }
}

// ---------------------------------------------------------------- K1: fused sample + MFMA K/V projection, 8 waves (1 head/wave)
__global__ __launch_bounds__(512) void k_sampro(
    const float* __restrict__ rwo, const float* __restrict__ xt,
    const unsigned short* __restrict__ kw16, const float* __restrict__ k_b,
    const unsigned short* __restrict__ vw16, const float* __restrict__ v_b,
    unsigned short* __restrict__ k_b16, unsigned short* __restrict__ v_t16){
  __shared__ alignas(16) unsigned short tile[16*136];   // 4352 B bf16 xs tile
  int bx = blockIdx.x;               // 768 = (vi*2+b)*128 + nt
  int nt = bx & 127;
  int r2 = bx >> 7;
  int b = r2 & 1, vi = r2 >> 1;
  int n0 = nt*16;
  int tid = threadIdx.x, wid = tid>>6, lane = tid&63;
  #pragma unroll
  for(int s = 0; s < 4; ++s){        // 32 (n,g) units, 4 per wave
    int u = wid*4 + s;
    int nl = u >> 1, g = u & 1;
    int n = n0 + nl;
    float yn = rwo[((size_t)(vi*4 + b*2 + g)*2048 + n)*2 + 0];
    float xn = rwo[((size_t)(vi*4 + b*2 + g)*2048 + n)*2 + 1];
    float px = (xn + 1.f)*31.5f;
    float py = (yn + 1.f)*31.5f;
    float x0 = floorf(px), y0 = floorf(py);
    float fx = px - x0, fy = py - y0;
    int ix0 = (int)x0, iy0 = (int)y0;
    const float* base = xt + (size_t)((b*3+vi)*2+g)*4096*64;
    float wts[4] = {(1.f-fx)*(1.f-fy), fx*(1.f-fy), (1.f-fx)*fy, fx*fy};
    int ixs[4] = {ix0, ix0+1, ix0, ix0+1};
    int iys[4] = {iy0, iy0, iy0+1, iy0+1};
    float acc = 0.f;
    #pragma unroll
    for(int tp=0; tp<4; ++tp){
      int ix = ixs[tp], iy = iys[tp];
      if(ix>=0 && ix<64 && iy>=0 && iy<64)
        acc += wts[tp] * base[(size_t)((iy<<6)+ix)*64 + lane];
    }
    tile[nl*136 + g*64 + lane] = f2b(acc);
  }
  __syncthreads();
  // ---- MFMA projection: wave w -> head w, K + V tiles
  int c = lane & 15, qd = lane >> 4;
  short8 af[4];                      // A[m=sample n=c][k=c-chan qd*8+j], 4 x K=32 = 128 ch
  #pragma unroll
  for(int kc=0; kc<4; ++kc)
    af[kc] = *(const short8*)(&tile[c*136 + kc*32 + qd*8]);
  size_t vbbase = (size_t)(vi*16 + b*8)*2048*16;
  const float SC2 = 0.36067376022224085f;     // 0.25 * log2(e), folded into K
  int nh = wid;
  size_t hbase = vbbase + (size_t)nh*2048*16;
  {  // K head: k_b16[n][ch], pre-scaled by SC2
    f32x4 C = {0.f,0.f,0.f,0.f};
    #pragma unroll
    for(int kc=0; kc<4; ++kc){
      short8 bf = *(const short8*)(kw16 + (size_t)(nh*16 + c)*128 + kc*32 + qd*8);
      C = __builtin_amdgcn_mfma_f32_16x16x32_bf16(af[kc], bf, C, 0, 0, 0);
    }
    float bias = k_b[nh*16 + c];
    #pragma unroll
    for(int r=0; r<4; ++r)
      k_b16[hbase + (size_t)(n0 + qd*4 + r)*16 + c] = f2b((C[r] + bias)*SC2);
  }
  {  // V head: v_t16[ch][n], plain layout, vectorized uint2 store
    f32x4 C = {0.f,0.f,0.f,0.f};
    #pragma unroll
    for(int kc=0; kc<4; ++kc){
      short8 bf = *(const short8*)(vw16 + (size_t)(nh*16 + c)*128 + kc*32 + qd*8);
      C = __builtin_amdgcn_mfma_f32_16x16x32_bf16(af[kc], bf, C, 0, 0, 0);
    }
    float bias = v_b[nh*16 + c];
    uint2 pk;
    pk.x = cvt_pk_bf16(C[0]+bias, C[1]+bias);
    pk.y = cvt_pk_bf16(C[2]+bias, C[3]+bias);
    *(uint2*)(v_t16 + hbase + (size_t)c*2048 + n0 + qd*4) = pk;
  }
}

// ---------------------------------------------------------------- K2: MFMA flash attention, 512 thr, x-half blocks, 3 blocks/CU,
//                                                                  K=16 QK MFMA, si via ones-A MFMA (denominator off the VALU)
__global__ __launch_bounds__(512,6) void k_attn(
    const float* __restrict__ rws, const unsigned short* __restrict__ k_b16,
    const unsigned short* __restrict__ v_t16, const float* __restrict__ query,
    const float* __restrict__ rpe, float* __restrict__ attn_pc){
  __shared__ unsigned P32[49*197];               // 38,612 B (lo, hi-lo) log2-scaled bf16 pairs
  __shared__ alignas(16) short p_sm[8][16*40];   // 10,240 B per-wave P^T buffer (reused as f32 merge buffer)
  int bx = blockIdx.x;            // 768 = vi*256 + bh*16 + mq*2 + h
  int vi = bx >> 8;
  int bh = (bx >> 4) & 15;
  int mq = (bx >> 1) & 7;         // m-quad: 4 consecutive grid rows
  int h  = bx & 1;                // x-half: m-cols [16h, 16h+16)
  int b = bh >> 3, nh = bh & 7, g = nh >> 2, bg = b*2 + g;
  int tid = threadIdx.x, wid = tid >> 6;
  int w4  = wid & 3;              // grid-row within the quad
  int nhf = wid >> 2;             // nc half: 0 -> nc 0..7, 1 -> nc 8..15
  int lane = tid & 63, c = lane & 15, qd = lane >> 4;
  int m0 = (mq*4 + w4)*32 + 16*h;
  int xoff = h*64;
  float gy0 = -1.f + (2.f/31.f)*(float)(mq*4);
  float pyL = 15.5f*(gy0 - 4.f/3.f) + 31.f - 0.01f;
  float pyH = 15.5f*(gy0 + 6.f/31.f + 4.f/3.f) + 31.f + 0.01f;
  int a  = max(-1, (int)floorf(pyL));
  int bb = min(63, (int)floorf(pyH));
  int iy_lo = max(a - 1, bb - 48);
  {
    const float* rt = rpe + (size_t)nh*16065;
    for(int e = tid; e < 49*197; e += 512){
      int rr = e / 197;
      int cc = e - rr*197;
      int iy = iy_lo + rr;
      int ix = cc - 1 + xoff;
      bool xv = (ix >= 0) && (ix <= 254);
      float lo = (xv && iy   >= 0 && iy   <= 62) ? rt[iy*255 + ix]     : 0.f;
      float hi = (xv && iy+1 >= 0 && iy+1 <= 62) ? rt[(iy+1)*255 + ix] : 0.f;
      P32[e] = cvt_pk_bf16(lo*1.44269504f, (hi - lo)*1.44269504f);
    }
  }
#if HAVE_MFMA16
  short4v qa;                      // K=16: ch = qd*4 + j, every lane real data
  #pragma unroll
  for(int j=0; j<4; ++j){
    int ch = qd*4 + j;
    qa[j] = (short)f2b(query[(size_t)(b*128 + nh*16 + ch)*1024 + m0 + c]);
  }
#else
  short8 qa;
  #pragma unroll
  for(int j=0; j<8; ++j){
    int ch = qd*8 + j;
    qa[j] = (qd < 2) ? (short)f2b(query[(size_t)(b*128 + nh*16 + ch)*1024 + m0 + c]) : (short)0;
  }
#endif
  float Ax2[4];                    // xoff folded in: px is window-local
  #pragma unroll
  for(int r=0; r<4; ++r){
    int mr = m0 + qd*4 + r;
    float gxr = -1.f + (2.f/31.f)*(mr & 31);
    Ax2[r] = 63.5f*gxr + 128.f - (float)xoff;
  }
  // wave's 16 m-rows share one grid row -> y-side wave-uniform per sample
  float gyw = -1.f + (2.f/31.f)*(float)(m0 >> 5);
  float Ay  = 15.5f*gyw + 31.f - (float)iy_lo;
  float loC = fmaxf(-1.f - (float)iy_lo, 0.f);
  float hiC = fminf(63.f - (float)iy_lo, 47.f);
  f32x4 sacc = {0.f, 0.f, 0.f, 0.f};   // denominator via ones-A MFMA
  f32x4 O = {0.f, 0.f, 0.f, 0.f};
  size_t kvb  = (size_t)(vi*16 + bh)*2048*16;
  size_t rwsb = (size_t)(vi*4 + bg)*2048;
  short* pw = &p_sm[wid][0];
  const f32x4 z = {0.f,0.f,0.f,0.f};
  short8 ones1;                    // bf16 1.0 in every A slot
  #pragma unroll
  for(int j=0; j<8; ++j) ones1[j] = (short)0x3F80;
  __syncthreads();
  for(int nc = nhf*8, ncE = nhf*8 + 8; nc < ncE; ++nc){
    int n0 = nc*128;
#if HAVE_MFMA16
    const unsigned short* kb = k_b16 + kvb + (size_t)(n0 + c)*16 + qd*4;   // + t*256
#else
    const unsigned short* kb = k_b16 + kvb + (size_t)(n0 + c)*16 + qd*8;   // + t*256
#endif
    #pragma unroll
    for(int kc=0; kc<4; ++kc){
      // ---- issue both S-MFMAs for this kc first; the per-t address/bias
      //      math below is S-independent and covers their latency
#if HAVE_MFMA16
      short4v bk0 = *(const short4v*)(kb + (2*kc)*256);
      short4v bk1 = *(const short4v*)(kb + (2*kc+1)*256);
      __builtin_amdgcn_s_setprio(1);
      f32x4 S0 = MFMA16(qa, bk0, z);
      f32x4 S1 = MFMA16(qa, bk1, z);
      __builtin_amdgcn_s_setprio(0);
#else
      short8 bk0 = {0,0,0,0,0,0,0,0}, bk1 = {0,0,0,0,0,0,0,0};
      if(qd < 2){ bk0 = *(const short8*)(kb + (2*kc)*256); bk1 = *(const short8*)(kb + (2*kc+1)*256); }
      f32x4 S0 = __builtin_amdgcn_mfma_f32_16x16x32_bf16(qa, bk0, z, 0, 0, 0);
      f32x4 S1 = __builtin_amdgcn_mfma_f32_16x16x32_bf16(qa, bk1, z, 0, 0, 0);
#endif
      // ---- fused bias+exp per (t,r)
      float pe[4], po[4];
      {
        float2 rs = *(const float2*)(rws + (rwsb + n0 + (2*kc)*16 + c)*2);
        float py = Ay - rs.x;
        py = fminf(fmaxf(py, loC), hiC);
        float rf = floorf(py);
        float fy = py - rf;
        int rbase = (int)rf * 197 + 1;
        #pragma unroll
        for(int r=0; r<4; ++r){
          float px = Ax2[r] - rs.y;
          px = fminf(fmaxf(px, 0.f), 192.f);
          float cf = floorf(px);
          float fx = px - cf;
          int idx = rbase + (int)cf;
          unsigned w0 = P32[idx], w1 = P32[idx+1];
          float lo0 = __uint_as_float(w0 << 16), d0 = __uint_as_float(w0 & 0xFFFF0000u);
          float lo1 = __uint_as_float(w1 << 16), d1 = __uint_as_float(w1 & 0xFFFF0000u);
          float t0 = lo0 + fy*d0;
          float t1 = lo1 + fy*d1;
          pe[r] = exp2f(S0[r] + t0 + fx*(t1 - t0));   // K pre-scaled by 0.25*log2e
        }
      }
      {
        float2 rs = *(const float2*)(rws + (rwsb + n0 + (2*kc+1)*16 + c)*2);
        float py = Ay - rs.x;
        py = fminf(fmaxf(py, loC), hiC);
        float rf = floorf(py);
        float fy = py - rf;
        int rbase = (int)rf * 197 + 1;
        #pragma unroll
        for(int r=0; r<4; ++r){
          float px = Ax2[r] - rs.y;
          px = fminf(fmaxf(px, 0.f), 192.f);
          float cf = floorf(px);
          float fx = px - cf;
          int idx = rbase + (int)cf;
          unsigned w0 = P32[idx], w1 = P32[idx+1];
          float lo0 = __uint_as_float(w0 << 16), d0 = __uint_as_float(w0 & 0xFFFF0000u);
          float lo1 = __uint_as_float(w1 << 16), d1 = __uint_as_float(w1 & 0xFFFF0000u);
          float t0 = lo0 + fy*d0;
          float t1 = lo1 + fy*d1;
          po[r] = exp2f(S1[r] + t0 + fx*(t1 - t0));
        }
      }
      // ---- pack P^T into per-wave LDS, then PV + ones-A (denominator) MFMAs
      #pragma unroll
      for(int r=0; r<4; ++r){
        unsigned pk = cvt_pk_bf16(pe[r], po[r]);
        pw[(qd*4 + r)*40 + c]      = (short)pk;
        pw[(qd*4 + r)*40 + 16 + c] = (short)(pk >> 16);
      }
      short8 va = *(const short8*)(v_t16 + kvb + (size_t)c*2048 + n0 + kc*32 + qd*8);
      short8 pbf = *(const short8*)(&pw[c*40 + qd*8]);
      __builtin_amdgcn_s_setprio(1);
      O    = __builtin_amdgcn_mfma_f32_16x16x32_bf16(va, pbf, O, 0, 0, 0);
      sacc = __builtin_amdgcn_mfma_f32_16x16x32_bf16(ones1, pbf, sacc, 0, 0, 0);
      __builtin_amdgcn_s_setprio(0);
    }
  }
  // ---- merge the two nc halves via LDS (reuse p_sm block as f32 buffer)
  // sacc[r] are all equal = si[m=c] (every D-row of the ones-A product is the
  // column sum); lane's output row is m=c, so no cross-lane reduce is needed.
  __syncthreads();
  float* red = (float*)&p_sm[0][0];
  int basei = (w4*64 + lane)*8;
  if(nhf){
    red[basei+0] = O[0];  red[basei+1] = O[1];
    red[basei+2] = O[2];  red[basei+3] = O[3];
    red[basei+4] = sacc[0];
  }
  __syncthreads();
  if(!nhf){
    O[0] += red[basei+0]; O[1] += red[basei+1];
    O[2] += red[basei+2]; O[3] += red[basei+3];
    float sv = sacc[0] + red[basei+4];
    float inv = 1.f/sv;
    float4 o4;
    o4.x = O[0]*inv; o4.y = O[1]*inv; o4.z = O[2]*inv; o4.w = O[3]*inv;
    *(float4*)(attn_pc + (size_t)(b*1024 + m0 + c)*384 + vi*128 + nh*16 + qd*4) = o4;
  }
}

// ---------------------------------------------------------------- K3: output projection (512 blocks, 4 m-rows each)
__global__ __launch_bounds__(256) void k_outproj(
    const float* __restrict__ attn_pc, const float* __restrict__ ow_t, const float* __restrict__ out_b,
    float* __restrict__ out){
  __shared__ float A[4*384];         // 6 KB
  int bx = blockIdx.x;               // 512 = b*256 + mt
  int b  = bx >> 8;
  int m0 = (bx & 255)*4;
  const float4* src = (const float4*)(attn_pc + ((size_t)b*1024 + m0)*384);
  float4* dst = (float4*)A;
  for(int i = threadIdx.x; i < 384; i += 256) dst[i] = src[i];
  __syncthreads();
  int oc = threadIdx.x & 127;
  int mh = threadIdx.x >> 7;         // 0..1, each handles 2 m-rows
  float acc[2] = {0.f,0.f};
  #pragma unroll 4
  for(int vc = 0; vc < 384; ++vc){
    float wv = ow_t[vc*128 + oc];
    #pragma unroll
    for(int j=0; j<2; ++j) acc[j] += wv * A[(mh*2+j)*384 + vc];
  }
  float ob = out_b[oc];
  #pragma unroll
  for(int j=0; j<2; ++j)
    out[((size_t)b*128 + oc)*1024 + m0 + mh*2 + j] = acc[j] + ob;
}

extern "C" void kernel_launch(void* const* d_in, const int* in_sizes, int n_in,
                              void* d_out, int out_size, void* d_ws, size_t ws_size,
                              hipStream_t stream){
  const float* x     = (const float*)d_in[0];
  const float* query = (const float*)d_in[1];
  const float* refp  = (const float*)d_in[2];
  const float* w1    = (const float*)d_in[3];
  const float* b1    = (const float*)d_in[4];
  const float* lng   = (const float*)d_in[5];
  const float* lnb   = (const float*)d_in[6];
  const float* w2    = (const float*)d_in[7];
  const float* k_w   = (const float*)d_in[8];
  const float* k_b   = (const float*)d_in[9];
  const float* v_w   = (const float*)d_in[10];
  const float* v_b   = (const float*)d_in[11];
  const float* out_w = (const float*)d_in[12];
  const float* out_b = (const float*)d_in[13];
  const float* rpe   = (const float*)d_in[14];

  const size_t O_XT   = 0;            // 12,582,912
  const size_t O_RWO  = 12582912;     //    196,608
  const size_t O_RWS  = 12779520;     //    196,608
  const size_t O_KB16 = 12976128;     //  3,145,728
  const size_t O_VT16 = 16121856;     //  3,145,728
  const size_t O_APC  = 19267584;     //  3,145,728
  const size_t O_KW16 = 22413312;     //     32,768
  const size_t O_VW16 = 22446080;     //     32,768
  const size_t O_OWT  = 22478848;     //    196,608
  const size_t NEED   = 22675456;
  if(ws_size < NEED){
    k_probe<<<1, 64, 0, stream>>>((float*)d_out, 100.f + (float)(ws_size >> 20));
    return;
  }
  char* ws = (char*)d_ws;
  float* xt      = (float*)(ws + O_XT);
  float* rwo     = (float*)(ws + O_RWO);
  float* rws     = (float*)(ws + O_RWS);
  unsigned short* k_b16 = (unsigned short*)(ws + O_KB16);
  unsigned short* v_t16 = (unsigned short*)(ws + O_VT16);
  float* attn_pc = (float*)(ws + O_APC);
  unsigned short* kw16 = (unsigned short*)(ws + O_KW16);
  unsigned short* vw16 = (unsigned short*)(ws + O_VW16);
  float* ow_t    = (float*)(ws + O_OWT);

  k_prep_off<<<4160, 256, 0, stream>>>(query, refp, w1, b1, lng, lnb, w2, rwo, rws,
                                       x, xt, k_w, v_w, out_w, kw16, vw16, ow_t);
  k_sampro  <<<768,  512, 0, stream>>>(rwo, xt, kw16, k_b, vw16, v_b, k_b16, v_t16);
  k_attn    <<<768,  512, 0, stream>>>(rws, k_b16, v_t16, query, rpe, attn_pc);
  k_outproj <<<512,  256, 0, stream>>>(attn_pc, ow_t, out_b, (float*)d_out);
}

// Round 11
// 223.404 us; speedup vs baseline: 1.2196x; 1.0222x over previous
//
#include <hip/hip_runtime.h>
#include <hip/hip_bf16.h>
#include <math.h>

// B=2 V=3 G=2 NH=8 C=128 CPG=64 CH=16 HPG=4 Hq=Wq=32 D=4 Hk=16 Wk=128 NS=2048
// Hi=Wi=64 SCALE=0.25 OFR=5 EPS=1e-5  RPE 63x255 per head
// All inputs fp32, output fp32 (established R2-R6).
// R24 = R23 with the bias-gather arithmetic strength-reduced (k_attn is
// VALU-issue-bound at 86%):
//   - float-domain window index: idx = (int)(rf*197.f + px) — exact (sums
//     < 2^14 << 2^24); removes per-t {cvt,mul,add} and per-r {cvt,add}.
//   - v_fract_f32 for fx (1 op vs floor+sub).
//   - hi(delta) unpack without the & 0xFFFF0000 mask: mantissa-tail garbage
//     <= d*2^-8 on a ~0.01 log2-value -> ~3e-5 P perturbation, invisible.
//   Net ~-24% of the per-kc bias VALU. Everything else identical to R23
//   (K=16 QK MFMA, ones-A MFMA denominator, setprio, x-half windows,
//   3 blocks/CU, no spill).

typedef __attribute__((ext_vector_type(8))) short short8;
typedef __attribute__((ext_vector_type(4))) short short4v;
typedef __attribute__((ext_vector_type(4))) float f32x4;

#if __has_builtin(__builtin_amdgcn_mfma_f32_16x16x16_bf16)
  #define MFMA16(a,b,c) __builtin_amdgcn_mfma_f32_16x16x16_bf16((a),(b),(c),0,0,0)
  #define HAVE_MFMA16 1
#elif __has_builtin(__builtin_amdgcn_mfma_f32_16x16x16bf16_1k)
  #define MFMA16(a,b,c) __builtin_amdgcn_mfma_f32_16x16x16bf16_1k((a),(b),(c),0,0,0)
  #define HAVE_MFMA16 1
#else
  #define HAVE_MFMA16 0
#endif

#if __has_builtin(__builtin_amdgcn_fractf)
  #define FRACT(x) __builtin_amdgcn_fractf(x)
#else
  #define FRACT(x) ((x) - floorf(x))
#endif

__device__ __forceinline__ unsigned short f2b(float f){        // fp32 -> bf16 RNE
  unsigned u = __float_as_uint(f);
  return (unsigned short)((u + 0x7FFFu + ((u>>16)&1u)) >> 16);
}
__device__ __forceinline__ unsigned cvt_pk_bf16(float lo, float hi){  // HW RNE pair-convert
  unsigned r;
  asm("v_cvt_pk_bf16_f32 %0, %1, %2" : "=v"(r) : "v"(lo), "v"(hi));
  return r;
}

__global__ void k_probe(float* __restrict__ out, float code){
  if(blockIdx.x==0 && threadIdx.x==0) out[0] = code;
}

// ---------------------------------------------------------------- K0: offsets (3072) + x-transpose (768) + weight prep (320)
__global__ __launch_bounds__(256) void k_prep_off(
    const float* __restrict__ query, const float* __restrict__ refp,
    const float* __restrict__ w1, const float* __restrict__ b1,
    const float* __restrict__ lng, const float* __restrict__ lnb,
    const float* __restrict__ w2, float* __restrict__ rwo, float* __restrict__ rws,
    const float* __restrict__ x, float* __restrict__ xt,
    const float* __restrict__ k_w, const float* __restrict__ v_w, const float* __restrict__ out_w,
    unsigned short* __restrict__ kw16, unsigned short* __restrict__ vw16, float* __restrict__ ow_t){
  __shared__ float t[64][65];
  int bx = blockIdx.x;               // 4160 = 3072 offsets + 768 transpose + 320 wprep
  if(bx < 3072){
    int wid  = bx*4 + (threadIdx.x>>6);
    int lane = threadIdx.x & 63;
    int vi  = wid >> 12;
    int rem = wid & 4095;
    int bg  = rem >> 10;
    int pix = rem & 1023;
    int y = pix >> 5, xq = pix & 31;
    int b = bg >> 1, g = bg & 1;
    float qv = query[(size_t)(b*128 + g*64 + lane)*1024 + pix];
    float h[4]; float s1 = 0.f, s2 = 0.f;
    #pragma unroll
    for(int d=0; d<4; ++d){
      h[d] = qv*w1[vi*256 + lane*4 + d] + b1[vi*256 + lane*4 + d];
      s1 += h[d]; s2 += h[d]*h[d];
    }
    #pragma unroll
    for(int off=1; off<64; off<<=1){ s1 += __shfl_xor(s1, off); s2 += __shfl_xor(s2, off); }
    float mu   = s1 * (1.f/256.f);
    float var  = s2 * (1.f/256.f) - mu*mu;
    float rstd = rsqrtf(fmaxf(var, 0.f) + 1e-5f);
    float po[4] = {0.f,0.f,0.f,0.f};
    #pragma unroll
    for(int d=0; d<4; ++d){
      float hv = (h[d]-mu)*rstd*lng[vi*256+lane*4+d] + lnb[vi*256+lane*4+d];
      hv = 0.5f*hv*(1.f + erff(hv*0.70710678118654752f));   // exact GELU
      #pragma unroll
      for(int o=0; o<4; ++o) po[o] += w2[(vi*4+o)*256 + lane*4 + d] * hv;
    }
    #pragma unroll
    for(int off=1; off<64; off<<=1){
      #pragma unroll
      for(int o=0; o<4; ++o) po[o] += __shfl_xor(po[o], off);
    }
    if(lane == 0){
      int tt = y & 1, hk = y >> 1;
      float rng = tt ? (5.f/127.f) : (5.f/15.f);
      float csc = tt ? 63.5f : 15.5f;
      #pragma unroll
      for(int d=0; d<4; ++d){
        int wk = xq*4 + d;
        float rv = refp[(size_t)(((b*3+vi)*16 + hk)*128 + wk)*2 + (1-tt)];  // [..., ::-1]
        float coord = tanhf(po[d])*rng + rv;
        size_t o2 = ((size_t)(vi*4+bg)*2048 + hk*128 + wk)*2 + tt;
        rwo[o2] = coord;
        rws[o2] = coord * csc;
      }
    }
  } else if(bx < 3840){
    int pb = bx - 3072;
    int iy = pb & 63;
    int o2 = pb >> 6;
    const float* src = x + ((size_t)o2*64)*4096 + (size_t)iy*64;
    int ix = threadIdx.x & 63, cq = threadIdx.x >> 6;
    #pragma unroll
    for(int c0 = 0; c0 < 64; c0 += 4)
      t[c0+cq][ix] = src[(size_t)(c0+cq)*4096 + ix];
    __syncthreads();
    float* dst = xt + (((size_t)o2*64 + iy)*64)*64;
    int c = threadIdx.x & 63, xq = threadIdx.x >> 6;
    #pragma unroll
    for(int x0 = 0; x0 < 64; x0 += 4)
      dst[(size_t)(x0+xq)*64 + c] = t[c][x0+xq];
  } else {
    int wb = bx - 3840;              // 320 = 64 kw16 + 64 vw16 + 192 ow_t
    if(wb < 128){
      int i = (wb & 63)*256 + threadIdx.x;
      if(wb < 64) kw16[i] = f2b(k_w[i]);
      else        vw16[i] = f2b(v_w[i]);
    } else {
      int i = (wb-128)*256 + threadIdx.x;
      if(i < 49152){
        int r = i / 384, c = i - r*384;
        ow_t[c*128 + r] = out_w[i];
      }
    }
  }
}

// ---------------------------------------------------------------- K1: fused sample + MFMA K/V projection, 8 waves (1 head/wave)
__global__ __launch_bounds__(512) void k_sampro(
    const float* __restrict__ rwo, const float* __restrict__ xt,
    const unsigned short* __restrict__ kw16, const float* __restrict__ k_b,
    const unsigned short* __restrict__ vw16, const float* __restrict__ v_b,
    unsigned short* __restrict__ k_b16, unsigned short* __restrict__ v_t16){
  __shared__ alignas(16) unsigned short tile[16*136];   // 4352 B bf16 xs tile
  int bx = blockIdx.x;               // 768 = (vi*2+b)*128 + nt
  int nt = bx & 127;
  int r2 = bx >> 7;
  int b = r2 & 1, vi = r2 >> 1;
  int n0 = nt*16;
  int tid = threadIdx.x, wid = tid>>6, lane = tid&63;
  #pragma unroll
  for(int s = 0; s < 4; ++s){        // 32 (n,g) units, 4 per wave
    int u = wid*4 + s;
    int nl = u >> 1, g = u & 1;
    int n = n0 + nl;
    float yn = rwo[((size_t)(vi*4 + b*2 + g)*2048 + n)*2 + 0];
    float xn = rwo[((size_t)(vi*4 + b*2 + g)*2048 + n)*2 + 1];
    float px = (xn + 1.f)*31.5f;
    float py = (yn + 1.f)*31.5f;
    float x0 = floorf(px), y0 = floorf(py);
    float fx = px - x0, fy = py - y0;
    int ix0 = (int)x0, iy0 = (int)y0;
    const float* base = xt + (size_t)((b*3+vi)*2+g)*4096*64;
    float wts[4] = {(1.f-fx)*(1.f-fy), fx*(1.f-fy), (1.f-fx)*fy, fx*fy};
    int ixs[4] = {ix0, ix0+1, ix0, ix0+1};
    int iys[4] = {iy0, iy0, iy0+1, iy0+1};
    float acc = 0.f;
    #pragma unroll
    for(int tp=0; tp<4; ++tp){
      int ix = ixs[tp], iy = iys[tp];
      if(ix>=0 && ix<64 && iy>=0 && iy<64)
        acc += wts[tp] * base[(size_t)((iy<<6)+ix)*64 + lane];
    }
    tile[nl*136 + g*64 + lane] = f2b(acc);
  }
  __syncthreads();
  // ---- MFMA projection: wave w -> head w, K + V tiles
  int c = lane & 15, qd = lane >> 4;
  short8 af[4];                      // A[m=sample n=c][k=c-chan qd*8+j], 4 x K=32 = 128 ch
  #pragma unroll
  for(int kc=0; kc<4; ++kc)
    af[kc] = *(const short8*)(&tile[c*136 + kc*32 + qd*8]);
  size_t vbbase = (size_t)(vi*16 + b*8)*2048*16;
  const float SC2 = 0.36067376022224085f;     // 0.25 * log2(e), folded into K
  int nh = wid;
  size_t hbase = vbbase + (size_t)nh*2048*16;
  {  // K head: k_b16[n][ch], pre-scaled by SC2
    f32x4 C = {0.f,0.f,0.f,0.f};
    #pragma unroll
    for(int kc=0; kc<4; ++kc){
      short8 bf = *(const short8*)(kw16 + (size_t)(nh*16 + c)*128 + kc*32 + qd*8);
      C = __builtin_amdgcn_mfma_f32_16x16x32_bf16(af[kc], bf, C, 0, 0, 0);
    }
    float bias = k_b[nh*16 + c];
    #pragma unroll
    for(int r=0; r<4; ++r)
      k_b16[hbase + (size_t)(n0 + qd*4 + r)*16 + c] = f2b((C[r] + bias)*SC2);
  }
  {  // V head: v_t16[ch][n], plain layout, vectorized uint2 store
    f32x4 C = {0.f,0.f,0.f,0.f};
    #pragma unroll
    for(int kc=0; kc<4; ++kc){
      short8 bf = *(const short8*)(vw16 + (size_t)(nh*16 + c)*128 + kc*32 + qd*8);
      C = __builtin_amdgcn_mfma_f32_16x16x32_bf16(af[kc], bf, C, 0, 0, 0);
    }
    float bias = v_b[nh*16 + c];
    uint2 pk;
    pk.x = cvt_pk_bf16(C[0]+bias, C[1]+bias);
    pk.y = cvt_pk_bf16(C[2]+bias, C[3]+bias);
    *(uint2*)(v_t16 + hbase + (size_t)c*2048 + n0 + qd*4) = pk;
  }
}

// ---------------------------------------------------------------- K2: MFMA flash attention, 512 thr, x-half blocks, 3 blocks/CU,
//                                                                  K=16 QK MFMA, ones-A denominator, strength-reduced bias gather
__global__ __launch_bounds__(512,6) void k_attn(
    const float* __restrict__ rws, const unsigned short* __restrict__ k_b16,
    const unsigned short* __restrict__ v_t16, const float* __restrict__ query,
    const float* __restrict__ rpe, float* __restrict__ attn_pc){
  __shared__ unsigned P32[49*197];               // 38,612 B (lo, hi-lo) log2-scaled bf16 pairs
  __shared__ alignas(16) short p_sm[8][16*40];   // 10,240 B per-wave P^T buffer (reused as f32 merge buffer)
  int bx = blockIdx.x;            // 768 = vi*256 + bh*16 + mq*2 + h
  int vi = bx >> 8;
  int bh = (bx >> 4) & 15;
  int mq = (bx >> 1) & 7;         // m-quad: 4 consecutive grid rows
  int h  = bx & 1;                // x-half: m-cols [16h, 16h+16)
  int b = bh >> 3, nh = bh & 7, g = nh >> 2, bg = b*2 + g;
  int tid = threadIdx.x, wid = tid >> 6;
  int w4  = wid & 3;              // grid-row within the quad
  int nhf = wid >> 2;             // nc half: 0 -> nc 0..7, 1 -> nc 8..15
  int lane = tid & 63, c = lane & 15, qd = lane >> 4;
  int m0 = (mq*4 + w4)*32 + 16*h;
  int xoff = h*64;
  float gy0 = -1.f + (2.f/31.f)*(float)(mq*4);
  float pyL = 15.5f*(gy0 - 4.f/3.f) + 31.f - 0.01f;
  float pyH = 15.5f*(gy0 + 6.f/31.f + 4.f/3.f) + 31.f + 0.01f;
  int a  = max(-1, (int)floorf(pyL));
  int bb = min(63, (int)floorf(pyH));
  int iy_lo = max(a - 1, bb - 48);
  {
    const float* rt = rpe + (size_t)nh*16065;
    for(int e = tid; e < 49*197; e += 512){
      int rr = e / 197;
      int cc = e - rr*197;
      int iy = iy_lo + rr;
      int ix = cc - 1 + xoff;
      bool xv = (ix >= 0) && (ix <= 254);
      float lo = (xv && iy   >= 0 && iy   <= 62) ? rt[iy*255 + ix]     : 0.f;
      float hi = (xv && iy+1 >= 0 && iy+1 <= 62) ? rt[(iy+1)*255 + ix] : 0.f;
      P32[e] = cvt_pk_bf16(lo*1.44269504f, (hi - lo)*1.44269504f);
    }
  }
#if HAVE_MFMA16
  short4v qa;                      // K=16: ch = qd*4 + j, every lane real data
  #pragma unroll
  for(int j=0; j<4; ++j){
    int ch = qd*4 + j;
    qa[j] = (short)f2b(query[(size_t)(b*128 + nh*16 + ch)*1024 + m0 + c]);
  }
#else
  short8 qa;
  #pragma unroll
  for(int j=0; j<8; ++j){
    int ch = qd*8 + j;
    qa[j] = (qd < 2) ? (short)f2b(query[(size_t)(b*128 + nh*16 + ch)*1024 + m0 + c]) : (short)0;
  }
#endif
  float Ax2[4];                    // xoff folded in: px is window-local
  #pragma unroll
  for(int r=0; r<4; ++r){
    int mr = m0 + qd*4 + r;
    float gxr = -1.f + (2.f/31.f)*(mr & 31);
    Ax2[r] = 63.5f*gxr + 128.f - (float)xoff;
  }
  // wave's 16 m-rows share one grid row -> y-side wave-uniform per sample
  float gyw = -1.f + (2.f/31.f)*(float)(m0 >> 5);
  float Ay  = 15.5f*gyw + 31.f - (float)iy_lo;
  float loC = fmaxf(-1.f - (float)iy_lo, 0.f);
  float hiC = fminf(63.f - (float)iy_lo, 47.f);
  f32x4 sacc = {0.f, 0.f, 0.f, 0.f};   // denominator via ones-A MFMA
  f32x4 O = {0.f, 0.f, 0.f, 0.f};
  size_t kvb  = (size_t)(vi*16 + bh)*2048*16;
  size_t rwsb = (size_t)(vi*4 + bg)*2048;
  short* pw = &p_sm[wid][0];
  const f32x4 z = {0.f,0.f,0.f,0.f};
  short8 ones1;                    // bf16 1.0 in every A slot
  #pragma unroll
  for(int j=0; j<8; ++j) ones1[j] = (short)0x3F80;
  __syncthreads();
  for(int nc = nhf*8, ncE = nhf*8 + 8; nc < ncE; ++nc){
    int n0 = nc*128;
#if HAVE_MFMA16
    const unsigned short* kb = k_b16 + kvb + (size_t)(n0 + c)*16 + qd*4;   // + t*256
#else
    const unsigned short* kb = k_b16 + kvb + (size_t)(n0 + c)*16 + qd*8;   // + t*256
#endif
    #pragma unroll
    for(int kc=0; kc<4; ++kc){
      // ---- issue both S-MFMAs for this kc first; the per-t address/bias
      //      math below is S-independent and covers their latency
#if HAVE_MFMA16
      short4v bk0 = *(const short4v*)(kb + (2*kc)*256);
      short4v bk1 = *(const short4v*)(kb + (2*kc+1)*256);
      __builtin_amdgcn_s_setprio(1);
      f32x4 S0 = MFMA16(qa, bk0, z);
      f32x4 S1 = MFMA16(qa, bk1, z);
      __builtin_amdgcn_s_setprio(0);
#else
      short8 bk0 = {0,0,0,0,0,0,0,0}, bk1 = {0,0,0,0,0,0,0,0};
      if(qd < 2){ bk0 = *(const short8*)(kb + (2*kc)*256); bk1 = *(const short8*)(kb + (2*kc+1)*256); }
      f32x4 S0 = __builtin_amdgcn_mfma_f32_16x16x32_bf16(qa, bk0, z, 0, 0, 0);
      f32x4 S1 = __builtin_amdgcn_mfma_f32_16x16x32_bf16(qa, bk1, z, 0, 0, 0);
#endif
      // ---- fused bias+exp per (t,r), strength-reduced indexing:
      //      idx = (int)(rf*197 + px) + 1  (f32-exact: sums < 2^14)
      //      hi-delta unpacked without mask (tail noise <= d*2^-8, invisible)
      float pe[4], po[4];
      {
        float2 rs = *(const float2*)(rws + (rwsb + n0 + (2*kc)*16 + c)*2);
        float py = Ay - rs.x;
        py = fminf(fmaxf(py, loC), hiC);
        float rf = floorf(py);
        float fy = py - rf;
        float rbasef = rf * 197.f;
        #pragma unroll
        for(int r=0; r<4; ++r){
          float px = Ax2[r] - rs.y;
          px = fminf(fmaxf(px, 0.f), 192.f);
          float fx = FRACT(px);
          int idx = (int)(rbasef + px) + 1;
          unsigned w0 = P32[idx], w1 = P32[idx+1];
          float lo0 = __uint_as_float(w0 << 16), d0 = __uint_as_float(w0);
          float lo1 = __uint_as_float(w1 << 16), d1 = __uint_as_float(w1);
          float t0 = lo0 + fy*d0;
          float t1 = lo1 + fy*d1;
          pe[r] = exp2f(S0[r] + t0 + fx*(t1 - t0));   // K pre-scaled by 0.25*log2e
        }
      }
      {
        float2 rs = *(const float2*)(rws + (rwsb + n0 + (2*kc+1)*16 + c)*2);
        float py = Ay - rs.x;
        py = fminf(fmaxf(py, loC), hiC);
        float rf = floorf(py);
        float fy = py - rf;
        float rbasef = rf * 197.f;
        #pragma unroll
        for(int r=0; r<4; ++r){
          float px = Ax2[r] - rs.y;
          px = fminf(fmaxf(px, 0.f), 192.f);
          float fx = FRACT(px);
          int idx = (int)(rbasef + px) + 1;
          unsigned w0 = P32[idx], w1 = P32[idx+1];
          float lo0 = __uint_as_float(w0 << 16), d0 = __uint_as_float(w0);
          float lo1 = __uint_as_float(w1 << 16), d1 = __uint_as_float(w1);
          float t0 = lo0 + fy*d0;
          float t1 = lo1 + fy*d1;
          po[r] = exp2f(S1[r] + t0 + fx*(t1 - t0));
        }
      }
      // ---- pack P^T into per-wave LDS, then PV + ones-A (denominator) MFMAs
      #pragma unroll
      for(int r=0; r<4; ++r){
        unsigned pk = cvt_pk_bf16(pe[r], po[r]);
        pw[(qd*4 + r)*40 + c]      = (short)pk;
        pw[(qd*4 + r)*40 + 16 + c] = (short)(pk >> 16);
      }
      short8 va = *(const short8*)(v_t16 + kvb + (size_t)c*2048 + n0 + kc*32 + qd*8);
      short8 pbf = *(const short8*)(&pw[c*40 + qd*8]);
      __builtin_amdgcn_s_setprio(1);
      O    = __builtin_amdgcn_mfma_f32_16x16x32_bf16(va, pbf, O, 0, 0, 0);
      sacc = __builtin_amdgcn_mfma_f32_16x16x32_bf16(ones1, pbf, sacc, 0, 0, 0);
      __builtin_amdgcn_s_setprio(0);
    }
  }
  // ---- merge the two nc halves via LDS (reuse p_sm block as f32 buffer)
  // sacc[0] = si[m=c] (every D-row of the ones-A product is the column sum).
  __syncthreads();
  float* red = (float*)&p_sm[0][0];
  int basei = (w4*64 + lane)*8;
  if(nhf){
    red[basei+0] = O[0];  red[basei+1] = O[1];
    red[basei+2] = O[2];  red[basei+3] = O[3];
    red[basei+4] = sacc[0];
  }
  __syncthreads();
  if(!nhf){
    O[0] += red[basei+0]; O[1] += red[basei+1];
    O[2] += red[basei+2]; O[3] += red[basei+3];
    float sv = sacc[0] + red[basei+4];
    float inv = 1.f/sv;
    float4 o4;
    o4.x = O[0]*inv; o4.y = O[1]*inv; o4.z = O[2]*inv; o4.w = O[3]*inv;
    *(float4*)(attn_pc + (size_t)(b*1024 + m0 + c)*384 + vi*128 + nh*16 + qd*4) = o4;
  }
}

// ---------------------------------------------------------------- K3: output projection (512 blocks, 4 m-rows each)
__global__ __launch_bounds__(256) void k_outproj(
    const float* __restrict__ attn_pc, const float* __restrict__ ow_t, const float* __restrict__ out_b,
    float* __restrict__ out){
  __shared__ float A[4*384];         // 6 KB
  int bx = blockIdx.x;               // 512 = b*256 + mt
  int b  = bx >> 8;
  int m0 = (bx & 255)*4;
  const float4* src = (const float4*)(attn_pc + ((size_t)b*1024 + m0)*384);
  float4* dst = (float4*)A;
  for(int i = threadIdx.x; i < 384; i += 256) dst[i] = src[i];
  __syncthreads();
  int oc = threadIdx.x & 127;
  int mh = threadIdx.x >> 7;         // 0..1, each handles 2 m-rows
  float acc[2] = {0.f,0.f};
  #pragma unroll 4
  for(int vc = 0; vc < 384; ++vc){
    float wv = ow_t[vc*128 + oc];
    #pragma unroll
    for(int j=0; j<2; ++j) acc[j] += wv * A[(mh*2+j)*384 + vc];
  }
  float ob = out_b[oc];
  #pragma unroll
  for(int j=0; j<2; ++j)
    out[((size_t)b*128 + oc)*1024 + m0 + mh*2 + j] = acc[j] + ob;
}

extern "C" void kernel_launch(void* const* d_in, const int* in_sizes, int n_in,
                              void* d_out, int out_size, void* d_ws, size_t ws_size,
                              hipStream_t stream){
  const float* x     = (const float*)d_in[0];
  const float* query = (const float*)d_in[1];
  const float* refp  = (const float*)d_in[2];
  const float* w1    = (const float*)d_in[3];
  const float* b1    = (const float*)d_in[4];
  const float* lng   = (const float*)d_in[5];
  const float* lnb   = (const float*)d_in[6];
  const float* w2    = (const float*)d_in[7];
  const float* k_w   = (const float*)d_in[8];
  const float* k_b   = (const float*)d_in[9];
  const float* v_w   = (const float*)d_in[10];
  const float* v_b   = (const float*)d_in[11];
  const float* out_w = (const float*)d_in[12];
  const float* out_b = (const float*)d_in[13];
  const float* rpe   = (const float*)d_in[14];

  const size_t O_XT   = 0;            // 12,582,912
  const size_t O_RWO  = 12582912;     //    196,608
  const size_t O_RWS  = 12779520;     //    196,608
  const size_t O_KB16 = 12976128;     //  3,145,728
  const size_t O_VT16 = 16121856;     //  3,145,728
  const size_t O_APC  = 19267584;     //  3,145,728
  const size_t O_KW16 = 22413312;     //     32,768
  const size_t O_VW16 = 22446080;     //     32,768
  const size_t O_OWT  = 22478848;     //    196,608
  const size_t NEED   = 22675456;
  if(ws_size < NEED){
    k_probe<<<1, 64, 0, stream>>>((float*)d_out, 100.f + (float)(ws_size >> 20));
    return;
  }
  char* ws = (char*)d_ws;
  float* xt      = (float*)(ws + O_XT);
  float* rwo     = (float*)(ws + O_RWO);
  float* rws     = (float*)(ws + O_RWS);
  unsigned short* k_b16 = (unsigned short*)(ws + O_KB16);
  unsigned short* v_t16 = (unsigned short*)(ws + O_VT16);
  float* attn_pc = (float*)(ws + O_APC);
  unsigned short* kw16 = (unsigned short*)(ws + O_KW16);
  unsigned short* vw16 = (unsigned short*)(ws + O_VW16);
  float* ow_t    = (float*)(ws + O_OWT);

  k_prep_off<<<4160, 256, 0, stream>>>(query, refp, w1, b1, lng, lnb, w2, rwo, rws,
                                       x, xt, k_w, v_w, out_w, kw16, vw16, ow_t);
  k_sampro  <<<768,  512, 0, stream>>>(rwo, xt, kw16, k_b, vw16, v_b, k_b16, v_t16);
  k_attn    <<<768,  512, 0, stream>>>(rws, k_b16, v_t16, query, rpe, attn_pc);
  k_outproj <<<512,  256, 0, stream>>>(attn_pc, ow_t, out_b, (float*)d_out);
}